// Round 2
// baseline (2174.188 us; speedup 1.0000x reference)
//
#include <hip/hip_runtime.h>

#define NFEAT 16
#define D 32
#define EH 64
#define NB 64        // num graphs
#define TCOLS 2080   // 65*32: h=0..63 from w2, h=64 row from b2

static inline size_t align_up(size_t x, size_t a){ return (x + a - 1) & ~(a - 1); }

// ---------- setup kernels ----------

// M[i][col], col = h*32+o : M[i][h*32+o] = w2[h][i*32+o] (h<64), = b2[i*32+o] (h==64)
__global__ __launch_bounds__(256) void kBuildM(const float* __restrict__ w2,
                                               const float* __restrict__ b2,
                                               float* __restrict__ M){
  int idx = blockIdx.x * 256 + threadIdx.x;
  if (idx >= 32 * TCOLS) return;
  int i = idx / TCOLS, col = idx % TCOLS;
  int h = col >> 5, o = col & 31;
  M[idx] = (h < 64) ? w2[h * 1024 + i * 32 + o] : b2[i * 32 + o];
}

__global__ __launch_bounds__(256) void kLin0(const float* __restrict__ x,
                                             const float* __restrict__ w,
                                             const float* __restrict__ b,
                                             float* __restrict__ feat, int N){
  int idx = blockIdx.x * 256 + threadIdx.x;
  int u = idx >> 5, o = idx & 31;
  if (u >= N) return;
  float acc = b[o];
#pragma unroll
  for (int i = 0; i < NFEAT; i++) acc += x[(size_t)u * NFEAT + i] * w[i * 32 + o];
  feat[idx] = fmaxf(acc, 0.f);
}

__global__ __launch_bounds__(256) void kCount(const int* __restrict__ ei,
                                              int* cnt_src, int* cnt_dst, int E){
  int e = blockIdx.x * 256 + threadIdx.x;
  if (e >= E) return;
  atomicAdd(&cnt_src[ei[e]], 1);
  atomicAdd(&cnt_dst[ei[E + e]], 1);
}

__global__ __launch_bounds__(256) void kBatchCount(const int* __restrict__ batch,
                                                   int* bc, int N){
  int i = blockIdx.x * 256 + threadIdx.x;
  if (i >= N) return;
  atomicAdd(&bc[batch[i]], 1);
}

// exclusive scan; blockIdx 0: src, 1: dst (+deg), 2: batch
__global__ __launch_bounds__(256) void kScan(const int* __restrict__ cnt_src,
                                             const int* __restrict__ cnt_dst,
                                             const int* __restrict__ bcnt,
                                             int* src_off, int* dst_off, int* boff,
                                             float* deg, int N, int B){
  __shared__ int part[256];
  const int* cnt; int* off; int n;
  if (blockIdx.x == 0)      { cnt = cnt_src; off = src_off; n = N; }
  else if (blockIdx.x == 1) { cnt = cnt_dst; off = dst_off; n = N; }
  else                      { cnt = bcnt;    off = boff;    n = B; }
  int t = threadIdx.x;
  int chunk = (n + 255) / 256;
  int lo = t * chunk, hi = min(n, lo + chunk);
  int s = 0;
  for (int i = lo; i < hi; i++) s += cnt[i];
  part[t] = s; __syncthreads();
  for (int d = 1; d < 256; d <<= 1){
    int v = (t >= d) ? part[t - d] : 0;
    __syncthreads();
    part[t] += v;
    __syncthreads();
  }
  int run = (t == 0) ? 0 : part[t - 1];
  for (int i = lo; i < hi; i++){ off[i] = run; run += cnt[i]; }
  if (t == 255) off[n] = part[255];
  if (blockIdx.x == 1){
    for (int i = lo; i < hi; i++) deg[i] = (float)max(cnt[i], 1);
  }
}

__global__ __launch_bounds__(256) void kFill(const int* __restrict__ ei,
                                             const int* __restrict__ src_off,
                                             const int* __restrict__ dst_off,
                                             int* fill_src, int* fill_dst,
                                             int* so_src, int* so_eid, int* dst_pos, int E){
  int e = blockIdx.x * 256 + threadIdx.x;
  if (e >= E) return;
  int s = ei[e], d = ei[E + e];
  int ps = src_off[s] + atomicAdd(&fill_src[s], 1);
  so_src[ps] = s;
  so_eid[ps] = e;
  int pd = dst_off[d] + atomicAdd(&fill_dst[d], 1);
  dst_pos[pd] = ps;
}

// ---------- per-iteration kernels ----------

// T = feat @ M for node chunk [c0,c1): [CH,32] x [32,2080]
__global__ __launch_bounds__(256) void kT(const float* __restrict__ feat,
                                          const float* __restrict__ M,
                                          float* __restrict__ T, int c0, int c1){
  __shared__ __attribute__((aligned(16))) float fT[32][32];   // fT[i][n]
  __shared__ __attribute__((aligned(16))) float Ml[32][128];
  int tid = threadIdx.x;
  int base = c0 + blockIdx.x * 32;
  for (int k = tid; k < 1024; k += 256){
    int n = k >> 5, i = k & 31;
    int u = base + n;
    fT[i][n] = (u < c1) ? feat[(size_t)u * 32 + i] : 0.f;
  }
  int wid = tid >> 6, lane = tid & 63;
  int r = lane >> 3, c = lane & 7;
  for (int ch = 0; ch < 17; ch++){
    int cbase = ch * 128;
    __syncthreads();
    for (int k = tid; k < 4096; k += 256){
      int row = k >> 7, cm = k & 127;
      int col = cbase + cm;
      Ml[row][cm] = (col < TCOLS) ? M[row * TCOLS + col] : 0.f;
    }
    __syncthreads();
    int col0 = cbase + wid * 32 + c * 4;
    if (col0 >= TCOLS) continue;
    float4 a0 = {0,0,0,0}, a1 = {0,0,0,0}, a2 = {0,0,0,0}, a3 = {0,0,0,0};
#pragma unroll
    for (int i = 0; i < 32; i++){
      float4 f = *(const float4*)&fT[i][r * 4];
      float4 m = *(const float4*)&Ml[i][wid * 32 + c * 4];
      a0.x += f.x * m.x; a0.y += f.x * m.y; a0.z += f.x * m.z; a0.w += f.x * m.w;
      a1.x += f.y * m.x; a1.y += f.y * m.y; a1.z += f.y * m.z; a1.w += f.y * m.w;
      a2.x += f.z * m.x; a2.y += f.z * m.y; a2.z += f.z * m.z; a2.w += f.z * m.w;
      a3.x += f.w * m.x; a3.y += f.w * m.y; a3.z += f.w * m.z; a3.w += f.w * m.w;
    }
    int u0 = base + r * 4;
    if (u0 + 0 < c1) *(float4*)&T[(size_t)(u0 + 0 - c0) * TCOLS + col0] = a0;
    if (u0 + 1 < c1) *(float4*)&T[(size_t)(u0 + 1 - c0) * TCOLS + col0] = a1;
    if (u0 + 2 < c1) *(float4*)&T[(size_t)(u0 + 2 - c0) * TCOLS + col0] = a2;
    if (u0 + 3 < c1) *(float4*)&T[(size_t)(u0 + 3 - c0) * TCOLS + col0] = a3;
  }
}

// msg[j][o] = sum_h a_j[h] * T[src(j)-c0][h*32+o] + T[src(j)-c0][2048+o]
// a_j computed on the fly from edge_attr; grid-strides over the chunk's
// contiguous src-CSR edge range [src_off[c0], src_off[c1]).
__global__ __launch_bounds__(256) void kA(const float* __restrict__ T,
                                          const int* __restrict__ so_src,
                                          const int* __restrict__ so_eid,
                                          const float* __restrict__ ea,
                                          const float* __restrict__ w1,
                                          const float* __restrict__ b1,
                                          const int* __restrict__ src_off,
                                          float* __restrict__ msg,
                                          int c0, int c1){
  __shared__ float alds[8][64];
  int tid = threadIdx.x;
  long long e0 = src_off[c0];
  long long e1 = src_off[c1];
  for (long long jb = e0 + (long long)blockIdx.x * 8; jb < e1;
       jb += (long long)gridDim.x * 8){
    // phase 1: edge MLP for up to 8 edges (64 threads per edge, one h each)
    for (int k = tid; k < 512; k += 256){
      int jj = k >> 6, h = k & 63;
      long long j = jb + jj;
      if (j < e1){
        int e = so_eid[j];
        float acc = b1[h];
#pragma unroll
        for (int q = 0; q < 5; q++) acc += ea[(size_t)e * 5 + q] * w1[q * 64 + h];
        alds[jj][h] = fmaxf(acc, 0.f);
      }
    }
    __syncthreads();
    // phase 2: contraction against T row of the source node
    {
      int jj = tid >> 5, o = tid & 31;
      long long j = jb + jj;
      if (j < e1){
        int u = so_src[j];
        const float* Tr = T + (size_t)(u - c0) * TCOLS;
        float acc = Tr[2048 + o];
#pragma unroll 8
        for (int h = 0; h < 64; h++) acc += alds[jj][h] * Tr[h * 32 + o];
        msg[(size_t)j * 32 + o] = acc;
      }
    }
    __syncthreads();
  }
}

// aggregate msg by dst + conv bias + relu + GRU step, 8 nodes/block
__global__ __launch_bounds__(256) void kB(const float* __restrict__ msg,
                                          const int* __restrict__ dst_off,
                                          const int* __restrict__ dst_pos,
                                          const float* __restrict__ deg,
                                          const float* __restrict__ feat_in,
                                          float* __restrict__ feat_out,
                                          const float* __restrict__ Wih,
                                          const float* __restrict__ Whh,
                                          const float* __restrict__ bih,
                                          const float* __restrict__ bhh,
                                          const float* __restrict__ cbias, int N){
  __shared__ float wih[96][33], whh[96][33];
  __shared__ float bi[96], bh[96], cb[32];
  __shared__ float msh[8][33], hsh[8][33];
  int tid = threadIdx.x;
  for (int k = tid; k < 96 * 32; k += 256){
    int g = k >> 5, o = k & 31;
    wih[g][o] = Wih[k];
    whh[g][o] = Whh[k];
  }
  if (tid < 96){ bi[tid] = bih[tid]; bh[tid] = bhh[tid]; }
  if (tid < 32) cb[tid] = cbias[tid];
  __syncthreads();
  int s = tid >> 5, o = tid & 31;
  int v = blockIdx.x * 8 + s;
  if (v >= N) return;
  int lo = dst_off[v], hi = dst_off[v + 1];
  float acc = 0.f;
  for (int k = lo; k < hi; k++){
    int p = dst_pos[k];
    acc += msg[(size_t)p * 32 + o];
  }
  float m = fmaxf(acc / deg[v] + cb[o], 0.f);
  float h = feat_in[(size_t)v * 32 + o];
  msh[s][o] = m;
  hsh[s][o] = h;
  float gr = bi[o], gz = bi[32 + o], gn = bi[64 + o];
  float hr = bh[o], hz = bh[32 + o], hn = bh[64 + o];
#pragma unroll
  for (int q = 0; q < 32; q++){
    float mq = msh[s][q], hq = hsh[s][q];
    gr += mq * wih[o][q];      gz += mq * wih[32 + o][q];  gn += mq * wih[64 + o][q];
    hr += hq * whh[o][q];      hz += hq * whh[32 + o][q];  hn += hq * whh[64 + o][q];
  }
  float r = 1.f / (1.f + expf(-(gr + hr)));
  float z = 1.f / (1.f + expf(-(gz + hz)));
  float n = tanhf(gn + r * hn);
  feat_out[(size_t)v * 32 + o] = (1.f - z) * n + z * h;
}

// ---------- Set2Set ----------

__global__ __launch_bounds__(256) void kLSTM(const float* __restrict__ Wih,
                                             const float* __restrict__ Whh,
                                             const float* __restrict__ bih,
                                             const float* __restrict__ bhh,
                                             float* __restrict__ q_star,
                                             float* __restrict__ hh,
                                             float* __restrict__ cc){
  __shared__ float WihT[64][129];
  __shared__ float WhhT[32][129];
  __shared__ float qs[8][65];
  __shared__ float hl[8][33];
  __shared__ float gates[8][129];
  int tid = threadIdx.x;
  int rbase = blockIdx.x * 8;
  for (int k = tid; k < 128 * 64; k += 256){ int j = k & 63, g = k >> 6; WihT[j][g] = Wih[g * 64 + j]; }
  for (int k = tid; k < 128 * 32; k += 256){ int j = k & 31, g = k >> 5; WhhT[j][g] = Whh[g * 32 + j]; }
  for (int k = tid; k < 512; k += 256){ int rr = k >> 6, j = k & 63; qs[rr][j] = q_star[(rbase + rr) * 64 + j]; }
  { int rr = tid >> 5, j = tid & 31; hl[rr][j] = hh[(rbase + rr) * 32 + j]; }
  __syncthreads();
  for (int k = tid; k < 1024; k += 256){
    int rr = k >> 7, g = k & 127;
    float acc = bih[g] + bhh[g];
#pragma unroll 8
    for (int j = 0; j < 64; j++) acc += qs[rr][j] * WihT[j][g];
#pragma unroll 8
    for (int j = 0; j < 32; j++) acc += hl[rr][j] * WhhT[j][g];
    gates[rr][g] = acc;
  }
  __syncthreads();
  {
    int rr = tid >> 5, j = tid & 31;
    int row = rbase + rr;
    float iv = gates[rr][j], fv = gates[rr][32 + j], gv = gates[rr][64 + j], ov = gates[rr][96 + j];
    iv = 1.f / (1.f + expf(-iv));
    fv = 1.f / (1.f + expf(-fv));
    gv = tanhf(gv);
    ov = 1.f / (1.f + expf(-ov));
    float c = fv * cc[row * 32 + j] + iv * gv;
    cc[row * 32 + j] = c;
    float hv = ov * tanhf(c);
    hh[row * 32 + j] = hv;
    q_star[row * 64 + j] = hv;
  }
}

// one block per graph: attention softmax + weighted pool
__global__ __launch_bounds__(256) void kPool(const float* __restrict__ feat,
                                             const int* __restrict__ boff,
                                             const float* __restrict__ hh,
                                             float* __restrict__ q_star,
                                             float* __restrict__ e_buf){
  int b = blockIdx.x;
  int lo = boff[b], hi = boff[b + 1];
  __shared__ float q[32];
  __shared__ float wred[4];
  __shared__ float part[8][33];
  int tid = threadIdx.x;
  if (tid < 32) q[tid] = hh[b * 32 + tid];
  __syncthreads();
  int sub = tid >> 5, o = tid & 31;
  float mx = -1e30f;
  for (int i = lo + sub; i < hi; i += 8){
    float v = feat[(size_t)i * 32 + o] * q[o];
#pragma unroll
    for (int d = 16; d; d >>= 1) v += __shfl_xor(v, d, 32);
    if (o == 0) e_buf[i] = v;
    mx = fmaxf(mx, v);
  }
#pragma unroll
  for (int d = 32; d; d >>= 1) mx = fmaxf(mx, __shfl_xor(mx, d, 64));
  if ((tid & 63) == 0) wred[tid >> 6] = mx;
  __syncthreads();
  mx = fmaxf(fmaxf(wred[0], wred[1]), fmaxf(wred[2], wred[3]));
  __syncthreads();
  float sm = 0.f;
  for (int i = lo + tid; i < hi; i += 256){
    float w = expf(e_buf[i] - mx);
    e_buf[i] = w;
    sm += w;
  }
#pragma unroll
  for (int d = 32; d; d >>= 1) sm += __shfl_xor(sm, d, 64);
  if ((tid & 63) == 0) wred[tid >> 6] = sm;
  __syncthreads();
  float denom = wred[0] + wred[1] + wred[2] + wred[3];
  denom = fmaxf(denom, 1e-30f);
  __syncthreads();
  float acc = 0.f;
  for (int i = lo + sub; i < hi; i += 8){
    acc += e_buf[i] * feat[(size_t)i * 32 + o];
  }
  part[sub][o] = acc;
  __syncthreads();
  if (tid < 32){
    float r = 0.f;
#pragma unroll
    for (int s2 = 0; s2 < 8; s2++) r += part[s2][tid];
    q_star[b * 64 + 32 + tid] = r / denom;
  }
}

__global__ __launch_bounds__(256) void kCopy(const float* __restrict__ src,
                                             float* __restrict__ dst, int n){
  int i = blockIdx.x * 256 + threadIdx.x;
  if (i < n) dst[i] = src[i];
}

// ---------- host ----------

extern "C" void kernel_launch(void* const* d_in, const int* in_sizes, int n_in,
                              void* d_out, int out_size, void* d_ws, size_t ws_size,
                              hipStream_t stream){
  (void)n_in; (void)out_size;
  const float* x        = (const float*)d_in[0];
  const int*   ei       = (const int*)  d_in[1];
  const float* eattr    = (const float*)d_in[2];
  const int*   batch    = (const int*)  d_in[3];
  const float* lin0_w   = (const float*)d_in[4];
  const float* lin0_b   = (const float*)d_in[5];
  const float* mlp_w1   = (const float*)d_in[6];
  const float* mlp_b1   = (const float*)d_in[7];
  const float* mlp_w2   = (const float*)d_in[8];
  const float* mlp_b2   = (const float*)d_in[9];
  const float* conv_b   = (const float*)d_in[10];
  const float* gru_wih  = (const float*)d_in[11];
  const float* gru_whh  = (const float*)d_in[12];
  const float* gru_bih  = (const float*)d_in[13];
  const float* gru_bhh  = (const float*)d_in[14];
  const float* lstm_wih = (const float*)d_in[15];
  const float* lstm_whh = (const float*)d_in[16];
  const float* lstm_bih = (const float*)d_in[17];
  const float* lstm_bhh = (const float*)d_in[18];

  int N = in_sizes[0] / NFEAT;
  int E = in_sizes[1] / 2;

  char* ws = (char*)d_ws;
  size_t off = 0;
  auto alloc = [&](size_t bytes) -> char* {
    char* p = ws + off;
    off = align_up(off + bytes, 256);
    return p;
  };

  // fixed-size buffers first; T gets the remainder (chunked if needed)
  float* feat0  = (float*)alloc((size_t)N * D * 4);
  float* feat1  = (float*)alloc((size_t)N * D * 4);
  float* msg    = (float*)alloc((size_t)E * D * 4);
  float* Mmat   = (float*)alloc((size_t)32 * TCOLS * 4);
  float* e_buf  = (float*)alloc((size_t)N * 4);
  float* deg    = (float*)alloc((size_t)N * 4);
  float* q_star = (float*)alloc((size_t)NB * 64 * 4);
  float* hhb    = (float*)alloc((size_t)NB * 32 * 4);
  float* ccb    = (float*)alloc((size_t)NB * 32 * 4);
  int* cnt_src  = (int*)alloc((size_t)N * 4);
  int* cnt_dst  = (int*)alloc((size_t)N * 4);
  int* fill_src = (int*)alloc((size_t)N * 4);
  int* fill_dst = (int*)alloc((size_t)N * 4);
  int* bcnt     = (int*)alloc((size_t)NB * 4);
  int* src_off  = (int*)alloc((size_t)(N + 1) * 4);
  int* dst_off  = (int*)alloc((size_t)(N + 1) * 4);
  int* boff     = (int*)alloc((size_t)(NB + 1) * 4);
  int* so_src   = (int*)alloc((size_t)E * 4);
  int* so_eid   = (int*)alloc((size_t)E * 4);
  int* dst_pos  = (int*)alloc((size_t)E * 4);

  // T chunk buffer: whatever space remains
  float* Tbuf = (float*)(ws + off);
  size_t avail = (ws_size > off) ? (ws_size - off) : 0;
  long long chll = (long long)(avail / ((size_t)TCOLS * 4));
  int CH = (chll > N) ? N : (int)chll;
  CH &= ~7;                 // multiple of 8
  if (CH < 8) CH = 8;       // minimal fallback
  int NC = (N + CH - 1) / CH;

  int eavg = E / NC + 1;
  int blocksA = (eavg + 7) / 8 + 64;
  if (blocksA > 4096) blocksA = 4096;

  // zero the state / counter regions (covers alignment gaps too)
  hipMemsetAsync(q_star, 0, (size_t)((char*)(ccb + NB * 32) - (char*)q_star), stream);
  hipMemsetAsync(cnt_src, 0, (size_t)((char*)(bcnt + NB) - (char*)cnt_src), stream);

  kBuildM<<<(32 * TCOLS + 255) / 256, 256, 0, stream>>>(mlp_w2, mlp_b2, Mmat);
  kLin0<<<(N * 32 + 255) / 256, 256, 0, stream>>>(x, lin0_w, lin0_b, feat0, N);
  kCount<<<(E + 255) / 256, 256, 0, stream>>>(ei, cnt_src, cnt_dst, E);
  kBatchCount<<<(N + 255) / 256, 256, 0, stream>>>(batch, bcnt, N);
  kScan<<<3, 256, 0, stream>>>(cnt_src, cnt_dst, bcnt, src_off, dst_off, boff, deg, N, NB);
  kFill<<<(E + 255) / 256, 256, 0, stream>>>(ei, src_off, dst_off, fill_src, fill_dst,
                                             so_src, so_eid, dst_pos, E);

  float* fcur = feat0;
  float* fnext = feat1;
  for (int t = 0; t < 3; t++){
    for (int c = 0; c < NC; c++){
      int c0 = c * CH;
      int c1 = (c0 + CH < N) ? (c0 + CH) : N;
      kT<<<(c1 - c0 + 31) / 32, 256, 0, stream>>>(fcur, Mmat, Tbuf, c0, c1);
      kA<<<blocksA, 256, 0, stream>>>(Tbuf, so_src, so_eid, eattr, mlp_w1, mlp_b1,
                                      src_off, msg, c0, c1);
    }
    kB<<<(N + 7) / 8, 256, 0, stream>>>(msg, dst_off, dst_pos, deg, fcur, fnext,
                                        gru_wih, gru_whh, gru_bih, gru_bhh, conv_b, N);
    float* tmp = fcur; fcur = fnext; fnext = tmp;
  }

  kCopy<<<(N * D + 255) / 256, 256, 0, stream>>>(fcur, (float*)d_out + NB * 64, N * D);

  for (int s = 0; s < 3; s++){
    kLSTM<<<8, 256, 0, stream>>>(lstm_wih, lstm_whh, lstm_bih, lstm_bhh, q_star, hhb, ccb);
    kPool<<<NB, 256, 0, stream>>>(fcur, boff, hhb, q_star, e_buf);
  }

  kCopy<<<(NB * 64 + 255) / 256, 256, 0, stream>>>(q_star, (float*)d_out, NB * 64);
}

// Round 3
// 1742.012 us; speedup vs baseline: 1.2481x; 1.2481x over previous
//
#include <hip/hip_runtime.h>

#define NFEAT 16
#define D 32
#define EH 64
#define NB 64        // num graphs
#define TCOLS 2080   // 65*32: h=0..63 from w2, h=64 row from b2

static inline size_t align_up(size_t x, size_t a){ return (x + a - 1) & ~(a - 1); }

// ---------- setup kernels ----------

// M[i][col], col = h*32+o : M[i][h*32+o] = w2[h][i*32+o] (h<64), = b2[i*32+o] (h==64)
__global__ __launch_bounds__(256) void kBuildM(const float* __restrict__ w2,
                                               const float* __restrict__ b2,
                                               float* __restrict__ M){
  int idx = blockIdx.x * 256 + threadIdx.x;
  if (idx >= 32 * TCOLS) return;
  int i = idx / TCOLS, col = idx % TCOLS;
  int h = col >> 5, o = col & 31;
  M[idx] = (h < 64) ? w2[h * 1024 + i * 32 + o] : b2[i * 32 + o];
}

__global__ __launch_bounds__(256) void kLin0(const float* __restrict__ x,
                                             const float* __restrict__ w,
                                             const float* __restrict__ b,
                                             float* __restrict__ feat, int N){
  int idx = blockIdx.x * 256 + threadIdx.x;
  int u = idx >> 5, o = idx & 31;
  if (u >= N) return;
  float acc = b[o];
#pragma unroll
  for (int i = 0; i < NFEAT; i++) acc += x[(size_t)u * NFEAT + i] * w[i * 32 + o];
  feat[idx] = fmaxf(acc, 0.f);
}

__global__ __launch_bounds__(256) void kCount(const int* __restrict__ ei,
                                              int* cnt_src, int* cnt_dst, int E){
  int e = blockIdx.x * 256 + threadIdx.x;
  if (e >= E) return;
  atomicAdd(&cnt_src[ei[e]], 1);
  atomicAdd(&cnt_dst[ei[E + e]], 1);
}

__global__ __launch_bounds__(256) void kBatchCount(const int* __restrict__ batch,
                                                   int* bc, int N){
  int i = blockIdx.x * 256 + threadIdx.x;
  if (i >= N) return;
  atomicAdd(&bc[batch[i]], 1);
}

// exclusive scan; blockIdx 0: src, 1: dst (+deg), 2: batch
__global__ __launch_bounds__(256) void kScan(const int* __restrict__ cnt_src,
                                             const int* __restrict__ cnt_dst,
                                             const int* __restrict__ bcnt,
                                             int* src_off, int* dst_off, int* boff,
                                             float* deg, int N, int B){
  __shared__ int part[256];
  const int* cnt; int* off; int n;
  if (blockIdx.x == 0)      { cnt = cnt_src; off = src_off; n = N; }
  else if (blockIdx.x == 1) { cnt = cnt_dst; off = dst_off; n = N; }
  else                      { cnt = bcnt;    off = boff;    n = B; }
  int t = threadIdx.x;
  int chunk = (n + 255) / 256;
  int lo = t * chunk, hi = min(n, lo + chunk);
  int s = 0;
  for (int i = lo; i < hi; i++) s += cnt[i];
  part[t] = s; __syncthreads();
  for (int d = 1; d < 256; d <<= 1){
    int v = (t >= d) ? part[t - d] : 0;
    __syncthreads();
    part[t] += v;
    __syncthreads();
  }
  int run = (t == 0) ? 0 : part[t - 1];
  for (int i = lo; i < hi; i++){ off[i] = run; run += cnt[i]; }
  if (t == 255) off[n] = part[255];
  if (blockIdx.x == 1){
    for (int i = lo; i < hi; i++) deg[i] = (float)max(cnt[i], 1);
  }
}

__global__ __launch_bounds__(256) void kFill(const int* __restrict__ ei,
                                             const int* __restrict__ src_off,
                                             const int* __restrict__ dst_off,
                                             int* fill_src, int* fill_dst,
                                             int* so_src, int* so_eid, int* s2d, int E){
  int e = blockIdx.x * 256 + threadIdx.x;
  if (e >= E) return;
  int s = ei[e], d = ei[E + e];
  int ps = src_off[s] + atomicAdd(&fill_src[s], 1);
  so_src[ps] = s;
  so_eid[ps] = e;
  int pd = dst_off[d] + atomicAdd(&fill_dst[d], 1);
  s2d[ps] = pd;
}

// ---------- per-iteration kernels ----------

// T = feat @ M for node chunk [c0,c1): [CH,32] x [32,2080]
// grid.x = node tiles of 32, grid.y = 17 col-chunks of 128
__global__ __launch_bounds__(256) void kT(const float* __restrict__ feat,
                                          const float* __restrict__ M,
                                          float* __restrict__ T, int c0, int c1){
  __shared__ __attribute__((aligned(16))) float fT[32][32];   // fT[i][n]
  __shared__ __attribute__((aligned(16))) float Ml[32][128];
  int tid = threadIdx.x;
  int base = c0 + blockIdx.x * 32;
  int cbase = blockIdx.y * 128;
  for (int k = tid; k < 1024; k += 256){
    int n = k >> 5, i = k & 31;
    int u = base + n;
    fT[i][n] = (u < c1) ? feat[(size_t)u * 32 + i] : 0.f;
  }
  for (int k = tid; k < 4096; k += 256){
    int row = k >> 7, cm = k & 127;
    int col = cbase + cm;
    Ml[row][cm] = (col < TCOLS) ? M[row * TCOLS + col] : 0.f;
  }
  __syncthreads();
  int wid = tid >> 6, lane = tid & 63;
  int r = lane >> 3, c = lane & 7;
  int col0 = cbase + wid * 32 + c * 4;
  if (col0 >= TCOLS) return;
  float4 a0 = {0,0,0,0}, a1 = {0,0,0,0}, a2 = {0,0,0,0}, a3 = {0,0,0,0};
#pragma unroll
  for (int i = 0; i < 32; i++){
    float4 f = *(const float4*)&fT[i][r * 4];
    float4 m = *(const float4*)&Ml[i][wid * 32 + c * 4];
    a0.x += f.x * m.x; a0.y += f.x * m.y; a0.z += f.x * m.z; a0.w += f.x * m.w;
    a1.x += f.y * m.x; a1.y += f.y * m.y; a1.z += f.y * m.z; a1.w += f.y * m.w;
    a2.x += f.z * m.x; a2.y += f.z * m.y; a2.z += f.z * m.z; a2.w += f.z * m.w;
    a3.x += f.w * m.x; a3.y += f.w * m.y; a3.z += f.w * m.z; a3.w += f.w * m.w;
  }
  int u0 = base + r * 4;
  if (u0 + 0 < c1) *(float4*)&T[(size_t)(u0 + 0 - c0) * TCOLS + col0] = a0;
  if (u0 + 1 < c1) *(float4*)&T[(size_t)(u0 + 1 - c0) * TCOLS + col0] = a1;
  if (u0 + 2 < c1) *(float4*)&T[(size_t)(u0 + 2 - c0) * TCOLS + col0] = a2;
  if (u0 + 3 < c1) *(float4*)&T[(size_t)(u0 + 3 - c0) * TCOLS + col0] = a3;
}

// msg[s2d[j]][o] = sum_h a_j[h] * T[src(j)-c0][h*32+o] + T[src(j)-c0][2048+o]
// a_j computed on the fly from edge_attr; block handles 8 contiguous edges of
// the chunk's src-CSR edge range [src_off[c0], src_off[c1]).
__global__ __launch_bounds__(256) void kA(const float* __restrict__ T,
                                          const int* __restrict__ so_src,
                                          const int* __restrict__ so_eid,
                                          const int* __restrict__ s2d,
                                          const float* __restrict__ ea,
                                          const float* __restrict__ w1,
                                          const float* __restrict__ b1,
                                          const int* __restrict__ src_off,
                                          float* __restrict__ msg,
                                          int c0, int c1){
  __shared__ float alds[8][64];
  int tid = threadIdx.x;
  long long e0 = src_off[c0];
  long long e1 = src_off[c1];
  long long jb = e0 + (long long)blockIdx.x * 8;
  if (jb >= e1) return;
  // phase 1: edge MLP for up to 8 edges (64 threads per edge, one h each)
  for (int k = tid; k < 512; k += 256){
    int jj = k >> 6, h = k & 63;
    long long j = jb + jj;
    if (j < e1){
      int e = so_eid[j];
      float acc = b1[h];
#pragma unroll
      for (int q = 0; q < 5; q++) acc += ea[(size_t)e * 5 + q] * w1[q * 64 + h];
      alds[jj][h] = fmaxf(acc, 0.f);
    }
  }
  __syncthreads();
  // phase 2: contraction against T row of the source node
  int jj = tid >> 5, o = tid & 31;
  long long j = jb + jj;
  if (j >= e1) return;
  int u = so_src[j];
  const float* Tr = T + (size_t)(u - c0) * TCOLS;
  float acc = Tr[2048 + o];
#pragma unroll 8
  for (int h = 0; h < 64; h++) acc += alds[jj][h] * Tr[h * 32 + o];
  msg[(size_t)s2d[j] * 32 + o] = acc;
}

// aggregate msg (dst-ordered) + conv bias + relu + GRU step, 8 nodes/block
__global__ __launch_bounds__(256) void kB(const float* __restrict__ msg,
                                          const int* __restrict__ dst_off,
                                          const float* __restrict__ deg,
                                          const float* __restrict__ feat_in,
                                          float* __restrict__ feat_out,
                                          const float* __restrict__ Wih,
                                          const float* __restrict__ Whh,
                                          const float* __restrict__ bih,
                                          const float* __restrict__ bhh,
                                          const float* __restrict__ cbias, int N){
  __shared__ float wih[96][33], whh[96][33];
  __shared__ float bi[96], bh[96], cb[32];
  __shared__ float msh[8][33], hsh[8][33];
  int tid = threadIdx.x;
  for (int k = tid; k < 96 * 32; k += 256){
    int g = k >> 5, o = k & 31;
    wih[g][o] = Wih[k];
    whh[g][o] = Whh[k];
  }
  if (tid < 96){ bi[tid] = bih[tid]; bh[tid] = bhh[tid]; }
  if (tid < 32) cb[tid] = cbias[tid];
  __syncthreads();
  int s = tid >> 5, o = tid & 31;
  int v = blockIdx.x * 8 + s;
  if (v >= N) return;
  int lo = dst_off[v], hi = dst_off[v + 1];
  float acc = 0.f;
  for (int k = lo; k < hi; k++){
    acc += msg[(size_t)k * 32 + o];
  }
  float m = fmaxf(acc / deg[v] + cb[o], 0.f);
  float h = feat_in[(size_t)v * 32 + o];
  msh[s][o] = m;
  hsh[s][o] = h;
  float gr = bi[o], gz = bi[32 + o], gn = bi[64 + o];
  float hr = bh[o], hz = bh[32 + o], hn = bh[64 + o];
#pragma unroll
  for (int q = 0; q < 32; q++){
    float mq = msh[s][q], hq = hsh[s][q];
    gr += mq * wih[o][q];      gz += mq * wih[32 + o][q];  gn += mq * wih[64 + o][q];
    hr += hq * whh[o][q];      hz += hq * whh[32 + o][q];  hn += hq * whh[64 + o][q];
  }
  float r = 1.f / (1.f + expf(-(gr + hr)));
  float z = 1.f / (1.f + expf(-(gz + hz)));
  float n = tanhf(gn + r * hn);
  feat_out[(size_t)v * 32 + o] = (1.f - z) * n + z * h;
}

// ---------- Set2Set ----------

__global__ __launch_bounds__(256) void kLSTM(const float* __restrict__ Wih,
                                             const float* __restrict__ Whh,
                                             const float* __restrict__ bih,
                                             const float* __restrict__ bhh,
                                             float* __restrict__ q_star,
                                             float* __restrict__ hh,
                                             float* __restrict__ cc){
  __shared__ float WihT[64][129];
  __shared__ float WhhT[32][129];
  __shared__ float qs[8][65];
  __shared__ float hl[8][33];
  __shared__ float gates[8][129];
  int tid = threadIdx.x;
  int rbase = blockIdx.x * 8;
  for (int k = tid; k < 128 * 64; k += 256){ int j = k & 63, g = k >> 6; WihT[j][g] = Wih[g * 64 + j]; }
  for (int k = tid; k < 128 * 32; k += 256){ int j = k & 31, g = k >> 5; WhhT[j][g] = Whh[g * 32 + j]; }
  for (int k = tid; k < 512; k += 256){ int rr = k >> 6, j = k & 63; qs[rr][j] = q_star[(rbase + rr) * 64 + j]; }
  { int rr = tid >> 5, j = tid & 31; hl[rr][j] = hh[(rbase + rr) * 32 + j]; }
  __syncthreads();
  for (int k = tid; k < 1024; k += 256){
    int rr = k >> 7, g = k & 127;
    float acc = bih[g] + bhh[g];
#pragma unroll 8
    for (int j = 0; j < 64; j++) acc += qs[rr][j] * WihT[j][g];
#pragma unroll 8
    for (int j = 0; j < 32; j++) acc += hl[rr][j] * WhhT[j][g];
    gates[rr][g] = acc;
  }
  __syncthreads();
  {
    int rr = tid >> 5, j = tid & 31;
    int row = rbase + rr;
    float iv = gates[rr][j], fv = gates[rr][32 + j], gv = gates[rr][64 + j], ov = gates[rr][96 + j];
    iv = 1.f / (1.f + expf(-iv));
    fv = 1.f / (1.f + expf(-fv));
    gv = tanhf(gv);
    ov = 1.f / (1.f + expf(-ov));
    float c = fv * cc[row * 32 + j] + iv * gv;
    cc[row * 32 + j] = c;
    float hv = ov * tanhf(c);
    hh[row * 32 + j] = hv;
    q_star[row * 64 + j] = hv;
  }
}

// one block per graph: attention softmax + weighted pool
__global__ __launch_bounds__(256) void kPool(const float* __restrict__ feat,
                                             const int* __restrict__ boff,
                                             const float* __restrict__ hh,
                                             float* __restrict__ q_star,
                                             float* __restrict__ e_buf){
  int b = blockIdx.x;
  int lo = boff[b], hi = boff[b + 1];
  __shared__ float q[32];
  __shared__ float wred[4];
  __shared__ float part[8][33];
  int tid = threadIdx.x;
  if (tid < 32) q[tid] = hh[b * 32 + tid];
  __syncthreads();
  int sub = tid >> 5, o = tid & 31;
  float mx = -1e30f;
  for (int i = lo + sub; i < hi; i += 8){
    float v = feat[(size_t)i * 32 + o] * q[o];
#pragma unroll
    for (int d = 16; d; d >>= 1) v += __shfl_xor(v, d, 32);
    if (o == 0) e_buf[i] = v;
    mx = fmaxf(mx, v);
  }
#pragma unroll
  for (int d = 32; d; d >>= 1) mx = fmaxf(mx, __shfl_xor(mx, d, 64));
  if ((tid & 63) == 0) wred[tid >> 6] = mx;
  __syncthreads();
  mx = fmaxf(fmaxf(wred[0], wred[1]), fmaxf(wred[2], wred[3]));
  __syncthreads();
  float sm = 0.f;
  for (int i = lo + tid; i < hi; i += 256){
    float w = expf(e_buf[i] - mx);
    e_buf[i] = w;
    sm += w;
  }
#pragma unroll
  for (int d = 32; d; d >>= 1) sm += __shfl_xor(sm, d, 64);
  if ((tid & 63) == 0) wred[tid >> 6] = sm;
  __syncthreads();
  float denom = wred[0] + wred[1] + wred[2] + wred[3];
  denom = fmaxf(denom, 1e-30f);
  __syncthreads();
  float acc = 0.f;
  for (int i = lo + sub; i < hi; i += 8){
    acc += e_buf[i] * feat[(size_t)i * 32 + o];
  }
  part[sub][o] = acc;
  __syncthreads();
  if (tid < 32){
    float r = 0.f;
#pragma unroll
    for (int s2 = 0; s2 < 8; s2++) r += part[s2][tid];
    q_star[b * 64 + 32 + tid] = r / denom;
  }
}

__global__ __launch_bounds__(256) void kCopy(const float* __restrict__ src,
                                             float* __restrict__ dst, int n){
  int i = blockIdx.x * 256 + threadIdx.x;
  if (i < n) dst[i] = src[i];
}

// ---------- host ----------

extern "C" void kernel_launch(void* const* d_in, const int* in_sizes, int n_in,
                              void* d_out, int out_size, void* d_ws, size_t ws_size,
                              hipStream_t stream){
  (void)n_in; (void)out_size;
  const float* x        = (const float*)d_in[0];
  const int*   ei       = (const int*)  d_in[1];
  const float* eattr    = (const float*)d_in[2];
  const int*   batch    = (const int*)  d_in[3];
  const float* lin0_w   = (const float*)d_in[4];
  const float* lin0_b   = (const float*)d_in[5];
  const float* mlp_w1   = (const float*)d_in[6];
  const float* mlp_b1   = (const float*)d_in[7];
  const float* mlp_w2   = (const float*)d_in[8];
  const float* mlp_b2   = (const float*)d_in[9];
  const float* conv_b   = (const float*)d_in[10];
  const float* gru_wih  = (const float*)d_in[11];
  const float* gru_whh  = (const float*)d_in[12];
  const float* gru_bih  = (const float*)d_in[13];
  const float* gru_bhh  = (const float*)d_in[14];
  const float* lstm_wih = (const float*)d_in[15];
  const float* lstm_whh = (const float*)d_in[16];
  const float* lstm_bih = (const float*)d_in[17];
  const float* lstm_bhh = (const float*)d_in[18];

  int N = in_sizes[0] / NFEAT;
  int E = in_sizes[1] / 2;

  char* ws = (char*)d_ws;
  size_t off = 0;
  auto alloc = [&](size_t bytes) -> char* {
    char* p = ws + off;
    off = align_up(off + bytes, 256);
    return p;
  };

  // fixed-size buffers first; T gets the remainder (chunked if needed)
  float* feat0  = (float*)alloc((size_t)N * D * 4);
  float* feat1  = (float*)alloc((size_t)N * D * 4);
  float* msg    = (float*)alloc((size_t)E * D * 4);
  float* Mmat   = (float*)alloc((size_t)32 * TCOLS * 4);
  float* e_buf  = (float*)alloc((size_t)N * 4);
  float* deg    = (float*)alloc((size_t)N * 4);
  float* q_star = (float*)alloc((size_t)NB * 64 * 4);
  float* hhb    = (float*)alloc((size_t)NB * 32 * 4);
  float* ccb    = (float*)alloc((size_t)NB * 32 * 4);
  int* cnt_src  = (int*)alloc((size_t)N * 4);
  int* cnt_dst  = (int*)alloc((size_t)N * 4);
  int* fill_src = (int*)alloc((size_t)N * 4);
  int* fill_dst = (int*)alloc((size_t)N * 4);
  int* bcnt     = (int*)alloc((size_t)NB * 4);
  int* src_off  = (int*)alloc((size_t)(N + 1) * 4);
  int* dst_off  = (int*)alloc((size_t)(N + 1) * 4);
  int* boff     = (int*)alloc((size_t)(NB + 1) * 4);
  int* so_src   = (int*)alloc((size_t)E * 4);
  int* so_eid   = (int*)alloc((size_t)E * 4);
  int* s2d      = (int*)alloc((size_t)E * 4);

  // T chunk buffer: whatever space remains
  float* Tbuf = (float*)(ws + off);
  size_t avail = (ws_size > off) ? (ws_size - off) : 0;
  long long chll = (long long)(avail / ((size_t)TCOLS * 4));
  int CH = (chll > N) ? N : (int)chll;
  CH &= ~7;                 // multiple of 8
  if (CH < 8) CH = 8;       // minimal fallback
  int NC = (N + CH - 1) / CH;

  int blocksA = (E + 7) / 8 + 1;   // covers worst-case chunk; extra blocks exit fast

  // zero the state / counter regions (covers alignment gaps too)
  hipMemsetAsync(q_star, 0, (size_t)((char*)(ccb + NB * 32) - (char*)q_star), stream);
  hipMemsetAsync(cnt_src, 0, (size_t)((char*)(bcnt + NB) - (char*)cnt_src), stream);

  kBuildM<<<(32 * TCOLS + 255) / 256, 256, 0, stream>>>(mlp_w2, mlp_b2, Mmat);
  kLin0<<<(N * 32 + 255) / 256, 256, 0, stream>>>(x, lin0_w, lin0_b, feat0, N);
  kCount<<<(E + 255) / 256, 256, 0, stream>>>(ei, cnt_src, cnt_dst, E);
  kBatchCount<<<(N + 255) / 256, 256, 0, stream>>>(batch, bcnt, N);
  kScan<<<3, 256, 0, stream>>>(cnt_src, cnt_dst, bcnt, src_off, dst_off, boff, deg, N, NB);
  kFill<<<(E + 255) / 256, 256, 0, stream>>>(ei, src_off, dst_off, fill_src, fill_dst,
                                             so_src, so_eid, s2d, E);

  float* fcur = feat0;
  float* fnext = feat1;
  for (int t = 0; t < 3; t++){
    for (int c = 0; c < NC; c++){
      int c0 = c * CH;
      int c1 = (c0 + CH < N) ? (c0 + CH) : N;
      dim3 gT((c1 - c0 + 31) / 32, 17);
      kT<<<gT, 256, 0, stream>>>(fcur, Mmat, Tbuf, c0, c1);
      kA<<<blocksA, 256, 0, stream>>>(Tbuf, so_src, so_eid, s2d, eattr, mlp_w1, mlp_b1,
                                      src_off, msg, c0, c1);
    }
    kB<<<(N + 7) / 8, 256, 0, stream>>>(msg, dst_off, deg, fcur, fnext,
                                        gru_wih, gru_whh, gru_bih, gru_bhh, conv_b, N);
    float* tmp = fcur; fcur = fnext; fnext = tmp;
  }

  kCopy<<<(N * D + 255) / 256, 256, 0, stream>>>(fcur, (float*)d_out + NB * 64, N * D);

  for (int s = 0; s < 3; s++){
    kLSTM<<<8, 256, 0, stream>>>(lstm_wih, lstm_whh, lstm_bih, lstm_bhh, q_star, hhb, ccb);
    kPool<<<NB, 256, 0, stream>>>(fcur, boff, hhb, q_star, e_buf);
  }

  kCopy<<<(NB * 64 + 255) / 256, 256, 0, stream>>>(q_star, (float*)d_out, NB * 64);
}

// Round 4
// 920.857 us; speedup vs baseline: 2.3610x; 1.8917x over previous
//
#include <hip/hip_runtime.h>

#define NFEAT 16
#define D 32
#define EH 64
#define NB 64        // num graphs
#define TCOLS 2080   // 65*32: h=0..63 from w2, h=64 row from b2
#define CHUNK 4      // nodes per fused block

static inline size_t align_up(size_t x, size_t a){ return (x + a - 1) & ~(a - 1); }

// ---------- setup kernels ----------

// M[i][col], col = h*32+o : M[i][h*32+o] = w2[h][i*32+o] (h<64), = b2[i*32+o] (h==64)
__global__ __launch_bounds__(256) void kBuildM(const float* __restrict__ w2,
                                               const float* __restrict__ b2,
                                               float* __restrict__ M){
  int idx = blockIdx.x * 256 + threadIdx.x;
  if (idx >= 32 * TCOLS) return;
  int i = idx / TCOLS, col = idx % TCOLS;
  int h = col >> 5, o = col & 31;
  M[idx] = (h < 64) ? w2[h * 1024 + i * 32 + o] : b2[i * 32 + o];
}

__global__ __launch_bounds__(256) void kLin0(const float* __restrict__ x,
                                             const float* __restrict__ w,
                                             const float* __restrict__ b,
                                             float* __restrict__ feat, int N){
  int idx = blockIdx.x * 256 + threadIdx.x;
  int u = idx >> 5, o = idx & 31;
  if (u >= N) return;
  float acc = b[o];
#pragma unroll
  for (int i = 0; i < NFEAT; i++) acc += x[(size_t)u * NFEAT + i] * w[i * 32 + o];
  feat[idx] = fmaxf(acc, 0.f);
}

__global__ __launch_bounds__(256) void kCount(const int* __restrict__ ei,
                                              int* cnt_src, int* cnt_dst, int E){
  int e = blockIdx.x * 256 + threadIdx.x;
  if (e >= E) return;
  atomicAdd(&cnt_src[ei[e]], 1);
  atomicAdd(&cnt_dst[ei[E + e]], 1);
}

__global__ __launch_bounds__(256) void kBatchCount(const int* __restrict__ batch,
                                                   int* bc, int N){
  int i = blockIdx.x * 256 + threadIdx.x;
  if (i >= N) return;
  atomicAdd(&bc[batch[i]], 1);
}

// exclusive scan; blockIdx 0: src, 1: dst (+deg), 2: batch
__global__ __launch_bounds__(256) void kScan(const int* __restrict__ cnt_src,
                                             const int* __restrict__ cnt_dst,
                                             const int* __restrict__ bcnt,
                                             int* src_off, int* dst_off, int* boff,
                                             float* deg, int N, int B){
  __shared__ int part[256];
  const int* cnt; int* off; int n;
  if (blockIdx.x == 0)      { cnt = cnt_src; off = src_off; n = N; }
  else if (blockIdx.x == 1) { cnt = cnt_dst; off = dst_off; n = N; }
  else                      { cnt = bcnt;    off = boff;    n = B; }
  int t = threadIdx.x;
  int chunk = (n + 255) / 256;
  int lo = t * chunk, hi = min(n, lo + chunk);
  int s = 0;
  for (int i = lo; i < hi; i++) s += cnt[i];
  part[t] = s; __syncthreads();
  for (int d = 1; d < 256; d <<= 1){
    int v = (t >= d) ? part[t - d] : 0;
    __syncthreads();
    part[t] += v;
    __syncthreads();
  }
  int run = (t == 0) ? 0 : part[t - 1];
  for (int i = lo; i < hi; i++){ off[i] = run; run += cnt[i]; }
  if (t == 255) off[n] = part[255];
  if (blockIdx.x == 1){
    for (int i = lo; i < hi; i++) deg[i] = (float)max(cnt[i], 1);
  }
}

__global__ __launch_bounds__(256) void kFill(const int* __restrict__ ei,
                                             const int* __restrict__ src_off,
                                             const int* __restrict__ dst_off,
                                             int* fill_src, int* fill_dst,
                                             int* so_src, int* so_eid, int* s2d, int E){
  int e = blockIdx.x * 256 + threadIdx.x;
  if (e >= E) return;
  int s = ei[e], d = ei[E + e];
  int ps = src_off[s] + atomicAdd(&fill_src[s], 1);
  so_src[ps] = s;
  so_eid[ps] = e;
  int pd = dst_off[d] + atomicAdd(&fill_dst[d], 1);
  s2d[ps] = pd;
}

// ---------- fused per-iteration kernel ----------
// Per block: 4 nodes. Phase A: T[4][2080] = feat_chunk @ M into LDS
// (h4-XOR-swizzled for conflict-free b128 reads). Phase B: each wave
// independently processes 2 edges/round from the chunk's contiguous src-CSR
// range: edge MLP on the fly, contract a_j (64) against T row, scatter msg
// to dst-CSR position.
__global__ __launch_bounds__(256) void kTA(const float* __restrict__ feat,
                                           const float* __restrict__ M,
                                           const int* __restrict__ so_src,
                                           const int* __restrict__ so_eid,
                                           const int* __restrict__ s2d,
                                           const float* __restrict__ ea,
                                           const float* __restrict__ w1,
                                           const float* __restrict__ b1,
                                           const int* __restrict__ src_off,
                                           float* __restrict__ msg,
                                           int N){
  __shared__ float fT[CHUNK][32];          // feat rows
  __shared__ float Tl[CHUNK * 32 * 64];    // (n,o) row of 64 h, h4 ^ (o&7) swizzle
  __shared__ float bias_l[CHUNK][32];      // h==64 (bias) column
  __shared__ float al[4][2][64];           // per-wave a values (2 edges)
  __shared__ float w1l[320];
  __shared__ float b1l[64];
  int tid = threadIdx.x;
  int c0 = blockIdx.x * CHUNK;
  int c1 = min(c0 + CHUNK, N);
  if (tid < CHUNK * 32){
    int n = tid >> 5, i = tid & 31;
    fT[n][i] = (c0 + n < c1) ? feat[(size_t)(c0 + n) * 32 + i] : 0.f;
  }
  for (int k = tid; k < 320; k += 256) w1l[k] = w1[k];
  if (tid < 64) b1l[tid] = b1[tid];
  __syncthreads();

  // ---- phase A: T = fT @ M ----
  for (int c4 = tid; c4 < 520; c4 += 256){
    int col0 = c4 * 4;
    int h = col0 >> 5;          // 0..64, same for all 4 cols
    int o0 = col0 & 31;
    float ax[CHUNK], ay[CHUNK], az[CHUNK], aw[CHUNK];
#pragma unroll
    for (int n = 0; n < CHUNK; n++){ ax[n] = 0.f; ay[n] = 0.f; az[n] = 0.f; aw[n] = 0.f; }
    const float* Mp = M + col0;
#pragma unroll 4
    for (int i = 0; i < 32; i++){
      float4 m = *(const float4*)(Mp + (size_t)i * TCOLS);
#pragma unroll
      for (int n = 0; n < CHUNK; n++){
        float f = fT[n][i];
        ax[n] += f * m.x; ay[n] += f * m.y; az[n] += f * m.z; aw[n] += f * m.w;
      }
    }
    if (h == 64){
#pragma unroll
      for (int n = 0; n < CHUNK; n++){
        bias_l[n][o0 + 0] = ax[n]; bias_l[n][o0 + 1] = ay[n];
        bias_l[n][o0 + 2] = az[n]; bias_l[n][o0 + 3] = aw[n];
      }
    } else {
      int h4 = h >> 2, hr = h & 3;
#pragma unroll
      for (int n = 0; n < CHUNK; n++){
        float v0 = ax[n], v1 = ay[n], v2 = az[n], v3 = aw[n];
#pragma unroll
        for (int k = 0; k < 4; k++){
          int o = o0 + k;
          int ph4 = h4 ^ (o & 7);
          float vv = (k == 0) ? v0 : (k == 1) ? v1 : (k == 2) ? v2 : v3;
          Tl[((n * 32 + o) << 6) + (ph4 << 2) + hr] = vv;
        }
      }
    }
  }
  __syncthreads();

  // ---- phase B: per-wave edge processing ----
  int w = tid >> 6, l = tid & 63;
  int jj = l >> 5, o = l & 31;
  int e0 = src_off[c0], e1 = src_off[c1];
  for (int jb = e0 + w * 2; jb < e1; jb += 8){
    int j = jb + jj;
    bool valid = (j < e1);
    int u = 0, dpos = 0;
    if (valid){
      int e = so_eid[j];
      const float* eap = ea + (size_t)e * 5;
      float q0 = eap[0], q1 = eap[1], q2 = eap[2], q3 = eap[3], q4 = eap[4];
      float alo = b1l[o]      + q0 * w1l[o]      + q1 * w1l[64 + o]  + q2 * w1l[128 + o]
                              + q3 * w1l[192 + o] + q4 * w1l[256 + o];
      float ahi = b1l[32 + o] + q0 * w1l[32 + o] + q1 * w1l[96 + o]  + q2 * w1l[160 + o]
                              + q3 * w1l[224 + o] + q4 * w1l[288 + o];
      al[w][jj][o]      = fmaxf(alo, 0.f);
      al[w][jj][o + 32] = fmaxf(ahi, 0.f);
      u = so_src[j] - c0;
      dpos = s2d[j];
    }
    __builtin_amdgcn_wave_barrier();
    if (valid){
      float acc = bias_l[u][o];
      const float* Tr = &Tl[(u * 32 + o) << 6];
      const float* ap = &al[w][jj][0];
      int om = o & 7;
#pragma unroll
      for (int g = 0; g < 16; g++){
        float4 av = *(const float4*)(ap + (g << 2));
        float4 tv = *(const float4*)(Tr + ((g ^ om) << 2));
        acc += av.x * tv.x + av.y * tv.y + av.z * tv.z + av.w * tv.w;
      }
      msg[(size_t)dpos * 32 + o] = acc;
    }
    __builtin_amdgcn_wave_barrier();
  }
}

// aggregate msg (dst-ordered) + conv bias + relu + GRU step, 8 nodes/block
__global__ __launch_bounds__(256) void kB(const float* __restrict__ msg,
                                          const int* __restrict__ dst_off,
                                          const float* __restrict__ deg,
                                          const float* __restrict__ feat_in,
                                          float* __restrict__ feat_out,
                                          const float* __restrict__ Wih,
                                          const float* __restrict__ Whh,
                                          const float* __restrict__ bih,
                                          const float* __restrict__ bhh,
                                          const float* __restrict__ cbias, int N){
  __shared__ float wih[96][33], whh[96][33];
  __shared__ float bi[96], bh[96], cb[32];
  __shared__ float msh[8][33], hsh[8][33];
  int tid = threadIdx.x;
  for (int k = tid; k < 96 * 32; k += 256){
    int g = k >> 5, o = k & 31;
    wih[g][o] = Wih[k];
    whh[g][o] = Whh[k];
  }
  if (tid < 96){ bi[tid] = bih[tid]; bh[tid] = bhh[tid]; }
  if (tid < 32) cb[tid] = cbias[tid];
  __syncthreads();
  int s = tid >> 5, o = tid & 31;
  int v = blockIdx.x * 8 + s;
  if (v >= N) return;
  int lo = dst_off[v], hi = dst_off[v + 1];
  float acc = 0.f;
  for (int k = lo; k < hi; k++){
    acc += msg[(size_t)k * 32 + o];
  }
  float m = fmaxf(acc / deg[v] + cb[o], 0.f);
  float h = feat_in[(size_t)v * 32 + o];
  msh[s][o] = m;
  hsh[s][o] = h;
  float gr = bi[o], gz = bi[32 + o], gn = bi[64 + o];
  float hr = bh[o], hz = bh[32 + o], hn = bh[64 + o];
#pragma unroll
  for (int q = 0; q < 32; q++){
    float mq = msh[s][q], hq = hsh[s][q];
    gr += mq * wih[o][q];      gz += mq * wih[32 + o][q];  gn += mq * wih[64 + o][q];
    hr += hq * whh[o][q];      hz += hq * whh[32 + o][q];  hn += hq * whh[64 + o][q];
  }
  float r = 1.f / (1.f + expf(-(gr + hr)));
  float z = 1.f / (1.f + expf(-(gz + hz)));
  float n = tanhf(gn + r * hn);
  feat_out[(size_t)v * 32 + o] = (1.f - z) * n + z * h;
}

// ---------- Set2Set ----------

__global__ __launch_bounds__(256) void kLSTM(const float* __restrict__ Wih,
                                             const float* __restrict__ Whh,
                                             const float* __restrict__ bih,
                                             const float* __restrict__ bhh,
                                             float* __restrict__ q_star,
                                             float* __restrict__ hh,
                                             float* __restrict__ cc){
  __shared__ float WihT[64][129];
  __shared__ float WhhT[32][129];
  __shared__ float qs[8][65];
  __shared__ float hl[8][33];
  __shared__ float gates[8][129];
  int tid = threadIdx.x;
  int rbase = blockIdx.x * 8;
  for (int k = tid; k < 128 * 64; k += 256){ int j = k & 63, g = k >> 6; WihT[j][g] = Wih[g * 64 + j]; }
  for (int k = tid; k < 128 * 32; k += 256){ int j = k & 31, g = k >> 5; WhhT[j][g] = Whh[g * 32 + j]; }
  for (int k = tid; k < 512; k += 256){ int rr = k >> 6, j = k & 63; qs[rr][j] = q_star[(rbase + rr) * 64 + j]; }
  { int rr = tid >> 5, j = tid & 31; hl[rr][j] = hh[(rbase + rr) * 32 + j]; }
  __syncthreads();
  for (int k = tid; k < 1024; k += 256){
    int rr = k >> 7, g = k & 127;
    float acc = bih[g] + bhh[g];
#pragma unroll 8
    for (int j = 0; j < 64; j++) acc += qs[rr][j] * WihT[j][g];
#pragma unroll 8
    for (int j = 0; j < 32; j++) acc += hl[rr][j] * WhhT[j][g];
    gates[rr][g] = acc;
  }
  __syncthreads();
  {
    int rr = tid >> 5, j = tid & 31;
    int row = rbase + rr;
    float iv = gates[rr][j], fv = gates[rr][32 + j], gv = gates[rr][64 + j], ov = gates[rr][96 + j];
    iv = 1.f / (1.f + expf(-iv));
    fv = 1.f / (1.f + expf(-fv));
    gv = tanhf(gv);
    ov = 1.f / (1.f + expf(-ov));
    float c = fv * cc[row * 32 + j] + iv * gv;
    cc[row * 32 + j] = c;
    float hv = ov * tanhf(c);
    hh[row * 32 + j] = hv;
    q_star[row * 64 + j] = hv;
  }
}

// one block per graph: attention softmax + weighted pool
__global__ __launch_bounds__(256) void kPool(const float* __restrict__ feat,
                                             const int* __restrict__ boff,
                                             const float* __restrict__ hh,
                                             float* __restrict__ q_star,
                                             float* __restrict__ e_buf){
  int b = blockIdx.x;
  int lo = boff[b], hi = boff[b + 1];
  __shared__ float q[32];
  __shared__ float wred[4];
  __shared__ float part[8][33];
  int tid = threadIdx.x;
  if (tid < 32) q[tid] = hh[b * 32 + tid];
  __syncthreads();
  int sub = tid >> 5, o = tid & 31;
  float mx = -1e30f;
  for (int i = lo + sub; i < hi; i += 8){
    float v = feat[(size_t)i * 32 + o] * q[o];
#pragma unroll
    for (int d = 16; d; d >>= 1) v += __shfl_xor(v, d, 32);
    if (o == 0) e_buf[i] = v;
    mx = fmaxf(mx, v);
  }
#pragma unroll
  for (int d = 32; d; d >>= 1) mx = fmaxf(mx, __shfl_xor(mx, d, 64));
  if ((tid & 63) == 0) wred[tid >> 6] = mx;
  __syncthreads();
  mx = fmaxf(fmaxf(wred[0], wred[1]), fmaxf(wred[2], wred[3]));
  __syncthreads();
  float sm = 0.f;
  for (int i = lo + tid; i < hi; i += 256){
    float w = expf(e_buf[i] - mx);
    e_buf[i] = w;
    sm += w;
  }
#pragma unroll
  for (int d = 32; d; d >>= 1) sm += __shfl_xor(sm, d, 64);
  if ((tid & 63) == 0) wred[tid >> 6] = sm;
  __syncthreads();
  float denom = wred[0] + wred[1] + wred[2] + wred[3];
  denom = fmaxf(denom, 1e-30f);
  __syncthreads();
  float acc = 0.f;
  for (int i = lo + sub; i < hi; i += 8){
    acc += e_buf[i] * feat[(size_t)i * 32 + o];
  }
  part[sub][o] = acc;
  __syncthreads();
  if (tid < 32){
    float r = 0.f;
#pragma unroll
    for (int s2 = 0; s2 < 8; s2++) r += part[s2][tid];
    q_star[b * 64 + 32 + tid] = r / denom;
  }
}

__global__ __launch_bounds__(256) void kCopy(const float* __restrict__ src,
                                             float* __restrict__ dst, int n){
  int i = blockIdx.x * 256 + threadIdx.x;
  if (i < n) dst[i] = src[i];
}

// ---------- host ----------

extern "C" void kernel_launch(void* const* d_in, const int* in_sizes, int n_in,
                              void* d_out, int out_size, void* d_ws, size_t ws_size,
                              hipStream_t stream){
  (void)n_in; (void)out_size; (void)ws_size;
  const float* x        = (const float*)d_in[0];
  const int*   ei       = (const int*)  d_in[1];
  const float* eattr    = (const float*)d_in[2];
  const int*   batch    = (const int*)  d_in[3];
  const float* lin0_w   = (const float*)d_in[4];
  const float* lin0_b   = (const float*)d_in[5];
  const float* mlp_w1   = (const float*)d_in[6];
  const float* mlp_b1   = (const float*)d_in[7];
  const float* mlp_w2   = (const float*)d_in[8];
  const float* mlp_b2   = (const float*)d_in[9];
  const float* conv_b   = (const float*)d_in[10];
  const float* gru_wih  = (const float*)d_in[11];
  const float* gru_whh  = (const float*)d_in[12];
  const float* gru_bih  = (const float*)d_in[13];
  const float* gru_bhh  = (const float*)d_in[14];
  const float* lstm_wih = (const float*)d_in[15];
  const float* lstm_whh = (const float*)d_in[16];
  const float* lstm_bih = (const float*)d_in[17];
  const float* lstm_bhh = (const float*)d_in[18];

  int N = in_sizes[0] / NFEAT;
  int E = in_sizes[1] / 2;

  char* ws = (char*)d_ws;
  size_t off = 0;
  auto alloc = [&](size_t bytes) -> char* {
    char* p = ws + off;
    off = align_up(off + bytes, 256);
    return p;
  };

  float* feat0  = (float*)alloc((size_t)N * D * 4);
  float* feat1  = (float*)alloc((size_t)N * D * 4);
  float* msg    = (float*)alloc((size_t)E * D * 4);
  float* Mmat   = (float*)alloc((size_t)32 * TCOLS * 4);
  float* e_buf  = (float*)alloc((size_t)N * 4);
  float* deg    = (float*)alloc((size_t)N * 4);
  float* q_star = (float*)alloc((size_t)NB * 64 * 4);
  float* hhb    = (float*)alloc((size_t)NB * 32 * 4);
  float* ccb    = (float*)alloc((size_t)NB * 32 * 4);
  int* cnt_src  = (int*)alloc((size_t)N * 4);
  int* cnt_dst  = (int*)alloc((size_t)N * 4);
  int* fill_src = (int*)alloc((size_t)N * 4);
  int* fill_dst = (int*)alloc((size_t)N * 4);
  int* bcnt     = (int*)alloc((size_t)NB * 4);
  int* src_off  = (int*)alloc((size_t)(N + 1) * 4);
  int* dst_off  = (int*)alloc((size_t)(N + 1) * 4);
  int* boff     = (int*)alloc((size_t)(NB + 1) * 4);
  int* so_src   = (int*)alloc((size_t)E * 4);
  int* so_eid   = (int*)alloc((size_t)E * 4);
  int* s2d      = (int*)alloc((size_t)E * 4);

  // zero the state / counter regions (covers alignment gaps too)
  hipMemsetAsync(q_star, 0, (size_t)((char*)(ccb + NB * 32) - (char*)q_star), stream);
  hipMemsetAsync(cnt_src, 0, (size_t)((char*)(bcnt + NB) - (char*)cnt_src), stream);

  kBuildM<<<(32 * TCOLS + 255) / 256, 256, 0, stream>>>(mlp_w2, mlp_b2, Mmat);
  kLin0<<<(N * 32 + 255) / 256, 256, 0, stream>>>(x, lin0_w, lin0_b, feat0, N);
  kCount<<<(E + 255) / 256, 256, 0, stream>>>(ei, cnt_src, cnt_dst, E);
  kBatchCount<<<(N + 255) / 256, 256, 0, stream>>>(batch, bcnt, N);
  kScan<<<3, 256, 0, stream>>>(cnt_src, cnt_dst, bcnt, src_off, dst_off, boff, deg, N, NB);
  kFill<<<(E + 255) / 256, 256, 0, stream>>>(ei, src_off, dst_off, fill_src, fill_dst,
                                             so_src, so_eid, s2d, E);

  int blocksTA = (N + CHUNK - 1) / CHUNK;
  float* fcur = feat0;
  float* fnext = feat1;
  for (int t = 0; t < 3; t++){
    kTA<<<blocksTA, 256, 0, stream>>>(fcur, Mmat, so_src, so_eid, s2d, eattr,
                                      mlp_w1, mlp_b1, src_off, msg, N);
    kB<<<(N + 7) / 8, 256, 0, stream>>>(msg, dst_off, deg, fcur, fnext,
                                        gru_wih, gru_whh, gru_bih, gru_bhh, conv_b, N);
    float* tmp = fcur; fcur = fnext; fnext = tmp;
  }

  kCopy<<<(N * D + 255) / 256, 256, 0, stream>>>(fcur, (float*)d_out + NB * 64, N * D);

  for (int s = 0; s < 3; s++){
    kLSTM<<<8, 256, 0, stream>>>(lstm_wih, lstm_whh, lstm_bih, lstm_bhh, q_star, hhb, ccb);
    kPool<<<NB, 256, 0, stream>>>(fcur, boff, hhb, q_star, e_buf);
  }

  kCopy<<<(NB * 64 + 255) / 256, 256, 0, stream>>>(q_star, (float*)d_out, NB * 64);
}

// Round 6
// 767.401 us; speedup vs baseline: 2.8332x; 1.2000x over previous
//
#include <hip/hip_runtime.h>
#include <hip/hip_fp16.h>

#define NFEAT 16
#define D 32
#define NB 64        // num graphs
#define TCOLS 2080   // 65*32: h=0..63 from w2, h=64 row from b2
#define CHUNK 8      // nodes per fused block
#define TROW 34      // u32 per (node,o) LDS row (64 f16 + 2 pad) -> conflict-free b64

static inline size_t align_up(size_t x, size_t a){ return (x + a - 1) & ~(a - 1); }

typedef _Float16 f16x2 __attribute__((ext_vector_type(2)));

__device__ inline unsigned int pk2(float a, float b){
  __half2 h = __floats2half2_rn(a, b);
  union { __half2 h; unsigned int u; } cv; cv.h = h; return cv.u;
}

__device__ inline float dot2(unsigned int a, unsigned int b, float c){
  union { unsigned int u; f16x2 h; } ua, ub; ua.u = a; ub.u = b;
#if __has_builtin(__builtin_amdgcn_fdot2)
  return __builtin_amdgcn_fdot2(ua.h, ub.h, c, false);
#else
  return c + (float)ua.h[0] * (float)ub.h[0] + (float)ua.h[1] * (float)ub.h[1];
#endif
}

// ---------- setup kernels ----------

// Mpk[i2][col] = pack(M[2*i2][col], M[2*i2+1][col]), col = h*32+o
// M[i][col] = w2[h*1024 + i*32 + o] (h<64), = b2[i*32+o] (h==64)
__global__ __launch_bounds__(256) void kBuildMpk(const float* __restrict__ w2,
                                                 const float* __restrict__ b2,
                                                 unsigned int* __restrict__ Mpk){
  int idx = blockIdx.x * 256 + threadIdx.x;
  if (idx >= 16 * TCOLS) return;
  int i2 = idx / TCOLS, col = idx % TCOLS;
  int h = col >> 5, o = col & 31;
  float f0, f1;
  if (h < 64){ f0 = w2[h * 1024 + (2 * i2) * 32 + o]; f1 = w2[h * 1024 + (2 * i2 + 1) * 32 + o]; }
  else       { f0 = b2[(2 * i2) * 32 + o];            f1 = b2[(2 * i2 + 1) * 32 + o]; }
  Mpk[idx] = pk2(f0, f1);
}

__global__ __launch_bounds__(256) void kLin0(const float* __restrict__ x,
                                             const float* __restrict__ w,
                                             const float* __restrict__ b,
                                             float* __restrict__ feat, int N){
  int idx = blockIdx.x * 256 + threadIdx.x;
  int u = idx >> 5, o = idx & 31;
  if (u >= N) return;
  float acc = b[o];
#pragma unroll
  for (int i = 0; i < NFEAT; i++) acc += x[(size_t)u * NFEAT + i] * w[i * 32 + o];
  feat[idx] = fmaxf(acc, 0.f);
}

__global__ __launch_bounds__(256) void kCount(const int* __restrict__ ei,
                                              const int* __restrict__ batch,
                                              int* cnt_src, int* cnt_dst, int* bc,
                                              int E, int N){
  int e = blockIdx.x * 256 + threadIdx.x;
  if (e < E){
    atomicAdd(&cnt_src[ei[e]], 1);
    atomicAdd(&cnt_dst[ei[E + e]], 1);
  }
  if (e < N) atomicAdd(&bc[batch[e]], 1);
}

// exclusive scan; blockIdx 0: src, 1: dst (+deg), 2: batch
__global__ __launch_bounds__(256) void kScan(const int* __restrict__ cnt_src,
                                             const int* __restrict__ cnt_dst,
                                             const int* __restrict__ bcnt,
                                             int* src_off, int* dst_off, int* boff,
                                             float* deg, int N, int B){
  __shared__ int part[256];
  const int* cnt; int* off; int n;
  if (blockIdx.x == 0)      { cnt = cnt_src; off = src_off; n = N; }
  else if (blockIdx.x == 1) { cnt = cnt_dst; off = dst_off; n = N; }
  else                      { cnt = bcnt;    off = boff;    n = B; }
  int t = threadIdx.x;
  int chunk = (n + 255) / 256;
  int lo = t * chunk, hi = min(n, lo + chunk);
  int s = 0;
  for (int i = lo; i < hi; i++) s += cnt[i];
  part[t] = s; __syncthreads();
  for (int d = 1; d < 256; d <<= 1){
    int v = (t >= d) ? part[t - d] : 0;
    __syncthreads();
    part[t] += v;
    __syncthreads();
  }
  int run = (t == 0) ? 0 : part[t - 1];
  for (int i = lo; i < hi; i++){ off[i] = run; run += cnt[i]; }
  if (t == 255) off[n] = part[255];
  if (blockIdx.x == 1){
    for (int i = lo; i < hi; i++) deg[i] = (float)max(cnt[i], 1);
  }
}

__global__ __launch_bounds__(256) void kFill(const int* __restrict__ ei,
                                             const int* __restrict__ src_off,
                                             const int* __restrict__ dst_off,
                                             int* fill_src, int* fill_dst,
                                             int* so_src, int* so_eid, int* s2d, int E){
  int e = blockIdx.x * 256 + threadIdx.x;
  if (e >= E) return;
  int s = ei[e], d = ei[E + e];
  int ps = src_off[s] + atomicAdd(&fill_src[s], 1);
  so_src[ps] = s;
  so_eid[ps] = e;
  int pd = dst_off[d] + atomicAdd(&fill_dst[d], 1);
  s2d[ps] = pd;
}

// aperm_pk[j][h2] = pack(relu(mlp)[2*h2], relu(mlp)[2*h2+1]), j in src-CSR order
__global__ __launch_bounds__(256) void kEdgeMLPpk(const float* __restrict__ ea,
                                                  const float* __restrict__ w1,
                                                  const float* __restrict__ b1,
                                                  const int* __restrict__ so_eid,
                                                  unsigned int* __restrict__ apk, int E){
  int idx = blockIdx.x * 256 + threadIdx.x;
  int j = idx >> 5, h2 = idx & 31;
  if (j >= E) return;
  int e = so_eid[j];
  const float* eap = ea + (size_t)e * 5;
  float q0 = eap[0], q1 = eap[1], q2 = eap[2], q3 = eap[3], q4 = eap[4];
  int h = 2 * h2;
  float lo = b1[h]     + q0 * w1[h]       + q1 * w1[64 + h]     + q2 * w1[128 + h]
                       + q3 * w1[192 + h] + q4 * w1[256 + h];
  float hi = b1[h + 1] + q0 * w1[h + 1]   + q1 * w1[64 + h + 1] + q2 * w1[128 + h + 1]
                       + q3 * w1[192 + h + 1] + q4 * w1[256 + h + 1];
  apk[(size_t)j * 32 + h2] = pk2(fmaxf(lo, 0.f), fmaxf(hi, 0.f));
}

// ---------- fused per-iteration kernel ----------
// Per block: 8 nodes. Phase A: T'[8][32 o][32 h2] (f16 h-pairs, stride-34 rows)
// = feat_chunk @ M via v_dot2. Phase B: waves independently process 2 edges
// per round from the chunk's contiguous src-CSR range: stage packed a, then
// 32 dot2 against T' row, scatter msg (f32) to dst-CSR position.
__global__ __launch_bounds__(256, 4) void kTA(const float* __restrict__ feat,
                                              const unsigned int* __restrict__ Mpk,
                                              const int* __restrict__ so_src,
                                              const int* __restrict__ s2d,
                                              const unsigned int* __restrict__ apk,
                                              const int* __restrict__ src_off,
                                              float* __restrict__ msg,
                                              int N){
  __shared__ unsigned int Tp[CHUNK * 32 * TROW];  // 34816 B
  __shared__ unsigned int fpk[CHUNK][16];         // packed feat i-pairs
  __shared__ float bias_l[CHUNK][32];
  __shared__ unsigned int al[4][2][32];           // per-wave packed a (2 edges)
  int tid = threadIdx.x;
  int c0 = blockIdx.x * CHUNK;
  int c1 = min(c0 + CHUNK, N);
  if (tid < CHUNK * 16){
    int n = tid >> 4, i2 = tid & 15;
    float f0 = 0.f, f1 = 0.f;
    if (c0 + n < c1){
      f0 = feat[(size_t)(c0 + n) * 32 + 2 * i2];
      f1 = feat[(size_t)(c0 + n) * 32 + 2 * i2 + 1];
    }
    fpk[n][i2] = pk2(f0, f1);
  }
  __syncthreads();

  // ---- phase A ----
#pragma unroll
  for (int r = 0; r < 2; r++){
    int h2 = (tid >> 4) + r * 16;   // 0..31
    int o2 = tid & 15;
    int cA = (2 * h2) * 32 + 2 * o2;
    int cB = cA + 32;
    float a0[CHUNK], a1[CHUNK], a2[CHUNK], a3[CHUNK];
#pragma unroll
    for (int n = 0; n < CHUNK; n++){ a0[n] = 0.f; a1[n] = 0.f; a2[n] = 0.f; a3[n] = 0.f; }
#pragma unroll 4
    for (int i2 = 0; i2 < 16; i2++){
      uint2 mA = *(const uint2*)(Mpk + (size_t)i2 * TCOLS + cA);
      uint2 mB = *(const uint2*)(Mpk + (size_t)i2 * TCOLS + cB);
#pragma unroll
      for (int n = 0; n < CHUNK; n++){
        unsigned int f = fpk[n][i2];
        a0[n] = dot2(f, mA.x, a0[n]);
        a1[n] = dot2(f, mA.y, a1[n]);
        a2[n] = dot2(f, mB.x, a2[n]);
        a3[n] = dot2(f, mB.y, a3[n]);
      }
    }
#pragma unroll
    for (int n = 0; n < CHUNK; n++){
      Tp[n * 1088 + (2 * o2) * TROW + h2]     = pk2(a0[n], a2[n]);
      Tp[n * 1088 + (2 * o2 + 1) * TROW + h2] = pk2(a1[n], a3[n]);
    }
  }
  if (tid < 32){
    int o = tid;
    float ab[CHUNK];
#pragma unroll
    for (int n = 0; n < CHUNK; n++) ab[n] = 0.f;
#pragma unroll 4
    for (int i2 = 0; i2 < 16; i2++){
      unsigned int m = Mpk[(size_t)i2 * TCOLS + 2048 + o];
#pragma unroll
      for (int n = 0; n < CHUNK; n++) ab[n] = dot2(fpk[n][i2], m, ab[n]);
    }
#pragma unroll
    for (int n = 0; n < CHUNK; n++) bias_l[n][o] = ab[n];
  }
  __syncthreads();

  // ---- phase B: per-wave edge processing ----
  int w = tid >> 6, l = tid & 63;
  int jj = l >> 5, o = l & 31;
  int e0 = src_off[c0], e1 = src_off[c1];
  for (int jb = e0 + w * 2; jb < e1; jb += 8){
    if (jb + (l >> 5) < e1)
      al[w][l >> 5][l & 31] = apk[(size_t)jb * 32 + l];
    __builtin_amdgcn_wave_barrier();
    int j = jb + jj;
    if (j < e1){
      int u = so_src[j] - c0;
      float s0 = bias_l[u][o], s1 = 0.f;
      const unsigned int* Tr = Tp + u * 1088 + o * TROW;
      const unsigned int* ap = &al[w][jj][0];
#pragma unroll
      for (int g = 0; g < 8; g++){
        uint2 tv = *(const uint2*)(Tr + g * 4);
        uint2 tw = *(const uint2*)(Tr + g * 4 + 2);
        uint2 av = *(const uint2*)(ap + g * 4);
        uint2 aw = *(const uint2*)(ap + g * 4 + 2);
        s0 = dot2(av.x, tv.x, s0);
        s1 = dot2(av.y, tv.y, s1);
        s0 = dot2(aw.x, tw.x, s0);
        s1 = dot2(aw.y, tw.y, s1);
      }
      msg[(size_t)s2d[j] * 32 + o] = s0 + s1;
    }
    __builtin_amdgcn_wave_barrier();
  }
}

// aggregate msg (dst-ordered) + conv bias + relu + GRU step, 8 nodes/block
__global__ __launch_bounds__(256) void kB(const float* __restrict__ msg,
                                          const int* __restrict__ dst_off,
                                          const float* __restrict__ deg,
                                          const float* __restrict__ feat_in,
                                          float* __restrict__ feat_out,
                                          const float* __restrict__ Wih,
                                          const float* __restrict__ Whh,
                                          const float* __restrict__ bih,
                                          const float* __restrict__ bhh,
                                          const float* __restrict__ cbias, int N){
  __shared__ float wih[96][33], whh[96][33];
  __shared__ float bi[96], bh[96], cb[32];
  __shared__ float msh[8][33], hsh[8][33];
  int tid = threadIdx.x;
  for (int k = tid; k < 96 * 32; k += 256){
    int g = k >> 5, o = k & 31;
    wih[g][o] = Wih[k];
    whh[g][o] = Whh[k];
  }
  if (tid < 96){ bi[tid] = bih[tid]; bh[tid] = bhh[tid]; }
  if (tid < 32) cb[tid] = cbias[tid];
  __syncthreads();
  int s = tid >> 5, o = tid & 31;
  int v = blockIdx.x * 8 + s;
  if (v >= N) return;
  int lo = dst_off[v], hi = dst_off[v + 1];
  float acc = 0.f;
  for (int k = lo; k < hi; k++){
    acc += msg[(size_t)k * 32 + o];
  }
  float m = fmaxf(acc / deg[v] + cb[o], 0.f);
  float h = feat_in[(size_t)v * 32 + o];
  msh[s][o] = m;
  hsh[s][o] = h;
  float gr = bi[o], gz = bi[32 + o], gn = bi[64 + o];
  float hr = bh[o], hz = bh[32 + o], hn = bh[64 + o];
#pragma unroll
  for (int q = 0; q < 32; q++){
    float mq = msh[s][q], hq = hsh[s][q];
    gr += mq * wih[o][q];      gz += mq * wih[32 + o][q];  gn += mq * wih[64 + o][q];
    hr += hq * whh[o][q];      hz += hq * whh[32 + o][q];  hn += hq * whh[64 + o][q];
  }
  float r = 1.f / (1.f + expf(-(gr + hr)));
  float z = 1.f / (1.f + expf(-(gz + hz)));
  float n = tanhf(gn + r * hn);
  feat_out[(size_t)v * 32 + o] = (1.f - z) * n + z * h;
}

// ---------- Set2Set ----------

__global__ __launch_bounds__(256) void kLSTM(const float* __restrict__ Wih,
                                             const float* __restrict__ Whh,
                                             const float* __restrict__ bih,
                                             const float* __restrict__ bhh,
                                             float* __restrict__ q_star,
                                             float* __restrict__ hh,
                                             float* __restrict__ cc,
                                             int first){
  __shared__ float WihT[64][129];
  __shared__ float WhhT[32][129];
  __shared__ float qs[8][65];
  __shared__ float hl[8][33];
  __shared__ float gates[8][129];
  int tid = threadIdx.x;
  int rbase = blockIdx.x * 8;
  for (int k = tid; k < 128 * 64; k += 256){ int j = k & 63, g = k >> 6; WihT[j][g] = Wih[g * 64 + j]; }
  for (int k = tid; k < 128 * 32; k += 256){ int j = k & 31, g = k >> 5; WhhT[j][g] = Whh[g * 32 + j]; }
  for (int k = tid; k < 512; k += 256){ int rr = k >> 6, j = k & 63; qs[rr][j] = first ? 0.f : q_star[(rbase + rr) * 64 + j]; }
  { int rr = tid >> 5, j = tid & 31; hl[rr][j] = first ? 0.f : hh[(rbase + rr) * 32 + j]; }
  __syncthreads();
  for (int k = tid; k < 1024; k += 256){
    int rr = k >> 7, g = k & 127;
    float acc = bih[g] + bhh[g];
#pragma unroll 8
    for (int j = 0; j < 64; j++) acc += qs[rr][j] * WihT[j][g];
#pragma unroll 8
    for (int j = 0; j < 32; j++) acc += hl[rr][j] * WhhT[j][g];
    gates[rr][g] = acc;
  }
  __syncthreads();
  {
    int rr = tid >> 5, j = tid & 31;
    int row = rbase + rr;
    float iv = gates[rr][j], fv = gates[rr][32 + j], gv = gates[rr][64 + j], ov = gates[rr][96 + j];
    iv = 1.f / (1.f + expf(-iv));
    fv = 1.f / (1.f + expf(-fv));
    gv = tanhf(gv);
    ov = 1.f / (1.f + expf(-ov));
    float cprev = first ? 0.f : cc[row * 32 + j];
    float c = fv * cprev + iv * gv;
    cc[row * 32 + j] = c;
    float hv = ov * tanhf(c);
    hh[row * 32 + j] = hv;
    q_star[row * 64 + j] = hv;
  }
}

// one block per graph: attention softmax + weighted pool
__global__ __launch_bounds__(256) void kPool(const float* __restrict__ feat,
                                             const int* __restrict__ boff,
                                             const float* __restrict__ hh,
                                             float* __restrict__ q_star,
                                             float* __restrict__ e_buf){
  int b = blockIdx.x;
  int lo = boff[b], hi = boff[b + 1];
  __shared__ float q[32];
  __shared__ float wred[4];
  __shared__ float part[8][33];
  int tid = threadIdx.x;
  if (tid < 32) q[tid] = hh[b * 32 + tid];
  __syncthreads();
  int sub = tid >> 5, o = tid & 31;
  float mx = -1e30f;
  for (int i = lo + sub; i < hi; i += 8){
    float v = feat[(size_t)i * 32 + o] * q[o];
#pragma unroll
    for (int d = 16; d; d >>= 1) v += __shfl_xor(v, d, 32);
    if (o == 0) e_buf[i] = v;
    mx = fmaxf(mx, v);
  }
#pragma unroll
  for (int d = 32; d; d >>= 1) mx = fmaxf(mx, __shfl_xor(mx, d, 64));
  if ((tid & 63) == 0) wred[tid >> 6] = mx;
  __syncthreads();
  mx = fmaxf(fmaxf(wred[0], wred[1]), fmaxf(wred[2], wred[3]));
  __syncthreads();
  float sm = 0.f;
  for (int i = lo + tid; i < hi; i += 256){
    float w = expf(e_buf[i] - mx);
    e_buf[i] = w;
    sm += w;
  }
#pragma unroll
  for (int d = 32; d; d >>= 1) sm += __shfl_xor(sm, d, 64);
  if ((tid & 63) == 0) wred[tid >> 6] = sm;
  __syncthreads();
  float denom = wred[0] + wred[1] + wred[2] + wred[3];
  denom = fmaxf(denom, 1e-30f);
  __syncthreads();
  float acc = 0.f;
  for (int i = lo + sub; i < hi; i += 8){
    acc += e_buf[i] * feat[(size_t)i * 32 + o];
  }
  part[sub][o] = acc;
  __syncthreads();
  if (tid < 32){
    float r = 0.f;
#pragma unroll
    for (int s2 = 0; s2 < 8; s2++) r += part[s2][tid];
    q_star[b * 64 + 32 + tid] = r / denom;
  }
}

__global__ __launch_bounds__(256) void kCopy(const float* __restrict__ src,
                                             float* __restrict__ dst, int n){
  int i = blockIdx.x * 256 + threadIdx.x;
  if (i < n) dst[i] = src[i];
}

// ---------- host ----------

extern "C" void kernel_launch(void* const* d_in, const int* in_sizes, int n_in,
                              void* d_out, int out_size, void* d_ws, size_t ws_size,
                              hipStream_t stream){
  (void)n_in; (void)out_size; (void)ws_size;
  const float* x        = (const float*)d_in[0];
  const int*   ei       = (const int*)  d_in[1];
  const float* eattr    = (const float*)d_in[2];
  const int*   batch    = (const int*)  d_in[3];
  const float* lin0_w   = (const float*)d_in[4];
  const float* lin0_b   = (const float*)d_in[5];
  const float* mlp_w1   = (const float*)d_in[6];
  const float* mlp_b1   = (const float*)d_in[7];
  const float* mlp_w2   = (const float*)d_in[8];
  const float* mlp_b2   = (const float*)d_in[9];
  const float* conv_b   = (const float*)d_in[10];
  const float* gru_wih  = (const float*)d_in[11];
  const float* gru_whh  = (const float*)d_in[12];
  const float* gru_bih  = (const float*)d_in[13];
  const float* gru_bhh  = (const float*)d_in[14];
  const float* lstm_wih = (const float*)d_in[15];
  const float* lstm_whh = (const float*)d_in[16];
  const float* lstm_bih = (const float*)d_in[17];
  const float* lstm_bhh = (const float*)d_in[18];

  int N = in_sizes[0] / NFEAT;
  int E = in_sizes[1] / 2;

  char* ws = (char*)d_ws;
  size_t off = 0;
  auto alloc = [&](size_t bytes) -> char* {
    char* p = ws + off;
    off = align_up(off + bytes, 256);
    return p;
  };

  float* feat0  = (float*)alloc((size_t)N * D * 4);
  float* feat1  = (float*)alloc((size_t)N * D * 4);
  float* msg    = (float*)alloc((size_t)E * D * 4);
  unsigned int* Mpk = (unsigned int*)alloc((size_t)16 * TCOLS * 4);
  unsigned int* apk = (unsigned int*)alloc((size_t)E * 32 * 4);
  float* e_buf  = (float*)alloc((size_t)N * 4);
  float* deg    = (float*)alloc((size_t)N * 4);
  float* q_star = (float*)alloc((size_t)NB * 64 * 4);
  float* hhb    = (float*)alloc((size_t)NB * 32 * 4);
  float* ccb    = (float*)alloc((size_t)NB * 32 * 4);
  int* cnt_src  = (int*)alloc((size_t)N * 4);
  int* cnt_dst  = (int*)alloc((size_t)N * 4);
  int* fill_src = (int*)alloc((size_t)N * 4);
  int* fill_dst = (int*)alloc((size_t)N * 4);
  int* bcnt     = (int*)alloc((size_t)NB * 4);
  int* src_off  = (int*)alloc((size_t)(N + 1) * 4);
  int* dst_off  = (int*)alloc((size_t)(N + 1) * 4);
  int* boff     = (int*)alloc((size_t)(NB + 1) * 4);
  int* so_src   = (int*)alloc((size_t)E * 4);
  int* so_eid   = (int*)alloc((size_t)E * 4);
  int* s2d      = (int*)alloc((size_t)E * 4);

  // zero atomic-counter region (covers alignment gaps too)
  (void)hipMemsetAsync(cnt_src, 0, (size_t)((char*)(bcnt + NB) - (char*)cnt_src), stream);

  kBuildMpk<<<(16 * TCOLS + 255) / 256, 256, 0, stream>>>(mlp_w2, mlp_b2, Mpk);
  kLin0<<<(N * 32 + 255) / 256, 256, 0, stream>>>(x, lin0_w, lin0_b, feat0, N);
  kCount<<<(E + 255) / 256, 256, 0, stream>>>(ei, batch, cnt_src, cnt_dst, bcnt, E, N);
  kScan<<<3, 256, 0, stream>>>(cnt_src, cnt_dst, bcnt, src_off, dst_off, boff, deg, N, NB);
  kFill<<<(E + 255) / 256, 256, 0, stream>>>(ei, src_off, dst_off, fill_src, fill_dst,
                                             so_src, so_eid, s2d, E);
  kEdgeMLPpk<<<((size_t)E * 32 + 255) / 256, 256, 0, stream>>>(eattr, mlp_w1, mlp_b1,
                                                               so_eid, apk, E);

  int blocksTA = (N + CHUNK - 1) / CHUNK;
  float* fcur = feat0;
  float* fnext = feat1;
  for (int t = 0; t < 3; t++){
    kTA<<<blocksTA, 256, 0, stream>>>(fcur, Mpk, so_src, s2d, apk, src_off, msg, N);
    kB<<<(N + 7) / 8, 256, 0, stream>>>(msg, dst_off, deg, fcur, fnext,
                                        gru_wih, gru_whh, gru_bih, gru_bhh, conv_b, N);
    float* tmp = fcur; fcur = fnext; fnext = tmp;
  }

  kCopy<<<(N * D + 255) / 256, 256, 0, stream>>>(fcur, (float*)d_out + NB * 64, N * D);

  for (int s = 0; s < 3; s++){
    kLSTM<<<8, 256, 0, stream>>>(lstm_wih, lstm_whh, lstm_bih, lstm_bhh, q_star, hhb, ccb,
                                 s == 0 ? 1 : 0);
    kPool<<<NB, 256, 0, stream>>>(fcur, boff, hhb, q_star, e_buf);
  }

  kCopy<<<(NB * 64 + 255) / 256, 256, 0, stream>>>(q_star, (float*)d_out, NB * 64);
}

// Round 7
// 643.685 us; speedup vs baseline: 3.3777x; 1.1922x over previous
//
#include <hip/hip_runtime.h>
#include <hip/hip_fp16.h>

#define NFEAT 16
#define D 32
#define NB 64        // num graphs
#define TCOLS 2080   // 65*32: h=0..63 from w2, h=64 row from b2
#define CHUNK 8      // nodes per fused block
#define TROW 34      // u32 per (node,o) LDS row (64 f16 + 2 pad) -> conflict-free b64
#define CPAD 16      // counter padding: one counter per 64B line

static inline size_t align_up(size_t x, size_t a){ return (x + a - 1) & ~(a - 1); }

typedef _Float16 f16x2 __attribute__((ext_vector_type(2)));

__device__ inline unsigned int pk2(float a, float b){
  __half2 h = __floats2half2_rn(a, b);
  union { __half2 h; unsigned int u; } cv; cv.h = h; return cv.u;
}

__device__ inline float dot2(unsigned int a, unsigned int b, float c){
  union { unsigned int u; f16x2 h; } ua, ub; ua.u = a; ub.u = b;
#if __has_builtin(__builtin_amdgcn_fdot2)
  return __builtin_amdgcn_fdot2(ua.h, ub.h, c, false);
#else
  return c + (float)ua.h[0] * (float)ub.h[0] + (float)ua.h[1] * (float)ub.h[1];
#endif
}

// ---------- setup kernels ----------

// Mpk[i2][col] = pack(M[2*i2][col], M[2*i2+1][col]), col = h*32+o
__global__ __launch_bounds__(256) void kBuildMpk(const float* __restrict__ w2,
                                                 const float* __restrict__ b2,
                                                 unsigned int* __restrict__ Mpk){
  int idx = blockIdx.x * 256 + threadIdx.x;
  if (idx >= 16 * TCOLS) return;
  int i2 = idx / TCOLS, col = idx % TCOLS;
  int h = col >> 5, o = col & 31;
  float f0, f1;
  if (h < 64){ f0 = w2[h * 1024 + (2 * i2) * 32 + o]; f1 = w2[h * 1024 + (2 * i2 + 1) * 32 + o]; }
  else       { f0 = b2[(2 * i2) * 32 + o];            f1 = b2[(2 * i2 + 1) * 32 + o]; }
  Mpk[idx] = pk2(f0, f1);
}

__global__ __launch_bounds__(256) void kLin0(const float* __restrict__ x,
                                             const float* __restrict__ w,
                                             const float* __restrict__ b,
                                             float* __restrict__ feat, int N){
  int idx = blockIdx.x * 256 + threadIdx.x;
  int u = idx >> 5, o = idx & 31;
  if (u >= N) return;
  float acc = b[o];
#pragma unroll
  for (int i = 0; i < NFEAT; i++) acc += x[(size_t)u * NFEAT + i] * w[i * 32 + o];
  feat[idx] = fmaxf(acc, 0.f);
}

// counts (padded) + ranks in one pass
__global__ __launch_bounds__(256) void kCountRank(const int* __restrict__ ei,
                                                  int* __restrict__ cnt_src,
                                                  int* __restrict__ cnt_dst,
                                                  int* __restrict__ rs,
                                                  int* __restrict__ rd, int E){
  int e = blockIdx.x * 256 + threadIdx.x;
  if (e >= E) return;
  int s = ei[e], d = ei[E + e];
  rs[e] = atomicAdd(&cnt_src[(size_t)s * CPAD], 1);
  rd[e] = atomicAdd(&cnt_dst[(size_t)d * CPAD], 1);
}

// exclusive scan of padded counts; blockIdx 0: src, 1: dst (+deg), 2: batch via bsearch
__global__ __launch_bounds__(256) void kScan(const int* __restrict__ cnt_src,
                                             const int* __restrict__ cnt_dst,
                                             const int* __restrict__ batch,
                                             int* src_off, int* dst_off, int* boff,
                                             float* deg, int N, int B){
  if (blockIdx.x == 2){
    int t = threadIdx.x;
    if (t <= B){
      int lo = 0, hi = N;
      while (lo < hi){ int mid = (lo + hi) >> 1; if (batch[mid] < t) lo = mid + 1; else hi = mid; }
      boff[t] = lo;
    }
    return;
  }
  __shared__ int part[256];
  const int* cnt = (blockIdx.x == 0) ? cnt_src : cnt_dst;
  int* off = (blockIdx.x == 0) ? src_off : dst_off;
  int n = N;
  int t = threadIdx.x;
  int chunk = (n + 255) / 256;
  int lo = t * chunk, hi = min(n, lo + chunk);
  int s = 0;
  for (int i = lo; i < hi; i++) s += cnt[(size_t)i * CPAD];
  part[t] = s; __syncthreads();
  for (int d = 1; d < 256; d <<= 1){
    int v = (t >= d) ? part[t - d] : 0;
    __syncthreads();
    part[t] += v;
    __syncthreads();
  }
  int run = (t == 0) ? 0 : part[t - 1];
  for (int i = lo; i < hi; i++){ off[i] = run; run += cnt[(size_t)i * CPAD]; }
  if (t == 255) off[n] = part[255];
  if (blockIdx.x == 1){
    for (int i = lo; i < hi; i++) deg[i] = (float)max(cnt[(size_t)i * CPAD], 1);
  }
}

// atomic-free placement using precomputed ranks
__global__ __launch_bounds__(256) void kPlace(const int* __restrict__ ei,
                                              const int* __restrict__ src_off,
                                              const int* __restrict__ dst_off,
                                              const int* __restrict__ rs,
                                              const int* __restrict__ rd,
                                              int* __restrict__ so_src,
                                              int* __restrict__ so_eid,
                                              int* __restrict__ s2d, int E){
  int e = blockIdx.x * 256 + threadIdx.x;
  if (e >= E) return;
  int s = ei[e], d = ei[E + e];
  int ps = src_off[s] + rs[e];
  so_src[ps] = s;
  so_eid[ps] = e;
  s2d[ps] = dst_off[d] + rd[e];
}

// aperm_pk[j][h2] = pack(relu(mlp)[2*h2], relu(mlp)[2*h2+1]), j in src-CSR order
__global__ __launch_bounds__(256) void kEdgeMLPpk(const float* __restrict__ ea,
                                                  const float* __restrict__ w1,
                                                  const float* __restrict__ b1,
                                                  const int* __restrict__ so_eid,
                                                  unsigned int* __restrict__ apk, int E){
  int idx = blockIdx.x * 256 + threadIdx.x;
  int j = idx >> 5, h2 = idx & 31;
  if (j >= E) return;
  int e = so_eid[j];
  const float* eap = ea + (size_t)e * 5;
  float q0 = eap[0], q1 = eap[1], q2 = eap[2], q3 = eap[3], q4 = eap[4];
  int h = 2 * h2;
  float lo = b1[h]     + q0 * w1[h]       + q1 * w1[64 + h]     + q2 * w1[128 + h]
                       + q3 * w1[192 + h] + q4 * w1[256 + h];
  float hi = b1[h + 1] + q0 * w1[h + 1]   + q1 * w1[64 + h + 1] + q2 * w1[128 + h + 1]
                       + q3 * w1[192 + h + 1] + q4 * w1[256 + h + 1];
  apk[(size_t)j * 32 + h2] = pk2(fmaxf(lo, 0.f), fmaxf(hi, 0.f));
}

// ---------- fused per-iteration kernel ----------
__global__ __launch_bounds__(256, 4) void kTA(const float* __restrict__ feat,
                                              const unsigned int* __restrict__ Mpk,
                                              const int* __restrict__ so_src,
                                              const int* __restrict__ s2d,
                                              const unsigned int* __restrict__ apk,
                                              const int* __restrict__ src_off,
                                              float* __restrict__ msg,
                                              int N){
  __shared__ unsigned int Tp[CHUNK * 32 * TROW];  // 34816 B
  __shared__ unsigned int fpk[CHUNK][16];         // packed feat i-pairs
  __shared__ float bias_l[CHUNK][32];
  __shared__ unsigned int al[4][2][32];           // per-wave packed a (2 edges)
  int tid = threadIdx.x;
  int c0 = blockIdx.x * CHUNK;
  int c1 = min(c0 + CHUNK, N);
  if (tid < CHUNK * 16){
    int n = tid >> 4, i2 = tid & 15;
    float f0 = 0.f, f1 = 0.f;
    if (c0 + n < c1){
      f0 = feat[(size_t)(c0 + n) * 32 + 2 * i2];
      f1 = feat[(size_t)(c0 + n) * 32 + 2 * i2 + 1];
    }
    fpk[n][i2] = pk2(f0, f1);
  }
  __syncthreads();

  // ---- phase A ----
#pragma unroll
  for (int r = 0; r < 2; r++){
    int h2 = (tid >> 4) + r * 16;   // 0..31
    int o2 = tid & 15;
    int cA = (2 * h2) * 32 + 2 * o2;
    int cB = cA + 32;
    float a0[CHUNK], a1[CHUNK], a2[CHUNK], a3[CHUNK];
#pragma unroll
    for (int n = 0; n < CHUNK; n++){ a0[n] = 0.f; a1[n] = 0.f; a2[n] = 0.f; a3[n] = 0.f; }
#pragma unroll 4
    for (int i2 = 0; i2 < 16; i2++){
      uint2 mA = *(const uint2*)(Mpk + (size_t)i2 * TCOLS + cA);
      uint2 mB = *(const uint2*)(Mpk + (size_t)i2 * TCOLS + cB);
#pragma unroll
      for (int n = 0; n < CHUNK; n++){
        unsigned int f = fpk[n][i2];
        a0[n] = dot2(f, mA.x, a0[n]);
        a1[n] = dot2(f, mA.y, a1[n]);
        a2[n] = dot2(f, mB.x, a2[n]);
        a3[n] = dot2(f, mB.y, a3[n]);
      }
    }
#pragma unroll
    for (int n = 0; n < CHUNK; n++){
      Tp[n * 1088 + (2 * o2) * TROW + h2]     = pk2(a0[n], a2[n]);
      Tp[n * 1088 + (2 * o2 + 1) * TROW + h2] = pk2(a1[n], a3[n]);
    }
  }
  if (tid < 32){
    int o = tid;
    float ab[CHUNK];
#pragma unroll
    for (int n = 0; n < CHUNK; n++) ab[n] = 0.f;
#pragma unroll 4
    for (int i2 = 0; i2 < 16; i2++){
      unsigned int m = Mpk[(size_t)i2 * TCOLS + 2048 + o];
#pragma unroll
      for (int n = 0; n < CHUNK; n++) ab[n] = dot2(fpk[n][i2], m, ab[n]);
    }
#pragma unroll
    for (int n = 0; n < CHUNK; n++) bias_l[n][o] = ab[n];
  }
  __syncthreads();

  // ---- phase B: per-wave edge processing ----
  int w = tid >> 6, l = tid & 63;
  int jj = l >> 5, o = l & 31;
  int e0 = src_off[c0], e1 = src_off[c1];
  for (int jb = e0 + w * 2; jb < e1; jb += 8){
    if (jb + (l >> 5) < e1)
      al[w][l >> 5][l & 31] = apk[(size_t)jb * 32 + l];
    __builtin_amdgcn_wave_barrier();
    int j = jb + jj;
    if (j < e1){
      int u = so_src[j] - c0;
      float s0 = bias_l[u][o], s1 = 0.f;
      const unsigned int* Tr = Tp + u * 1088 + o * TROW;
      const unsigned int* ap = &al[w][jj][0];
#pragma unroll
      for (int g = 0; g < 8; g++){
        uint2 tv = *(const uint2*)(Tr + g * 4);
        uint2 tw = *(const uint2*)(Tr + g * 4 + 2);
        uint2 av = *(const uint2*)(ap + g * 4);
        uint2 aw = *(const uint2*)(ap + g * 4 + 2);
        s0 = dot2(av.x, tv.x, s0);
        s1 = dot2(av.y, tv.y, s1);
        s0 = dot2(aw.x, tw.x, s0);
        s1 = dot2(aw.y, tw.y, s1);
      }
      msg[(size_t)s2d[j] * 32 + o] = s0 + s1;
    }
    __builtin_amdgcn_wave_barrier();
  }
}

// aggregate msg (dst-ordered) + conv bias + relu + GRU step, 8 nodes/block
__global__ __launch_bounds__(256) void kB(const float* __restrict__ msg,
                                          const int* __restrict__ dst_off,
                                          const float* __restrict__ deg,
                                          const float* __restrict__ feat_in,
                                          float* __restrict__ feat_out,
                                          const float* __restrict__ Wih,
                                          const float* __restrict__ Whh,
                                          const float* __restrict__ bih,
                                          const float* __restrict__ bhh,
                                          const float* __restrict__ cbias, int N){
  __shared__ float wih[96][33], whh[96][33];
  __shared__ float bi[96], bh[96], cb[32];
  __shared__ float msh[8][33], hsh[8][33];
  int tid = threadIdx.x;
  for (int k = tid; k < 96 * 32; k += 256){
    int g = k >> 5, o = k & 31;
    wih[g][o] = Wih[k];
    whh[g][o] = Whh[k];
  }
  if (tid < 96){ bi[tid] = bih[tid]; bh[tid] = bhh[tid]; }
  if (tid < 32) cb[tid] = cbias[tid];
  __syncthreads();
  int s = tid >> 5, o = tid & 31;
  int v = blockIdx.x * 8 + s;
  if (v >= N) return;
  int lo = dst_off[v], hi = dst_off[v + 1];
  float acc = 0.f;
  for (int k = lo; k < hi; k++){
    acc += msg[(size_t)k * 32 + o];
  }
  float m = fmaxf(acc / deg[v] + cb[o], 0.f);
  float h = feat_in[(size_t)v * 32 + o];
  msh[s][o] = m;
  hsh[s][o] = h;
  float gr = bi[o], gz = bi[32 + o], gn = bi[64 + o];
  float hr = bh[o], hz = bh[32 + o], hn = bh[64 + o];
#pragma unroll
  for (int q = 0; q < 32; q++){
    float mq = msh[s][q], hq = hsh[s][q];
    gr += mq * wih[o][q];      gz += mq * wih[32 + o][q];  gn += mq * wih[64 + o][q];
    hr += hq * whh[o][q];      hz += hq * whh[32 + o][q];  hn += hq * whh[64 + o][q];
  }
  float r = 1.f / (1.f + expf(-(gr + hr)));
  float z = 1.f / (1.f + expf(-(gz + hz)));
  float n = tanhf(gn + r * hn);
  feat_out[(size_t)v * 32 + o] = (1.f - z) * n + z * h;
}

// ---------- Set2Set ----------

__global__ __launch_bounds__(256) void kLSTM(const float* __restrict__ Wih,
                                             const float* __restrict__ Whh,
                                             const float* __restrict__ bih,
                                             const float* __restrict__ bhh,
                                             float* __restrict__ q_star,
                                             float* __restrict__ hh,
                                             float* __restrict__ cc,
                                             int first){
  __shared__ float WihT[64][129];
  __shared__ float WhhT[32][129];
  __shared__ float qs[8][65];
  __shared__ float hl[8][33];
  __shared__ float gates[8][129];
  int tid = threadIdx.x;
  int rbase = blockIdx.x * 8;
  for (int k = tid; k < 128 * 64; k += 256){ int j = k & 63, g = k >> 6; WihT[j][g] = Wih[g * 64 + j]; }
  for (int k = tid; k < 128 * 32; k += 256){ int j = k & 31, g = k >> 5; WhhT[j][g] = Whh[g * 32 + j]; }
  for (int k = tid; k < 512; k += 256){ int rr = k >> 6, j = k & 63; qs[rr][j] = first ? 0.f : q_star[(rbase + rr) * 64 + j]; }
  { int rr = tid >> 5, j = tid & 31; hl[rr][j] = first ? 0.f : hh[(rbase + rr) * 32 + j]; }
  __syncthreads();
  for (int k = tid; k < 1024; k += 256){
    int rr = k >> 7, g = k & 127;
    float acc = bih[g] + bhh[g];
#pragma unroll 8
    for (int j = 0; j < 64; j++) acc += qs[rr][j] * WihT[j][g];
#pragma unroll 8
    for (int j = 0; j < 32; j++) acc += hl[rr][j] * WhhT[j][g];
    gates[rr][g] = acc;
  }
  __syncthreads();
  {
    int rr = tid >> 5, j = tid & 31;
    int row = rbase + rr;
    float iv = gates[rr][j], fv = gates[rr][32 + j], gv = gates[rr][64 + j], ov = gates[rr][96 + j];
    iv = 1.f / (1.f + expf(-iv));
    fv = 1.f / (1.f + expf(-fv));
    gv = tanhf(gv);
    ov = 1.f / (1.f + expf(-ov));
    float cprev = first ? 0.f : cc[row * 32 + j];
    float c = fv * cprev + iv * gv;
    cc[row * 32 + j] = c;
    float hv = ov * tanhf(c);
    hh[row * 32 + j] = hv;
    q_star[row * 64 + j] = hv;
  }
}

// one block per graph: attention softmax + weighted pool
__global__ __launch_bounds__(256) void kPool(const float* __restrict__ feat,
                                             const int* __restrict__ boff,
                                             const float* __restrict__ hh,
                                             float* __restrict__ q_star,
                                             float* __restrict__ e_buf){
  int b = blockIdx.x;
  int lo = boff[b], hi = boff[b + 1];
  __shared__ float q[32];
  __shared__ float wred[4];
  __shared__ float part[8][33];
  int tid = threadIdx.x;
  if (tid < 32) q[tid] = hh[b * 32 + tid];
  __syncthreads();
  int sub = tid >> 5, o = tid & 31;
  float mx = -1e30f;
  for (int i = lo + sub; i < hi; i += 8){
    float v = feat[(size_t)i * 32 + o] * q[o];
#pragma unroll
    for (int d = 16; d; d >>= 1) v += __shfl_xor(v, d, 32);
    if (o == 0) e_buf[i] = v;
    mx = fmaxf(mx, v);
  }
#pragma unroll
  for (int d = 32; d; d >>= 1) mx = fmaxf(mx, __shfl_xor(mx, d, 64));
  if ((tid & 63) == 0) wred[tid >> 6] = mx;
  __syncthreads();
  mx = fmaxf(fmaxf(wred[0], wred[1]), fmaxf(wred[2], wred[3]));
  __syncthreads();
  float sm = 0.f;
  for (int i = lo + tid; i < hi; i += 256){
    float w = expf(e_buf[i] - mx);
    e_buf[i] = w;
    sm += w;
  }
#pragma unroll
  for (int d = 32; d; d >>= 1) sm += __shfl_xor(sm, d, 64);
  if ((tid & 63) == 0) wred[tid >> 6] = sm;
  __syncthreads();
  float denom = wred[0] + wred[1] + wred[2] + wred[3];
  denom = fmaxf(denom, 1e-30f);
  __syncthreads();
  float acc = 0.f;
  for (int i = lo + sub; i < hi; i += 8){
    acc += e_buf[i] * feat[(size_t)i * 32 + o];
  }
  part[sub][o] = acc;
  __syncthreads();
  if (tid < 32){
    float r = 0.f;
#pragma unroll
    for (int s2 = 0; s2 < 8; s2++) r += part[s2][tid];
    q_star[b * 64 + 32 + tid] = r / denom;
  }
}

__global__ __launch_bounds__(256) void kCopy(const float* __restrict__ src,
                                             float* __restrict__ dst, int n){
  int i = blockIdx.x * 256 + threadIdx.x;
  if (i < n) dst[i] = src[i];
}

// ---------- host ----------

extern "C" void kernel_launch(void* const* d_in, const int* in_sizes, int n_in,
                              void* d_out, int out_size, void* d_ws, size_t ws_size,
                              hipStream_t stream){
  (void)n_in; (void)out_size; (void)ws_size;
  const float* x        = (const float*)d_in[0];
  const int*   ei       = (const int*)  d_in[1];
  const float* eattr    = (const float*)d_in[2];
  const int*   batch    = (const int*)  d_in[3];
  const float* lin0_w   = (const float*)d_in[4];
  const float* lin0_b   = (const float*)d_in[5];
  const float* mlp_w1   = (const float*)d_in[6];
  const float* mlp_b1   = (const float*)d_in[7];
  const float* mlp_w2   = (const float*)d_in[8];
  const float* mlp_b2   = (const float*)d_in[9];
  const float* conv_b   = (const float*)d_in[10];
  const float* gru_wih  = (const float*)d_in[11];
  const float* gru_whh  = (const float*)d_in[12];
  const float* gru_bih  = (const float*)d_in[13];
  const float* gru_bhh  = (const float*)d_in[14];
  const float* lstm_wih = (const float*)d_in[15];
  const float* lstm_whh = (const float*)d_in[16];
  const float* lstm_bih = (const float*)d_in[17];
  const float* lstm_bhh = (const float*)d_in[18];

  int N = in_sizes[0] / NFEAT;
  int E = in_sizes[1] / 2;

  char* ws = (char*)d_ws;
  size_t off = 0;
  auto alloc = [&](size_t bytes) -> char* {
    char* p = ws + off;
    off = align_up(off + bytes, 256);
    return p;
  };

  float* feat0  = (float*)alloc((size_t)N * D * 4);
  float* feat1  = (float*)alloc((size_t)N * D * 4);
  float* msg    = (float*)alloc((size_t)E * D * 4);
  unsigned int* Mpk = (unsigned int*)alloc((size_t)16 * TCOLS * 4);
  unsigned int* apk = (unsigned int*)alloc((size_t)E * 32 * 4);
  float* e_buf  = (float*)alloc((size_t)N * 4);
  float* deg    = (float*)alloc((size_t)N * 4);
  float* q_star = (float*)alloc((size_t)NB * 64 * 4);
  float* hhb    = (float*)alloc((size_t)NB * 32 * 4);
  float* ccb    = (float*)alloc((size_t)NB * 32 * 4);
  int* cnt_src  = (int*)alloc((size_t)N * CPAD * 4);   // padded: 1 counter / 64B
  int* cnt_dst  = (int*)alloc((size_t)N * CPAD * 4);
  int* rs       = (int*)alloc((size_t)E * 4);
  int* rd       = (int*)alloc((size_t)E * 4);
  int* src_off  = (int*)alloc((size_t)(N + 1) * 4);
  int* dst_off  = (int*)alloc((size_t)(N + 1) * 4);
  int* boff     = (int*)alloc((size_t)(NB + 1) * 4);
  int* so_src   = (int*)alloc((size_t)E * 4);
  int* so_eid   = (int*)alloc((size_t)E * 4);
  int* s2d      = (int*)alloc((size_t)E * 4);

  // zero the padded counters
  (void)hipMemsetAsync(cnt_src, 0, (size_t)N * CPAD * 4 * 2, stream);

  kBuildMpk<<<(16 * TCOLS + 255) / 256, 256, 0, stream>>>(mlp_w2, mlp_b2, Mpk);
  kLin0<<<(N * 32 + 255) / 256, 256, 0, stream>>>(x, lin0_w, lin0_b, feat0, N);
  kCountRank<<<(E + 255) / 256, 256, 0, stream>>>(ei, cnt_src, cnt_dst, rs, rd, E);
  kScan<<<3, 256, 0, stream>>>(cnt_src, cnt_dst, batch, src_off, dst_off, boff, deg, N, NB);
  kPlace<<<(E + 255) / 256, 256, 0, stream>>>(ei, src_off, dst_off, rs, rd,
                                              so_src, so_eid, s2d, E);
  kEdgeMLPpk<<<((size_t)E * 32 + 255) / 256, 256, 0, stream>>>(eattr, mlp_w1, mlp_b1,
                                                               so_eid, apk, E);

  int blocksTA = (N + CHUNK - 1) / CHUNK;
  float* fcur = feat0;
  float* fnext = feat1;
  for (int t = 0; t < 3; t++){
    kTA<<<blocksTA, 256, 0, stream>>>(fcur, Mpk, so_src, s2d, apk, src_off, msg, N);
    kB<<<(N + 7) / 8, 256, 0, stream>>>(msg, dst_off, deg, fcur, fnext,
                                        gru_wih, gru_whh, gru_bih, gru_bhh, conv_b, N);
    float* tmp = fcur; fcur = fnext; fnext = tmp;
  }

  kCopy<<<(N * D + 255) / 256, 256, 0, stream>>>(fcur, (float*)d_out + NB * 64, N * D);

  for (int s = 0; s < 3; s++){
    kLSTM<<<8, 256, 0, stream>>>(lstm_wih, lstm_whh, lstm_bih, lstm_bhh, q_star, hhb, ccb,
                                 s == 0 ? 1 : 0);
    kPool<<<NB, 256, 0, stream>>>(fcur, boff, hhb, q_star, e_buf);
  }

  kCopy<<<(NB * 64 + 255) / 256, 256, 0, stream>>>(q_star, (float*)d_out, NB * 64);
}

// Round 8
// 636.078 us; speedup vs baseline: 3.4181x; 1.0120x over previous
//
#include <hip/hip_runtime.h>
#include <hip/hip_fp16.h>

#define NFEAT 16
#define D 32
#define NB 64        // num graphs
#define TCOLS 2080   // 65*32: h=0..63 from w2, h=64 row from b2
#define CHUNK 8      // nodes per fused block
#define TROW 34      // u32 per (node,o) LDS row (64 f16 + 2 pad) -> conflict-free b64
#define CPAD 16      // counter padding: one counter per 64B line
#define KBN 32       // nodes per kB block

static inline size_t align_up(size_t x, size_t a){ return (x + a - 1) & ~(a - 1); }

typedef _Float16 f16x2 __attribute__((ext_vector_type(2)));

__device__ inline unsigned int pk2(float a, float b){
  __half2 h = __floats2half2_rn(a, b);
  union { __half2 h; unsigned int u; } cv; cv.h = h; return cv.u;
}

__device__ inline float dot2(unsigned int a, unsigned int b, float c){
  union { unsigned int u; f16x2 h; } ua, ub; ua.u = a; ub.u = b;
#if __has_builtin(__builtin_amdgcn_fdot2)
  return __builtin_amdgcn_fdot2(ua.h, ub.h, c, false);
#else
  return c + (float)ua.h[0] * (float)ub.h[0] + (float)ua.h[1] * (float)ub.h[1];
#endif
}

// ---------- setup kernels ----------

// Mpk[i2][col] = pack(M[2*i2][col], M[2*i2+1][col]), col = h*32+o
__global__ __launch_bounds__(256) void kBuildMpk(const float* __restrict__ w2,
                                                 const float* __restrict__ b2,
                                                 unsigned int* __restrict__ Mpk){
  int idx = blockIdx.x * 256 + threadIdx.x;
  if (idx >= 16 * TCOLS) return;
  int i2 = idx / TCOLS, col = idx % TCOLS;
  int h = col >> 5, o = col & 31;
  float f0, f1;
  if (h < 64){ f0 = w2[h * 1024 + (2 * i2) * 32 + o]; f1 = w2[h * 1024 + (2 * i2 + 1) * 32 + o]; }
  else       { f0 = b2[(2 * i2) * 32 + o];            f1 = b2[(2 * i2 + 1) * 32 + o]; }
  Mpk[idx] = pk2(f0, f1);
}

__global__ __launch_bounds__(256) void kLin0(const float* __restrict__ x,
                                             const float* __restrict__ w,
                                             const float* __restrict__ b,
                                             float* __restrict__ feat, int N){
  int idx = blockIdx.x * 256 + threadIdx.x;
  int u = idx >> 5, o = idx & 31;
  if (u >= N) return;
  float acc = b[o];
#pragma unroll
  for (int i = 0; i < NFEAT; i++) acc += x[(size_t)u * NFEAT + i] * w[i * 32 + o];
  feat[idx] = fmaxf(acc, 0.f);
}

// counts (padded) + ranks in one pass
__global__ __launch_bounds__(256) void kCountRank(const int* __restrict__ ei,
                                                  int* __restrict__ cnt_src,
                                                  int* __restrict__ cnt_dst,
                                                  int* __restrict__ rs,
                                                  int* __restrict__ rd, int E){
  int e = blockIdx.x * 256 + threadIdx.x;
  if (e >= E) return;
  int s = ei[e], d = ei[E + e];
  rs[e] = atomicAdd(&cnt_src[(size_t)s * CPAD], 1);
  rd[e] = atomicAdd(&cnt_dst[(size_t)d * CPAD], 1);
}

// exclusive scan of padded counts; blockIdx 0: src, 1: dst (+deg), 2: batch via bsearch
__global__ __launch_bounds__(256) void kScan(const int* __restrict__ cnt_src,
                                             const int* __restrict__ cnt_dst,
                                             const int* __restrict__ batch,
                                             int* src_off, int* dst_off, int* boff,
                                             float* deg, int N, int B){
  if (blockIdx.x == 2){
    int t = threadIdx.x;
    if (t <= B){
      int lo = 0, hi = N;
      while (lo < hi){ int mid = (lo + hi) >> 1; if (batch[mid] < t) lo = mid + 1; else hi = mid; }
      boff[t] = lo;
    }
    return;
  }
  __shared__ int part[256];
  const int* cnt = (blockIdx.x == 0) ? cnt_src : cnt_dst;
  int* off = (blockIdx.x == 0) ? src_off : dst_off;
  int n = N;
  int t = threadIdx.x;
  int chunk = (n + 255) / 256;
  int lo = t * chunk, hi = min(n, lo + chunk);
  int s = 0;
  for (int i = lo; i < hi; i++) s += cnt[(size_t)i * CPAD];
  part[t] = s; __syncthreads();
  for (int d = 1; d < 256; d <<= 1){
    int v = (t >= d) ? part[t - d] : 0;
    __syncthreads();
    part[t] += v;
    __syncthreads();
  }
  int run = (t == 0) ? 0 : part[t - 1];
  for (int i = lo; i < hi; i++){ off[i] = run; run += cnt[(size_t)i * CPAD]; }
  if (t == 255) off[n] = part[255];
  if (blockIdx.x == 1){
    for (int i = lo; i < hi; i++) deg[i] = (float)max(cnt[(size_t)i * CPAD], 1);
  }
}

// atomic-free placement using precomputed ranks
__global__ __launch_bounds__(256) void kPlace(const int* __restrict__ ei,
                                              const int* __restrict__ src_off,
                                              const int* __restrict__ dst_off,
                                              const int* __restrict__ rs,
                                              const int* __restrict__ rd,
                                              int* __restrict__ so_src,
                                              int* __restrict__ so_eid,
                                              int* __restrict__ s2d, int E){
  int e = blockIdx.x * 256 + threadIdx.x;
  if (e >= E) return;
  int s = ei[e], d = ei[E + e];
  int ps = src_off[s] + rs[e];
  so_src[ps] = s;
  so_eid[ps] = e;
  s2d[ps] = dst_off[d] + rd[e];
}

// aperm_pk[j][h2] = pack(relu(mlp)[2*h2], relu(mlp)[2*h2+1]), j in src-CSR order
__global__ __launch_bounds__(256) void kEdgeMLPpk(const float* __restrict__ ea,
                                                  const float* __restrict__ w1,
                                                  const float* __restrict__ b1,
                                                  const int* __restrict__ so_eid,
                                                  unsigned int* __restrict__ apk, int E){
  int idx = blockIdx.x * 256 + threadIdx.x;
  int j = idx >> 5, h2 = idx & 31;
  if (j >= E) return;
  int e = so_eid[j];
  const float* eap = ea + (size_t)e * 5;
  float q0 = eap[0], q1 = eap[1], q2 = eap[2], q3 = eap[3], q4 = eap[4];
  int h = 2 * h2;
  float lo = b1[h]     + q0 * w1[h]       + q1 * w1[64 + h]     + q2 * w1[128 + h]
                       + q3 * w1[192 + h] + q4 * w1[256 + h];
  float hi = b1[h + 1] + q0 * w1[h + 1]   + q1 * w1[64 + h + 1] + q2 * w1[128 + h + 1]
                       + q3 * w1[192 + h + 1] + q4 * w1[256 + h + 1];
  apk[(size_t)j * 32 + h2] = pk2(fmaxf(lo, 0.f), fmaxf(hi, 0.f));
}

// ---------- fused per-iteration kernel ----------
__global__ __launch_bounds__(256, 4) void kTA(const float* __restrict__ feat,
                                              const unsigned int* __restrict__ Mpk,
                                              const int* __restrict__ so_src,
                                              const int* __restrict__ s2d,
                                              const unsigned int* __restrict__ apk,
                                              const int* __restrict__ src_off,
                                              float* __restrict__ msg,
                                              int N){
  __shared__ unsigned int Tp[CHUNK * 32 * TROW];  // 34816 B
  __shared__ unsigned int fpk[CHUNK][16];         // packed feat i-pairs
  __shared__ float bias_l[CHUNK][32];
  __shared__ unsigned int al[4][2][64];           // per-wave double-buffered packed a
  int tid = threadIdx.x;
  int c0 = blockIdx.x * CHUNK;
  int c1 = min(c0 + CHUNK, N);
  if (tid < CHUNK * 16){
    int n = tid >> 4, i2 = tid & 15;
    float f0 = 0.f, f1 = 0.f;
    if (c0 + n < c1){
      f0 = feat[(size_t)(c0 + n) * 32 + 2 * i2];
      f1 = feat[(size_t)(c0 + n) * 32 + 2 * i2 + 1];
    }
    fpk[n][i2] = pk2(f0, f1);
  }
  __syncthreads();

  // ---- phase A ----
#pragma unroll
  for (int r = 0; r < 2; r++){
    int h2 = (tid >> 4) + r * 16;   // 0..31
    int o2 = tid & 15;
    int cA = (2 * h2) * 32 + 2 * o2;
    int cB = cA + 32;
    float a0[CHUNK], a1[CHUNK], a2[CHUNK], a3[CHUNK];
#pragma unroll
    for (int n = 0; n < CHUNK; n++){ a0[n] = 0.f; a1[n] = 0.f; a2[n] = 0.f; a3[n] = 0.f; }
#pragma unroll 4
    for (int i2 = 0; i2 < 16; i2++){
      uint2 mA = *(const uint2*)(Mpk + (size_t)i2 * TCOLS + cA);
      uint2 mB = *(const uint2*)(Mpk + (size_t)i2 * TCOLS + cB);
#pragma unroll
      for (int n = 0; n < CHUNK; n++){
        unsigned int f = fpk[n][i2];
        a0[n] = dot2(f, mA.x, a0[n]);
        a1[n] = dot2(f, mA.y, a1[n]);
        a2[n] = dot2(f, mB.x, a2[n]);
        a3[n] = dot2(f, mB.y, a3[n]);
      }
    }
#pragma unroll
    for (int n = 0; n < CHUNK; n++){
      Tp[n * 1088 + (2 * o2) * TROW + h2]     = pk2(a0[n], a2[n]);
      Tp[n * 1088 + (2 * o2 + 1) * TROW + h2] = pk2(a1[n], a3[n]);
    }
  }
  if (tid < 32){
    int o = tid;
    float ab[CHUNK];
#pragma unroll
    for (int n = 0; n < CHUNK; n++) ab[n] = 0.f;
#pragma unroll 4
    for (int i2 = 0; i2 < 16; i2++){
      unsigned int m = Mpk[(size_t)i2 * TCOLS + 2048 + o];
#pragma unroll
      for (int n = 0; n < CHUNK; n++) ab[n] = dot2(fpk[n][i2], m, ab[n]);
    }
#pragma unroll
    for (int n = 0; n < CHUNK; n++) bias_l[n][o] = ab[n];
  }
  __syncthreads();

  // ---- phase B: per-wave edge processing, double-buffered apk prefetch ----
  int w = tid >> 6, l = tid & 63;
  int jj = l >> 5, o = l & 31;
  int e0 = src_off[c0], e1 = src_off[c1];
  int jb = e0 + w * 2;
  int buf = 0;
  if (jb < e1){
    if (jb + jj < e1) al[w][0][l] = apk[(size_t)jb * 32 + l];
  }
  __builtin_amdgcn_wave_barrier();
  for (; jb < e1; jb += 8){
    int jbn = jb + 8;
    unsigned int pre = 0;
    bool pv = (jbn + jj < e1);
    if (pv) pre = apk[(size_t)jbn * 32 + l];   // issue early; waits after compute
    int j = jb + jj;
    if (j < e1){
      int u = so_src[j] - c0;
      float s0 = bias_l[u][o], s1 = 0.f;
      const unsigned int* Tr = Tp + u * 1088 + o * TROW;
      const unsigned int* ap = &al[w][buf][jj * 32];
#pragma unroll
      for (int g = 0; g < 8; g++){
        uint2 tv = *(const uint2*)(Tr + g * 4);
        uint2 tw = *(const uint2*)(Tr + g * 4 + 2);
        uint2 av = *(const uint2*)(ap + g * 4);
        uint2 aw = *(const uint2*)(ap + g * 4 + 2);
        s0 = dot2(av.x, tv.x, s0);
        s1 = dot2(av.y, tv.y, s1);
        s0 = dot2(aw.x, tw.x, s0);
        s1 = dot2(aw.y, tw.y, s1);
      }
      msg[(size_t)s2d[j] * 32 + o] = s0 + s1;
    }
    __builtin_amdgcn_wave_barrier();
    if (pv) al[w][buf ^ 1][l] = pre;
    __builtin_amdgcn_wave_barrier();
    buf ^= 1;
  }
}

// aggregate msg (dst-ordered) + conv bias + relu + GRU step, KBN nodes/block
__global__ __launch_bounds__(256) void kB(const float* __restrict__ msg,
                                          const int* __restrict__ dst_off,
                                          const float* __restrict__ deg,
                                          const float* __restrict__ feat_in,
                                          float* __restrict__ feat_out,
                                          const float* __restrict__ Wih,
                                          const float* __restrict__ Whh,
                                          const float* __restrict__ bih,
                                          const float* __restrict__ bhh,
                                          const float* __restrict__ cbias, int N){
  __shared__ float wih[96][33], whh[96][33];
  __shared__ float bi[96], bh[96], cb[32];
  __shared__ float msh[8][33], hsh[8][33];
  int tid = threadIdx.x;
  for (int k = tid; k < 96 * 32; k += 256){
    int g = k >> 5, o = k & 31;
    wih[g][o] = Wih[k];
    whh[g][o] = Whh[k];
  }
  if (tid < 96){ bi[tid] = bih[tid]; bh[tid] = bhh[tid]; }
  if (tid < 32) cb[tid] = cbias[tid];
  __syncthreads();
  int s = tid >> 5, o = tid & 31;
  for (int g8 = 0; g8 < KBN / 8; g8++){
    int v = blockIdx.x * KBN + g8 * 8 + s;
    if (v >= N) continue;
    int lo = dst_off[v], hi = dst_off[v + 1];
    float h = feat_in[(size_t)v * 32 + o];
    float a0 = 0.f, a1 = 0.f, a2 = 0.f, a3 = 0.f;
    int k = lo;
    for (; k + 3 < hi; k += 4){
      a0 += msg[(size_t)(k + 0) * 32 + o];
      a1 += msg[(size_t)(k + 1) * 32 + o];
      a2 += msg[(size_t)(k + 2) * 32 + o];
      a3 += msg[(size_t)(k + 3) * 32 + o];
    }
    for (; k < hi; k++) a0 += msg[(size_t)k * 32 + o];
    float acc = (a0 + a1) + (a2 + a3);
    float m = fmaxf(acc / deg[v] + cb[o], 0.f);
    msh[s][o] = m;
    hsh[s][o] = h;
    float gr = bi[o], gz = bi[32 + o], gn = bi[64 + o];
    float hr = bh[o], hz = bh[32 + o], hn = bh[64 + o];
#pragma unroll
    for (int q = 0; q < 32; q++){
      float mq = msh[s][q], hq = hsh[s][q];
      gr += mq * wih[o][q];      gz += mq * wih[32 + o][q];  gn += mq * wih[64 + o][q];
      hr += hq * whh[o][q];      hz += hq * whh[32 + o][q];  hn += hq * whh[64 + o][q];
    }
    float r = 1.f / (1.f + expf(-(gr + hr)));
    float z = 1.f / (1.f + expf(-(gz + hz)));
    float n = tanhf(gn + r * hn);
    feat_out[(size_t)v * 32 + o] = (1.f - z) * n + z * h;
  }
}

// ---------- Set2Set ----------

__global__ __launch_bounds__(256) void kLSTM(const float* __restrict__ Wih,
                                             const float* __restrict__ Whh,
                                             const float* __restrict__ bih,
                                             const float* __restrict__ bhh,
                                             float* __restrict__ q_star,
                                             float* __restrict__ hh,
                                             float* __restrict__ cc,
                                             int first){
  __shared__ float WihT[64][129];
  __shared__ float WhhT[32][129];
  __shared__ float qs[8][65];
  __shared__ float hl[8][33];
  __shared__ float gates[8][129];
  int tid = threadIdx.x;
  int rbase = blockIdx.x * 8;
  for (int k = tid; k < 128 * 64; k += 256){ int j = k & 63, g = k >> 6; WihT[j][g] = Wih[g * 64 + j]; }
  for (int k = tid; k < 128 * 32; k += 256){ int j = k & 31, g = k >> 5; WhhT[j][g] = Whh[g * 32 + j]; }
  for (int k = tid; k < 512; k += 256){ int rr = k >> 6, j = k & 63; qs[rr][j] = first ? 0.f : q_star[(rbase + rr) * 64 + j]; }
  { int rr = tid >> 5, j = tid & 31; hl[rr][j] = first ? 0.f : hh[(rbase + rr) * 32 + j]; }
  __syncthreads();
  for (int k = tid; k < 1024; k += 256){
    int rr = k >> 7, g = k & 127;
    float acc = bih[g] + bhh[g];
#pragma unroll 8
    for (int j = 0; j < 64; j++) acc += qs[rr][j] * WihT[j][g];
#pragma unroll 8
    for (int j = 0; j < 32; j++) acc += hl[rr][j] * WhhT[j][g];
    gates[rr][g] = acc;
  }
  __syncthreads();
  {
    int rr = tid >> 5, j = tid & 31;
    int row = rbase + rr;
    float iv = gates[rr][j], fv = gates[rr][32 + j], gv = gates[rr][64 + j], ov = gates[rr][96 + j];
    iv = 1.f / (1.f + expf(-iv));
    fv = 1.f / (1.f + expf(-fv));
    gv = tanhf(gv);
    ov = 1.f / (1.f + expf(-ov));
    float cprev = first ? 0.f : cc[row * 32 + j];
    float c = fv * cprev + iv * gv;
    cc[row * 32 + j] = c;
    float hv = ov * tanhf(c);
    hh[row * 32 + j] = hv;
    q_star[row * 64 + j] = hv;
  }
}

// one block per graph: attention softmax + weighted pool
__global__ __launch_bounds__(256) void kPool(const float* __restrict__ feat,
                                             const int* __restrict__ boff,
                                             const float* __restrict__ hh,
                                             float* __restrict__ q_star,
                                             float* __restrict__ e_buf){
  int b = blockIdx.x;
  int lo = boff[b], hi = boff[b + 1];
  __shared__ float q[32];
  __shared__ float wred[4];
  __shared__ float part[8][33];
  int tid = threadIdx.x;
  if (tid < 32) q[tid] = hh[b * 32 + tid];
  __syncthreads();
  int sub = tid >> 5, o = tid & 31;
  float mx = -1e30f;
  for (int i = lo + sub; i < hi; i += 8){
    float v = feat[(size_t)i * 32 + o] * q[o];
#pragma unroll
    for (int d = 16; d; d >>= 1) v += __shfl_xor(v, d, 32);
    if (o == 0) e_buf[i] = v;
    mx = fmaxf(mx, v);
  }
#pragma unroll
  for (int d = 32; d; d >>= 1) mx = fmaxf(mx, __shfl_xor(mx, d, 64));
  if ((tid & 63) == 0) wred[tid >> 6] = mx;
  __syncthreads();
  mx = fmaxf(fmaxf(wred[0], wred[1]), fmaxf(wred[2], wred[3]));
  __syncthreads();
  float sm = 0.f;
  for (int i = lo + tid; i < hi; i += 256){
    float w = expf(e_buf[i] - mx);
    e_buf[i] = w;
    sm += w;
  }
#pragma unroll
  for (int d = 32; d; d >>= 1) sm += __shfl_xor(sm, d, 64);
  if ((tid & 63) == 0) wred[tid >> 6] = sm;
  __syncthreads();
  float denom = wred[0] + wred[1] + wred[2] + wred[3];
  denom = fmaxf(denom, 1e-30f);
  __syncthreads();
  float acc = 0.f;
  for (int i = lo + sub; i < hi; i += 8){
    acc += e_buf[i] * feat[(size_t)i * 32 + o];
  }
  part[sub][o] = acc;
  __syncthreads();
  if (tid < 32){
    float r = 0.f;
#pragma unroll
    for (int s2 = 0; s2 < 8; s2++) r += part[s2][tid];
    q_star[b * 64 + 32 + tid] = r / denom;
  }
}

__global__ __launch_bounds__(256) void kCopy(const float* __restrict__ src,
                                             float* __restrict__ dst, int n){
  int i = blockIdx.x * 256 + threadIdx.x;
  if (i < n) dst[i] = src[i];
}

// ---------- host ----------

extern "C" void kernel_launch(void* const* d_in, const int* in_sizes, int n_in,
                              void* d_out, int out_size, void* d_ws, size_t ws_size,
                              hipStream_t stream){
  (void)n_in; (void)out_size; (void)ws_size;
  const float* x        = (const float*)d_in[0];
  const int*   ei       = (const int*)  d_in[1];
  const float* eattr    = (const float*)d_in[2];
  const int*   batch    = (const int*)  d_in[3];
  const float* lin0_w   = (const float*)d_in[4];
  const float* lin0_b   = (const float*)d_in[5];
  const float* mlp_w1   = (const float*)d_in[6];
  const float* mlp_b1   = (const float*)d_in[7];
  const float* mlp_w2   = (const float*)d_in[8];
  const float* mlp_b2   = (const float*)d_in[9];
  const float* conv_b   = (const float*)d_in[10];
  const float* gru_wih  = (const float*)d_in[11];
  const float* gru_whh  = (const float*)d_in[12];
  const float* gru_bih  = (const float*)d_in[13];
  const float* gru_bhh  = (const float*)d_in[14];
  const float* lstm_wih = (const float*)d_in[15];
  const float* lstm_whh = (const float*)d_in[16];
  const float* lstm_bih = (const float*)d_in[17];
  const float* lstm_bhh = (const float*)d_in[18];

  int N = in_sizes[0] / NFEAT;
  int E = in_sizes[1] / 2;

  char* ws = (char*)d_ws;
  size_t off = 0;
  auto alloc = [&](size_t bytes) -> char* {
    char* p = ws + off;
    off = align_up(off + bytes, 256);
    return p;
  };

  float* feat0  = (float*)alloc((size_t)N * D * 4);
  float* feat1  = (float*)alloc((size_t)N * D * 4);
  float* msg    = (float*)alloc((size_t)E * D * 4);
  unsigned int* Mpk = (unsigned int*)alloc((size_t)16 * TCOLS * 4);
  unsigned int* apk = (unsigned int*)alloc((size_t)E * 32 * 4);
  float* e_buf  = (float*)alloc((size_t)N * 4);
  float* deg    = (float*)alloc((size_t)N * 4);
  float* q_star = (float*)alloc((size_t)NB * 64 * 4);
  float* hhb    = (float*)alloc((size_t)NB * 32 * 4);
  float* ccb    = (float*)alloc((size_t)NB * 32 * 4);
  int* cnt_src  = (int*)alloc((size_t)N * CPAD * 4);   // padded: 1 counter / 64B
  int* cnt_dst  = (int*)alloc((size_t)N * CPAD * 4);
  int* rs       = (int*)alloc((size_t)E * 4);
  int* rd       = (int*)alloc((size_t)E * 4);
  int* src_off  = (int*)alloc((size_t)(N + 1) * 4);
  int* dst_off  = (int*)alloc((size_t)(N + 1) * 4);
  int* boff     = (int*)alloc((size_t)(NB + 1) * 4);
  int* so_src   = (int*)alloc((size_t)E * 4);
  int* so_eid   = (int*)alloc((size_t)E * 4);
  int* s2d      = (int*)alloc((size_t)E * 4);

  // zero the padded counters
  (void)hipMemsetAsync(cnt_src, 0, (size_t)N * CPAD * 4 * 2, stream);

  kBuildMpk<<<(16 * TCOLS + 255) / 256, 256, 0, stream>>>(mlp_w2, mlp_b2, Mpk);
  kLin0<<<(N * 32 + 255) / 256, 256, 0, stream>>>(x, lin0_w, lin0_b, feat0, N);
  kCountRank<<<(E + 255) / 256, 256, 0, stream>>>(ei, cnt_src, cnt_dst, rs, rd, E);
  kScan<<<3, 256, 0, stream>>>(cnt_src, cnt_dst, batch, src_off, dst_off, boff, deg, N, NB);
  kPlace<<<(E + 255) / 256, 256, 0, stream>>>(ei, src_off, dst_off, rs, rd,
                                              so_src, so_eid, s2d, E);
  kEdgeMLPpk<<<((size_t)E * 32 + 255) / 256, 256, 0, stream>>>(eattr, mlp_w1, mlp_b1,
                                                               so_eid, apk, E);

  int blocksTA = (N + CHUNK - 1) / CHUNK;
  float* fcur = feat0;
  float* fnext = feat1;
  for (int t = 0; t < 3; t++){
    kTA<<<blocksTA, 256, 0, stream>>>(fcur, Mpk, so_src, s2d, apk, src_off, msg, N);
    kB<<<(N + KBN - 1) / KBN, 256, 0, stream>>>(msg, dst_off, deg, fcur, fnext,
                                                gru_wih, gru_whh, gru_bih, gru_bhh, conv_b, N);
    float* tmp = fcur; fcur = fnext; fnext = tmp;
  }

  kCopy<<<(N * D + 255) / 256, 256, 0, stream>>>(fcur, (float*)d_out + NB * 64, N * D);

  for (int s = 0; s < 3; s++){
    kLSTM<<<8, 256, 0, stream>>>(lstm_wih, lstm_whh, lstm_bih, lstm_bhh, q_star, hhb, ccb,
                                 s == 0 ? 1 : 0);
    kPool<<<NB, 256, 0, stream>>>(fcur, boff, hhb, q_star, e_buf);
  }

  kCopy<<<(NB * 64 + 255) / 256, 256, 0, stream>>>(q_star, (float*)d_out, NB * 64);
}

// Round 9
// 467.899 us; speedup vs baseline: 4.6467x; 1.3594x over previous
//
#include <hip/hip_runtime.h>
#include <hip/hip_fp16.h>

#define NFEAT 16
#define D 32
#define NB 64        // num graphs
#define TCOLS 2080   // 65*32: h=0..63 from w2, h=64 row from b2
#define CHUNK 8      // nodes per fused block
#define TROW 34      // u32 per (node,o) LDS row (64 f16 + 2 pad) -> conflict-free b64
#define CPAD 16      // counter padding: one counter per 64B line
#define KBN 16       // nodes per kB block

static inline size_t align_up(size_t x, size_t a){ return (x + a - 1) & ~(a - 1); }

typedef _Float16 f16x2 __attribute__((ext_vector_type(2)));
typedef _Float16 f16x8 __attribute__((ext_vector_type(8)));
typedef float f32x4 __attribute__((ext_vector_type(4)));

__device__ inline unsigned int pk2(float a, float b){
  __half2 h = __floats2half2_rn(a, b);
  union { __half2 h; unsigned int u; } cv; cv.h = h; return cv.u;
}

__device__ inline float dot2(unsigned int a, unsigned int b, float c){
  union { unsigned int u; f16x2 h; } ua, ub; ua.u = a; ub.u = b;
#if __has_builtin(__builtin_amdgcn_fdot2)
  return __builtin_amdgcn_fdot2(ua.h, ub.h, c, false);
#else
  return c + (float)ua.h[0] * (float)ub.h[0] + (float)ua.h[1] * (float)ub.h[1];
#endif
}

// ---------- setup kernels ----------

// B-fragment layout for v_mfma_f32_16x16x32_f16:
// tile c (c=0..129) covers cols c*16..c*16+15 (col = h*32+o).
// lane l: col = c*16 + (l&15), k = (l>>4)*8 + e (e=0..7, u32 j2 holds e=2*j2, 2*j2+1).
// M[k][col] = w2[h*1024 + k*32 + o] (h<64), b2[k*32+o] (h==64); k = inner dim (32).
__global__ __launch_bounds__(256) void kBuildMpk2(const float* __restrict__ w2,
                                                  const float* __restrict__ b2,
                                                  unsigned int* __restrict__ Mpk2){
  int idx = blockIdx.x * 256 + threadIdx.x;
  if (idx >= 130 * 64 * 4) return;
  int j2 = idx & 3;
  int l  = (idx >> 2) & 63;
  int c  = idx >> 8;
  int col = c * 16 + (l & 15);
  int h = col >> 5, o = col & 31;
  int ke = (l >> 4) * 8 + 2 * j2;
  float f0, f1;
  if (h < 64){
    f0 = w2[h * 1024 + ke * 32 + o];
    f1 = w2[h * 1024 + (ke + 1) * 32 + o];
  } else {
    f0 = b2[ke * 32 + o];
    f1 = b2[(ke + 1) * 32 + o];
  }
  Mpk2[idx] = pk2(f0, f1);
}

__global__ __launch_bounds__(256) void kLin0(const float* __restrict__ x,
                                             const float* __restrict__ w,
                                             const float* __restrict__ b,
                                             float* __restrict__ feat, int N){
  int idx = blockIdx.x * 256 + threadIdx.x;
  int u = idx >> 5, o = idx & 31;
  if (u >= N) return;
  float acc = b[o];
#pragma unroll
  for (int i = 0; i < NFEAT; i++) acc += x[(size_t)u * NFEAT + i] * w[i * 32 + o];
  feat[idx] = fmaxf(acc, 0.f);
}

// counts (padded) + ranks in one pass
__global__ __launch_bounds__(256) void kCountRank(const int* __restrict__ ei,
                                                  int* __restrict__ cnt_src,
                                                  int* __restrict__ cnt_dst,
                                                  int* __restrict__ rs,
                                                  int* __restrict__ rd, int E){
  int e = blockIdx.x * 256 + threadIdx.x;
  if (e >= E) return;
  int s = ei[e], d = ei[E + e];
  rs[e] = atomicAdd(&cnt_src[(size_t)s * CPAD], 1);
  rd[e] = atomicAdd(&cnt_dst[(size_t)d * CPAD], 1);
}

// exclusive scan of padded counts; blockIdx 0: src, 1: dst (+deg), 2: batch via bsearch
__global__ __launch_bounds__(256) void kScan(const int* __restrict__ cnt_src,
                                             const int* __restrict__ cnt_dst,
                                             const int* __restrict__ batch,
                                             int* src_off, int* dst_off, int* boff,
                                             float* deg, int N, int B){
  if (blockIdx.x == 2){
    int t = threadIdx.x;
    if (t <= B){
      int lo = 0, hi = N;
      while (lo < hi){ int mid = (lo + hi) >> 1; if (batch[mid] < t) lo = mid + 1; else hi = mid; }
      boff[t] = lo;
    }
    return;
  }
  __shared__ int part[256];
  const int* cnt = (blockIdx.x == 0) ? cnt_src : cnt_dst;
  int* off = (blockIdx.x == 0) ? src_off : dst_off;
  int n = N;
  int t = threadIdx.x;
  int chunk = (n + 255) / 256;
  int lo = t * chunk, hi = min(n, lo + chunk);
  int s = 0;
  for (int i = lo; i < hi; i++) s += cnt[(size_t)i * CPAD];
  part[t] = s; __syncthreads();
  for (int d = 1; d < 256; d <<= 1){
    int v = (t >= d) ? part[t - d] : 0;
    __syncthreads();
    part[t] += v;
    __syncthreads();
  }
  int run = (t == 0) ? 0 : part[t - 1];
  for (int i = lo; i < hi; i++){ off[i] = run; run += cnt[(size_t)i * CPAD]; }
  if (t == 255) off[n] = part[255];
  if (blockIdx.x == 1){
    for (int i = lo; i < hi; i++) deg[i] = (float)max(cnt[(size_t)i * CPAD], 1);
  }
}

// atomic-free placement using precomputed ranks
__global__ __launch_bounds__(256) void kPlace(const int* __restrict__ ei,
                                              const int* __restrict__ src_off,
                                              const int* __restrict__ dst_off,
                                              const int* __restrict__ rs,
                                              const int* __restrict__ rd,
                                              int* __restrict__ so_src,
                                              int* __restrict__ so_eid,
                                              int* __restrict__ s2d, int E){
  int e = blockIdx.x * 256 + threadIdx.x;
  if (e >= E) return;
  int s = ei[e], d = ei[E + e];
  int ps = src_off[s] + rs[e];
  so_src[ps] = s;
  so_eid[ps] = e;
  s2d[ps] = dst_off[d] + rd[e];
}

// aperm_pk[j][h2] = pack(relu(mlp)[2*h2], relu(mlp)[2*h2+1]), j in src-CSR order
__global__ __launch_bounds__(256) void kEdgeMLPpk(const float* __restrict__ ea,
                                                  const float* __restrict__ w1,
                                                  const float* __restrict__ b1,
                                                  const int* __restrict__ so_eid,
                                                  unsigned int* __restrict__ apk, int E){
  int idx = blockIdx.x * 256 + threadIdx.x;
  int j = idx >> 5, h2 = idx & 31;
  if (j >= E) return;
  int e = so_eid[j];
  const float* eap = ea + (size_t)e * 5;
  float q0 = eap[0], q1 = eap[1], q2 = eap[2], q3 = eap[3], q4 = eap[4];
  int h = 2 * h2;
  float lo = b1[h]     + q0 * w1[h]       + q1 * w1[64 + h]     + q2 * w1[128 + h]
                       + q3 * w1[192 + h] + q4 * w1[256 + h];
  float hi = b1[h + 1] + q0 * w1[h + 1]   + q1 * w1[64 + h + 1] + q2 * w1[128 + h + 1]
                       + q3 * w1[192 + h + 1] + q4 * w1[256 + h + 1];
  apk[(size_t)j * 32 + h2] = pk2(fmaxf(lo, 0.f), fmaxf(hi, 0.f));
}

// ---------- fused per-iteration kernel ----------
// Phase A: T = feat_chunk @ M via MFMA (16x16x32 f16). 65 pair-jobs:
// job<64: t=job>>1 (h2), s=job&1 (o half); tiles 4t+s (h even) and 4t+2+s (h odd),
// C pairs packed f16 into swizzled Tp. job==64: bias row h=64 -> bias_l f32.
// Phase B: per-wave edge processing with double-buffered apk prefetch (unchanged).
__global__ __launch_bounds__(256, 4) void kTA(const float* __restrict__ feat,
                                              const uint4* __restrict__ Mpk2,
                                              const int* __restrict__ so_src,
                                              const int* __restrict__ s2d,
                                              const unsigned int* __restrict__ apk,
                                              const int* __restrict__ src_off,
                                              float* __restrict__ msg,
                                              int N){
  __shared__ unsigned int Tp[CHUNK * 32 * TROW];  // 34816 B
  __shared__ float bias_l[CHUNK][33];
  __shared__ unsigned int al[4][2][64];           // per-wave double-buffered packed a
  int tid = threadIdx.x;
  int c0 = blockIdx.x * CHUNK;
  int c1 = min(c0 + CHUNK, N);
  int nvalid = c1 - c0;
  int w = tid >> 6, l = tid & 63;

  // ---- phase A: A-fragment (row = l&15 node, k = (l>>4)*8+e) ----
  {
    int nodeA = c0 + (l & 15);
    if (nodeA > c1 - 1) nodeA = c1 - 1;
    int k0 = (l >> 4) * 8;
    const float* fr = feat + (size_t)nodeA * 32 + k0;
    float4 fa = *(const float4*)fr;
    float4 fb = *(const float4*)(fr + 4);
    union { uint4 u; f16x8 h; } A;
    A.u.x = pk2(fa.x, fa.y); A.u.y = pk2(fa.z, fa.w);
    A.u.z = pk2(fb.x, fb.y); A.u.w = pk2(fb.z, fb.w);

    for (int job = w; job < 65; job += 4){
      int cE, cO, s = 0;
      if (job < 64){ int t = job >> 1; s = job & 1; cE = 4 * t + s; cO = 4 * t + 2 + s; }
      else { cE = 128; cO = 129; }
      union { uint4 u; f16x8 h; } BE, BO;
      BE.u = Mpk2[cE * 64 + l];
      BO.u = Mpk2[cO * 64 + l];
      f32x4 z = {0.f, 0.f, 0.f, 0.f};
      f32x4 dE = __builtin_amdgcn_mfma_f32_16x16x32_f16(A.h, BE.h, z, 0, 0, 0);
      f32x4 dO = __builtin_amdgcn_mfma_f32_16x16x32_f16(A.h, BO.h, z, 0, 0, 0);
      if (job < 64){
        int t = job >> 1;
        int o = s * 16 + (l & 15);
#pragma unroll
        for (int r = 0; r < 4; r++){
          int nn = (l >> 4) * 4 + r;
          if (nn < nvalid) Tp[nn * 1088 + o * TROW + t] = pk2(dE[r], dO[r]);
        }
      } else {
#pragma unroll
        for (int r = 0; r < 4; r++){
          int nn = (l >> 4) * 4 + r;
          if (nn < nvalid){
            bias_l[nn][l & 15]      = dE[r];
            bias_l[nn][16 + (l & 15)] = dO[r];
          }
        }
      }
    }
  }
  __syncthreads();

  // ---- phase B: per-wave edge processing, double-buffered apk prefetch ----
  int jj = l >> 5, o = l & 31;
  int e0 = src_off[c0], e1 = src_off[c1];
  int jb = e0 + w * 2;
  int buf = 0;
  if (jb < e1){
    if (jb + jj < e1) al[w][0][l] = apk[(size_t)jb * 32 + l];
  }
  __builtin_amdgcn_wave_barrier();
  for (; jb < e1; jb += 8){
    int jbn = jb + 8;
    unsigned int pre = 0;
    bool pv = (jbn + jj < e1);
    if (pv) pre = apk[(size_t)jbn * 32 + l];
    int j = jb + jj;
    if (j < e1){
      int u = so_src[j] - c0;
      float s0 = bias_l[u][o], s1 = 0.f;
      const unsigned int* Tr = Tp + u * 1088 + o * TROW;
      const unsigned int* ap = &al[w][buf][jj * 32];
#pragma unroll
      for (int g = 0; g < 8; g++){
        uint2 tv = *(const uint2*)(Tr + g * 4);
        uint2 tw = *(const uint2*)(Tr + g * 4 + 2);
        uint2 av = *(const uint2*)(ap + g * 4);
        uint2 aw = *(const uint2*)(ap + g * 4 + 2);
        s0 = dot2(av.x, tv.x, s0);
        s1 = dot2(av.y, tv.y, s1);
        s0 = dot2(aw.x, tw.x, s0);
        s1 = dot2(aw.y, tw.y, s1);
      }
      msg[(size_t)s2d[j] * 32 + o] = s0 + s1;
    }
    __builtin_amdgcn_wave_barrier();
    if (pv) al[w][buf ^ 1][l] = pre;
    __builtin_amdgcn_wave_barrier();
    buf ^= 1;
  }
}

// aggregate msg (dst-ordered) + conv bias + relu + GRU (packed-f16 dot2)
__global__ __launch_bounds__(256) void kB(const float* __restrict__ msg,
                                          const int* __restrict__ dst_off,
                                          const float* __restrict__ deg,
                                          const float* __restrict__ feat_in,
                                          float* __restrict__ feat_out,
                                          float* __restrict__ out2,
                                          const float* __restrict__ Wih,
                                          const float* __restrict__ Whh,
                                          const float* __restrict__ bih,
                                          const float* __restrict__ bhh,
                                          const float* __restrict__ cbias, int N){
  __shared__ unsigned int wihpk[96][17], whhpk[96][17];
  __shared__ float bi[96], bh[96], cb[32];
  __shared__ unsigned int mshpk[8][17], hshpk[8][17];
  int tid = threadIdx.x;
  for (int k = tid; k < 96 * 16; k += 256){
    int g = k >> 4, q2 = k & 15;
    wihpk[g][q2] = pk2(Wih[g * 32 + 2 * q2], Wih[g * 32 + 2 * q2 + 1]);
    whhpk[g][q2] = pk2(Whh[g * 32 + 2 * q2], Whh[g * 32 + 2 * q2 + 1]);
  }
  if (tid < 96){ bi[tid] = bih[tid]; bh[tid] = bhh[tid]; }
  if (tid < 32) cb[tid] = cbias[tid];
  __syncthreads();
  int s = tid >> 5, o = tid & 31;
  for (int g8 = 0; g8 < KBN / 8; g8++){
    int v = blockIdx.x * KBN + g8 * 8 + s;
    if (v < N){
      int lo = dst_off[v], hi = dst_off[v + 1];
      float h = feat_in[(size_t)v * 32 + o];
      float a0 = 0.f, a1 = 0.f, a2 = 0.f, a3 = 0.f;
      int k = lo;
      for (; k + 3 < hi; k += 4){
        a0 += msg[(size_t)(k + 0) * 32 + o];
        a1 += msg[(size_t)(k + 1) * 32 + o];
        a2 += msg[(size_t)(k + 2) * 32 + o];
        a3 += msg[(size_t)(k + 3) * 32 + o];
      }
      for (; k < hi; k++) a0 += msg[(size_t)k * 32 + o];
      float acc = (a0 + a1) + (a2 + a3);
      float m = fmaxf(acc / deg[v] + cb[o], 0.f);
      float m1 = __shfl_down(m, 1);
      float h1 = __shfl_down(h, 1);
      if (!(o & 1)){
        mshpk[s][o >> 1] = pk2(m, m1);
        hshpk[s][o >> 1] = pk2(h, h1);
      }
      float gr = bi[o], gz = bi[32 + o], gn = bi[64 + o];
      float hr = bh[o], hz = bh[32 + o], hn = bh[64 + o];
#pragma unroll
      for (int q2 = 0; q2 < 16; q2++){
        unsigned int mq = mshpk[s][q2], hq = hshpk[s][q2];
        gr = dot2(mq, wihpk[o][q2], gr);
        gz = dot2(mq, wihpk[32 + o][q2], gz);
        gn = dot2(mq, wihpk[64 + o][q2], gn);
        hr = dot2(hq, whhpk[o][q2], hr);
        hz = dot2(hq, whhpk[32 + o][q2], hz);
        hn = dot2(hq, whhpk[64 + o][q2], hn);
      }
      float r = 1.f / (1.f + expf(-(gr + hr)));
      float z = 1.f / (1.f + expf(-(gz + hz)));
      float n = tanhf(gn + r * hn);
      float val = (1.f - z) * n + z * h;
      feat_out[(size_t)v * 32 + o] = val;
      if (out2) out2[(size_t)v * 32 + o] = val;
    }
  }
}

// ---------- fused Set2Set: one block per graph, 3 LSTM+pool steps in-block ----------
__global__ __launch_bounds__(256) void kS2S(const float* __restrict__ feat,
                                            const int* __restrict__ boff,
                                            const float* __restrict__ Wih,
                                            const float* __restrict__ Whh,
                                            const float* __restrict__ bih,
                                            const float* __restrict__ bhh,
                                            float* __restrict__ e_buf,
                                            float* __restrict__ out){
  int b = blockIdx.x;
  __shared__ float WihL[128][65];
  __shared__ float WhhL[128][33];
  __shared__ float qs[64], hst[32], cst[32], garr[128];
  __shared__ float wred[4];
  __shared__ float part[8][33];
  int tid = threadIdx.x;
  for (int k = tid; k < 128 * 64; k += 256) WihL[k >> 6][k & 63] = Wih[k];
  for (int k = tid; k < 128 * 32; k += 256) WhhL[k >> 5][k & 31] = Whh[k];
  if (tid < 64) qs[tid] = 0.f;
  if (tid < 32){ hst[tid] = 0.f; cst[tid] = 0.f; }
  __syncthreads();
  int lo = boff[b], hi = boff[b + 1];
  int sub = tid >> 5, o = tid & 31;
  for (int step = 0; step < 3; step++){
    if (tid < 128){
      int g = tid;
      float acc = bih[g] + bhh[g];
#pragma unroll 8
      for (int j = 0; j < 64; j++) acc += qs[j] * WihL[g][j];
#pragma unroll 8
      for (int j = 0; j < 32; j++) acc += hst[j] * WhhL[g][j];
      garr[g] = acc;
    }
    __syncthreads();
    if (tid < 32){
      float iv = 1.f / (1.f + expf(-garr[tid]));
      float fv = 1.f / (1.f + expf(-garr[32 + tid]));
      float gv = tanhf(garr[64 + tid]);
      float ov = 1.f / (1.f + expf(-garr[96 + tid]));
      float c = fv * cst[tid] + iv * gv;
      cst[tid] = c;
      float hv = ov * tanhf(c);
      hst[tid] = hv;
      qs[tid] = hv;
    }
    __syncthreads();
    // pool with q = hst
    float mx = -1e30f;
    for (int i = lo + sub; i < hi; i += 8){
      float v = feat[(size_t)i * 32 + o] * hst[o];
#pragma unroll
      for (int d2 = 16; d2; d2 >>= 1) v += __shfl_xor(v, d2, 32);
      if (o == 0) e_buf[i] = v;
      mx = fmaxf(mx, v);
    }
#pragma unroll
    for (int d2 = 32; d2; d2 >>= 1) mx = fmaxf(mx, __shfl_xor(mx, d2, 64));
    if ((tid & 63) == 0) wred[tid >> 6] = mx;
    __syncthreads();
    mx = fmaxf(fmaxf(wred[0], wred[1]), fmaxf(wred[2], wred[3]));
    __syncthreads();
    float sm = 0.f;
    for (int i = lo + tid; i < hi; i += 256){
      float w2 = expf(e_buf[i] - mx);
      e_buf[i] = w2;
      sm += w2;
    }
#pragma unroll
    for (int d2 = 32; d2; d2 >>= 1) sm += __shfl_xor(sm, d2, 64);
    if ((tid & 63) == 0) wred[tid >> 6] = sm;
    __syncthreads();
    float denom = fmaxf(wred[0] + wred[1] + wred[2] + wred[3], 1e-30f);
    __syncthreads();
    float acc2 = 0.f;
    for (int i = lo + sub; i < hi; i += 8){
      acc2 += e_buf[i] * feat[(size_t)i * 32 + o];
    }
    part[sub][o] = acc2;
    __syncthreads();
    if (tid < 32){
      float r2 = 0.f;
#pragma unroll
      for (int s2 = 0; s2 < 8; s2++) r2 += part[s2][tid];
      qs[32 + tid] = r2 / denom;
    }
    __syncthreads();
  }
  if (tid < 64) out[b * 64 + tid] = qs[tid];
}

// ---------- host ----------

extern "C" void kernel_launch(void* const* d_in, const int* in_sizes, int n_in,
                              void* d_out, int out_size, void* d_ws, size_t ws_size,
                              hipStream_t stream){
  (void)n_in; (void)out_size; (void)ws_size;
  const float* x        = (const float*)d_in[0];
  const int*   ei       = (const int*)  d_in[1];
  const float* eattr    = (const float*)d_in[2];
  const int*   batch    = (const int*)  d_in[3];
  const float* lin0_w   = (const float*)d_in[4];
  const float* lin0_b   = (const float*)d_in[5];
  const float* mlp_w1   = (const float*)d_in[6];
  const float* mlp_b1   = (const float*)d_in[7];
  const float* mlp_w2   = (const float*)d_in[8];
  const float* mlp_b2   = (const float*)d_in[9];
  const float* conv_b   = (const float*)d_in[10];
  const float* gru_wih  = (const float*)d_in[11];
  const float* gru_whh  = (const float*)d_in[12];
  const float* gru_bih  = (const float*)d_in[13];
  const float* gru_bhh  = (const float*)d_in[14];
  const float* lstm_wih = (const float*)d_in[15];
  const float* lstm_whh = (const float*)d_in[16];
  const float* lstm_bih = (const float*)d_in[17];
  const float* lstm_bhh = (const float*)d_in[18];

  int N = in_sizes[0] / NFEAT;
  int E = in_sizes[1] / 2;

  char* ws = (char*)d_ws;
  size_t off = 0;
  auto alloc = [&](size_t bytes) -> char* {
    char* p = ws + off;
    off = align_up(off + bytes, 256);
    return p;
  };

  float* feat0  = (float*)alloc((size_t)N * D * 4);
  float* feat1  = (float*)alloc((size_t)N * D * 4);
  float* msg    = (float*)alloc((size_t)E * D * 4);
  unsigned int* Mpk2 = (unsigned int*)alloc((size_t)130 * 64 * 4 * 4);
  unsigned int* apk = (unsigned int*)alloc((size_t)E * 32 * 4);
  float* e_buf  = (float*)alloc((size_t)N * 4);
  float* deg    = (float*)alloc((size_t)N * 4);
  int* cnt_src  = (int*)alloc((size_t)N * CPAD * 4);   // padded: 1 counter / 64B
  int* cnt_dst  = (int*)alloc((size_t)N * CPAD * 4);
  int* rs       = (int*)alloc((size_t)E * 4);
  int* rd       = (int*)alloc((size_t)E * 4);
  int* src_off  = (int*)alloc((size_t)(N + 1) * 4);
  int* dst_off  = (int*)alloc((size_t)(N + 1) * 4);
  int* boff     = (int*)alloc((size_t)(NB + 1) * 4);
  int* so_src   = (int*)alloc((size_t)E * 4);
  int* so_eid   = (int*)alloc((size_t)E * 4);
  int* s2d      = (int*)alloc((size_t)E * 4);

  // zero the padded counters
  (void)hipMemsetAsync(cnt_src, 0, (size_t)N * CPAD * 4 * 2, stream);

  kBuildMpk2<<<(130 * 64 * 4 + 255) / 256, 256, 0, stream>>>(mlp_w2, mlp_b2, Mpk2);
  kLin0<<<(N * 32 + 255) / 256, 256, 0, stream>>>(x, lin0_w, lin0_b, feat0, N);
  kCountRank<<<(E + 255) / 256, 256, 0, stream>>>(ei, cnt_src, cnt_dst, rs, rd, E);
  kScan<<<3, 256, 0, stream>>>(cnt_src, cnt_dst, batch, src_off, dst_off, boff, deg, N, NB);
  kPlace<<<(E + 255) / 256, 256, 0, stream>>>(ei, src_off, dst_off, rs, rd,
                                              so_src, so_eid, s2d, E);
  kEdgeMLPpk<<<((size_t)E * 32 + 255) / 256, 256, 0, stream>>>(eattr, mlp_w1, mlp_b1,
                                                               so_eid, apk, E);

  int blocksTA = (N + CHUNK - 1) / CHUNK;
  float* fcur = feat0;
  float* fnext = feat1;
  for (int t = 0; t < 3; t++){
    kTA<<<blocksTA, 256, 0, stream>>>(fcur, (const uint4*)Mpk2, so_src, s2d, apk,
                                      src_off, msg, N);
    float* out2 = (t == 2) ? ((float*)d_out + NB * 64) : nullptr;
    kB<<<(N + KBN - 1) / KBN, 256, 0, stream>>>(msg, dst_off, deg, fcur, fnext, out2,
                                                gru_wih, gru_whh, gru_bih, gru_bhh,
                                                conv_b, N);
    float* tmp = fcur; fcur = fnext; fnext = tmp;
  }

  kS2S<<<NB, 256, 0, stream>>>(fcur, boff, lstm_wih, lstm_whh, lstm_bih, lstm_bhh,
                               e_buf, (float*)d_out);
}

// Round 10
// 412.346 us; speedup vs baseline: 5.2727x; 1.1347x over previous
//
#include <hip/hip_runtime.h>
#include <hip/hip_fp16.h>

#define NFEAT 16
#define D 32
#define NB 64        // num graphs
#define TCOLS 2080   // 65*32: h=0..63 from w2, h=64 row from b2
#define CHUNK 8      // nodes per fused block
#define TROW 34      // u32 per (node,o) LDS row (64 f16 + 2 pad) -> conflict-free b64
#define CPAD 16      // counter padding: one counter per 64B line
#define KBN 16       // nodes per kB block

static inline size_t align_up(size_t x, size_t a){ return (x + a - 1) & ~(a - 1); }

typedef _Float16 f16x2 __attribute__((ext_vector_type(2)));
typedef _Float16 f16x8 __attribute__((ext_vector_type(8)));
typedef float f32x4 __attribute__((ext_vector_type(4)));

__device__ inline unsigned int pk2(float a, float b){
  __half2 h = __floats2half2_rn(a, b);
  union { __half2 h; unsigned int u; } cv; cv.h = h; return cv.u;
}

__device__ inline float dot2(unsigned int a, unsigned int b, float c){
  union { unsigned int u; f16x2 h; } ua, ub; ua.u = a; ub.u = b;
#if __has_builtin(__builtin_amdgcn_fdot2)
  return __builtin_amdgcn_fdot2(ua.h, ub.h, c, false);
#else
  return c + (float)ua.h[0] * (float)ub.h[0] + (float)ua.h[1] * (float)ub.h[1];
#endif
}

// ---------- setup kernels ----------

// B-fragment layout for v_mfma_f32_16x16x32_f16:
// tile c (c=0..129) covers cols c*16..c*16+15 (col = h*32+o).
// lane l: col = c*16 + (l&15), k = (l>>4)*8 + e (u32 j2 holds e=2*j2, 2*j2+1).
__global__ __launch_bounds__(256) void kBuildMpk2(const float* __restrict__ w2,
                                                  const float* __restrict__ b2,
                                                  unsigned int* __restrict__ Mpk2){
  int idx = blockIdx.x * 256 + threadIdx.x;
  if (idx >= 130 * 64 * 4) return;
  int j2 = idx & 3;
  int l  = (idx >> 2) & 63;
  int c  = idx >> 8;
  int col = c * 16 + (l & 15);
  int h = col >> 5, o = col & 31;
  int ke = (l >> 4) * 8 + 2 * j2;
  float f0, f1;
  if (h < 64){
    f0 = w2[h * 1024 + ke * 32 + o];
    f1 = w2[h * 1024 + (ke + 1) * 32 + o];
  } else {
    f0 = b2[ke * 32 + o];
    f1 = b2[(ke + 1) * 32 + o];
  }
  Mpk2[idx] = pk2(f0, f1);
}

__global__ __launch_bounds__(256) void kLin0(const float* __restrict__ x,
                                             const float* __restrict__ w,
                                             const float* __restrict__ b,
                                             float* __restrict__ feat, int N){
  int idx = blockIdx.x * 256 + threadIdx.x;
  int u = idx >> 5, o = idx & 31;
  if (u >= N) return;
  float acc = b[o];
#pragma unroll
  for (int i = 0; i < NFEAT; i++) acc += x[(size_t)u * NFEAT + i] * w[i * 32 + o];
  feat[idx] = fmaxf(acc, 0.f);
}

// counts (padded) + ranks in one pass
__global__ __launch_bounds__(256) void kCountRank(const int* __restrict__ ei,
                                                  int* __restrict__ cnt_src,
                                                  int* __restrict__ cnt_dst,
                                                  int* __restrict__ rs,
                                                  int* __restrict__ rd, int E){
  int e = blockIdx.x * 256 + threadIdx.x;
  if (e >= E) return;
  int s = ei[e], d = ei[E + e];
  rs[e] = atomicAdd(&cnt_src[(size_t)s * CPAD], 1);
  rd[e] = atomicAdd(&cnt_dst[(size_t)d * CPAD], 1);
}

// exclusive scan of padded counts; blockIdx 0: src, 1: dst (+deg), 2: batch via bsearch
__global__ __launch_bounds__(256) void kScan(const int* __restrict__ cnt_src,
                                             const int* __restrict__ cnt_dst,
                                             const int* __restrict__ batch,
                                             int* src_off, int* dst_off, int* boff,
                                             float* deg, int N, int B){
  if (blockIdx.x == 2){
    int t = threadIdx.x;
    if (t <= B){
      int lo = 0, hi = N;
      while (lo < hi){ int mid = (lo + hi) >> 1; if (batch[mid] < t) lo = mid + 1; else hi = mid; }
      boff[t] = lo;
    }
    return;
  }
  __shared__ int part[256];
  const int* cnt = (blockIdx.x == 0) ? cnt_src : cnt_dst;
  int* off = (blockIdx.x == 0) ? src_off : dst_off;
  int n = N;
  int t = threadIdx.x;
  int chunk = (n + 255) / 256;
  int lo = t * chunk, hi = min(n, lo + chunk);
  int s = 0;
  for (int i = lo; i < hi; i++) s += cnt[(size_t)i * CPAD];
  part[t] = s; __syncthreads();
  for (int d = 1; d < 256; d <<= 1){
    int v = (t >= d) ? part[t - d] : 0;
    __syncthreads();
    part[t] += v;
    __syncthreads();
  }
  int run = (t == 0) ? 0 : part[t - 1];
  for (int i = lo; i < hi; i++){ off[i] = run; run += cnt[(size_t)i * CPAD]; }
  if (t == 255) off[n] = part[255];
  if (blockIdx.x == 1){
    for (int i = lo; i < hi; i++) deg[i] = (float)max(cnt[(size_t)i * CPAD], 1);
  }
}

// atomic-free placement using precomputed ranks
__global__ __launch_bounds__(256) void kPlace(const int* __restrict__ ei,
                                              const int* __restrict__ src_off,
                                              const int* __restrict__ dst_off,
                                              const int* __restrict__ rs,
                                              const int* __restrict__ rd,
                                              int* __restrict__ so_src,
                                              int* __restrict__ so_eid,
                                              int* __restrict__ s2d, int E){
  int e = blockIdx.x * 256 + threadIdx.x;
  if (e >= E) return;
  int s = ei[e], d = ei[E + e];
  int ps = src_off[s] + rs[e];
  so_src[ps] = s;
  so_eid[ps] = e;
  s2d[ps] = dst_off[d] + rd[e];
}

// aperm_pk[j][h2] = pack(relu(mlp)[2*h2], relu(mlp)[2*h2+1]), j in src-CSR order
__global__ __launch_bounds__(256) void kEdgeMLPpk(const float* __restrict__ ea,
                                                  const float* __restrict__ w1,
                                                  const float* __restrict__ b1,
                                                  const int* __restrict__ so_eid,
                                                  unsigned int* __restrict__ apk, int E){
  int idx = blockIdx.x * 256 + threadIdx.x;
  int j = idx >> 5, h2 = idx & 31;
  if (j >= E) return;
  int e = so_eid[j];
  const float* eap = ea + (size_t)e * 5;
  float q0 = eap[0], q1 = eap[1], q2 = eap[2], q3 = eap[3], q4 = eap[4];
  int h = 2 * h2;
  float lo = b1[h]     + q0 * w1[h]       + q1 * w1[64 + h]     + q2 * w1[128 + h]
                       + q3 * w1[192 + h] + q4 * w1[256 + h];
  float hi = b1[h + 1] + q0 * w1[h + 1]   + q1 * w1[64 + h + 1] + q2 * w1[128 + h + 1]
                       + q3 * w1[192 + h + 1] + q4 * w1[256 + h + 1];
  apk[(size_t)j * 32 + h2] = pk2(fmaxf(lo, 0.f), fmaxf(hi, 0.f));
}

// ---------- fused per-iteration kernel ----------
// Phase A: T = feat_chunk @ M via MFMA (16x16x32 f16), 65 pair-jobs.
// Phase B: per-wave edge processing; a loaded direct global->registers
// (broadcast uint4 loads), no LDS staging, no wave barriers.
__global__ __launch_bounds__(256, 4) void kTA(const float* __restrict__ feat,
                                              const uint4* __restrict__ Mpk2,
                                              const int* __restrict__ so_src,
                                              const int* __restrict__ s2d,
                                              const unsigned int* __restrict__ apk,
                                              const int* __restrict__ src_off,
                                              float* __restrict__ msg,
                                              int N){
  __shared__ unsigned int Tp[CHUNK * 32 * TROW];  // 34816 B
  __shared__ float bias_l[CHUNK][33];
  int tid = threadIdx.x;
  int c0 = blockIdx.x * CHUNK;
  int c1 = min(c0 + CHUNK, N);
  int nvalid = c1 - c0;
  int w = tid >> 6, l = tid & 63;

  // ---- phase A: A-fragment (row = l&15 node, k = (l>>4)*8+e) ----
  {
    int nodeA = c0 + (l & 15);
    if (nodeA > c1 - 1) nodeA = c1 - 1;
    int k0 = (l >> 4) * 8;
    const float* fr = feat + (size_t)nodeA * 32 + k0;
    float4 fa = *(const float4*)fr;
    float4 fb = *(const float4*)(fr + 4);
    union { uint4 u; f16x8 h; } A;
    A.u.x = pk2(fa.x, fa.y); A.u.y = pk2(fa.z, fa.w);
    A.u.z = pk2(fb.x, fb.y); A.u.w = pk2(fb.z, fb.w);

    for (int job = w; job < 65; job += 4){
      int cE, cO, s = 0;
      if (job < 64){ int t = job >> 1; s = job & 1; cE = 4 * t + s; cO = 4 * t + 2 + s; }
      else { cE = 128; cO = 129; }
      union { uint4 u; f16x8 h; } BE, BO;
      BE.u = Mpk2[cE * 64 + l];
      BO.u = Mpk2[cO * 64 + l];
      f32x4 z = {0.f, 0.f, 0.f, 0.f};
      f32x4 dE = __builtin_amdgcn_mfma_f32_16x16x32_f16(A.h, BE.h, z, 0, 0, 0);
      f32x4 dO = __builtin_amdgcn_mfma_f32_16x16x32_f16(A.h, BO.h, z, 0, 0, 0);
      if (job < 64){
        int t = job >> 1;
        int o = s * 16 + (l & 15);
#pragma unroll
        for (int r = 0; r < 4; r++){
          int nn = (l >> 4) * 4 + r;
          if (nn < nvalid) Tp[nn * 1088 + o * TROW + t] = pk2(dE[r], dO[r]);
        }
      } else {
#pragma unroll
        for (int r = 0; r < 4; r++){
          int nn = (l >> 4) * 4 + r;
          if (nn < nvalid){
            bias_l[nn][l & 15]        = dE[r];
            bias_l[nn][16 + (l & 15)] = dO[r];
          }
        }
      }
    }
  }
  __syncthreads();

  // ---- phase B: per-wave edge processing, a in registers ----
  int jj = l >> 5, o = l & 31;
  int e0 = src_off[c0], e1 = src_off[c1];
  for (int j = e0 + w * 2 + jj; j < e1; j += 8){
    const uint4* ap4 = (const uint4*)(apk + (size_t)j * 32);
    uint4 A0 = ap4[0], A1 = ap4[1], A2 = ap4[2], A3 = ap4[3];
    uint4 A4 = ap4[4], A5 = ap4[5], A6 = ap4[6], A7 = ap4[7];
    int u = so_src[j] - c0;
    int dpos = s2d[j];
    const unsigned int* Tr = Tp + u * 1088 + o * TROW;
    float s0 = bias_l[u][o], s1 = 0.f;
#define TA_STEP(g, Ar) { \
    uint2 tv = *(const uint2*)(Tr + (g) * 4); \
    uint2 tw = *(const uint2*)(Tr + (g) * 4 + 2); \
    s0 = dot2(Ar.x, tv.x, s0); \
    s1 = dot2(Ar.y, tv.y, s1); \
    s0 = dot2(Ar.z, tw.x, s0); \
    s1 = dot2(Ar.w, tw.y, s1); }
    TA_STEP(0, A0) TA_STEP(1, A1) TA_STEP(2, A2) TA_STEP(3, A3)
    TA_STEP(4, A4) TA_STEP(5, A5) TA_STEP(6, A6) TA_STEP(7, A7)
#undef TA_STEP
    msg[(size_t)dpos * 32 + o] = s0 + s1;
  }
}

// aggregate msg (dst-ordered) + conv bias + relu + GRU (packed-f16 dot2)
__global__ __launch_bounds__(256) void kB(const float* __restrict__ msg,
                                          const int* __restrict__ dst_off,
                                          const float* __restrict__ deg,
                                          const float* __restrict__ feat_in,
                                          float* __restrict__ feat_out,
                                          float* __restrict__ out2,
                                          const float* __restrict__ Wih,
                                          const float* __restrict__ Whh,
                                          const float* __restrict__ bih,
                                          const float* __restrict__ bhh,
                                          const float* __restrict__ cbias, int N){
  __shared__ unsigned int wihpk[96][17], whhpk[96][17];
  __shared__ float bi[96], bh[96], cb[32];
  __shared__ unsigned int mshpk[8][17], hshpk[8][17];
  int tid = threadIdx.x;
  for (int k = tid; k < 96 * 16; k += 256){
    int g = k >> 4, q2 = k & 15;
    wihpk[g][q2] = pk2(Wih[g * 32 + 2 * q2], Wih[g * 32 + 2 * q2 + 1]);
    whhpk[g][q2] = pk2(Whh[g * 32 + 2 * q2], Whh[g * 32 + 2 * q2 + 1]);
  }
  if (tid < 96){ bi[tid] = bih[tid]; bh[tid] = bhh[tid]; }
  if (tid < 32) cb[tid] = cbias[tid];
  __syncthreads();
  int s = tid >> 5, o = tid & 31;
  for (int g8 = 0; g8 < KBN / 8; g8++){
    int v = blockIdx.x * KBN + g8 * 8 + s;
    if (v < N){
      int lo = dst_off[v], hi = dst_off[v + 1];
      float h = feat_in[(size_t)v * 32 + o];
      float a0 = 0.f, a1 = 0.f, a2 = 0.f, a3 = 0.f;
      int k = lo;
      for (; k + 3 < hi; k += 4){
        a0 += msg[(size_t)(k + 0) * 32 + o];
        a1 += msg[(size_t)(k + 1) * 32 + o];
        a2 += msg[(size_t)(k + 2) * 32 + o];
        a3 += msg[(size_t)(k + 3) * 32 + o];
      }
      for (; k < hi; k++) a0 += msg[(size_t)k * 32 + o];
      float acc = (a0 + a1) + (a2 + a3);
      float m = fmaxf(acc / deg[v] + cb[o], 0.f);
      float m1 = __shfl_down(m, 1);
      float h1 = __shfl_down(h, 1);
      if (!(o & 1)){
        mshpk[s][o >> 1] = pk2(m, m1);
        hshpk[s][o >> 1] = pk2(h, h1);
      }
      float gr = bi[o], gz = bi[32 + o], gn = bi[64 + o];
      float hr = bh[o], hz = bh[32 + o], hn = bh[64 + o];
#pragma unroll
      for (int q2 = 0; q2 < 16; q2++){
        unsigned int mq = mshpk[s][q2], hq = hshpk[s][q2];
        gr = dot2(mq, wihpk[o][q2], gr);
        gz = dot2(mq, wihpk[32 + o][q2], gz);
        gn = dot2(mq, wihpk[64 + o][q2], gn);
        hr = dot2(hq, whhpk[o][q2], hr);
        hz = dot2(hq, whhpk[32 + o][q2], hz);
        hn = dot2(hq, whhpk[64 + o][q2], hn);
      }
      float r = 1.f / (1.f + expf(-(gr + hr)));
      float z = 1.f / (1.f + expf(-(gz + hz)));
      float n = tanhf(gn + r * hn);
      float val = (1.f - z) * n + z * h;
      feat_out[(size_t)v * 32 + o] = val;
      if (out2) out2[(size_t)v * 32 + o] = val;
    }
  }
}

// ---------- fused Set2Set: one block per graph, parallel e/pool passes ----------
__global__ __launch_bounds__(256) void kS2S(const float* __restrict__ feat,
                                            const int* __restrict__ boff,
                                            const float* __restrict__ Wih,
                                            const float* __restrict__ Whh,
                                            const float* __restrict__ bih,
                                            const float* __restrict__ bhh,
                                            float* __restrict__ e_buf,
                                            float* __restrict__ out){
  int b = blockIdx.x;
  __shared__ float WihL[128][65];
  __shared__ float WhhL[128][33];
  __shared__ float qs[64], hst[32], cst[32], garr[128];
  __shared__ float wred[4];
  __shared__ float part[8][33];
  int tid = threadIdx.x;
  for (int k = tid; k < 128 * 64; k += 256) WihL[k >> 6][k & 63] = Wih[k];
  for (int k = tid; k < 128 * 32; k += 256) WhhL[k >> 5][k & 31] = Whh[k];
  if (tid < 64) qs[tid] = 0.f;
  if (tid < 32){ hst[tid] = 0.f; cst[tid] = 0.f; }
  __syncthreads();
  int lo = boff[b], hi = boff[b + 1];
  int sub = tid >> 5, o = tid & 31;
  for (int step = 0; step < 3; step++){
    if (tid < 128){
      float acc = bih[tid] + bhh[tid];
#pragma unroll 8
      for (int j = 0; j < 64; j++) acc += qs[j] * WihL[tid][j];
#pragma unroll 8
      for (int j = 0; j < 32; j++) acc += hst[j] * WhhL[tid][j];
      garr[tid] = acc;
    }
    __syncthreads();
    if (tid < 32){
      float iv = 1.f / (1.f + expf(-garr[tid]));
      float fv = 1.f / (1.f + expf(-garr[32 + tid]));
      float gv = tanhf(garr[64 + tid]);
      float ov = 1.f / (1.f + expf(-garr[96 + tid]));
      float c = fv * cst[tid] + iv * gv;
      cst[tid] = c;
      float hv = ov * tanhf(c);
      hst[tid] = hv;
      qs[tid] = hv;
    }
    __syncthreads();
    // e-pass: one node per thread (parallel dot products)
    float mx = -1e30f;
    for (int i = lo + tid; i < hi; i += 256){
      const float* fr = feat + (size_t)i * 32;
      float acc = 0.f;
#pragma unroll
      for (int c4 = 0; c4 < 8; c4++){
        float4 f = *(const float4*)(fr + c4 * 4);
        acc += f.x * hst[c4 * 4] + f.y * hst[c4 * 4 + 1]
             + f.z * hst[c4 * 4 + 2] + f.w * hst[c4 * 4 + 3];
      }
      e_buf[i] = acc;
      mx = fmaxf(mx, acc);
    }
#pragma unroll
    for (int d2 = 32; d2; d2 >>= 1) mx = fmaxf(mx, __shfl_xor(mx, d2, 64));
    if ((tid & 63) == 0) wred[tid >> 6] = mx;
    __syncthreads();
    mx = fmaxf(fmaxf(wred[0], wred[1]), fmaxf(wred[2], wred[3]));
    __syncthreads();
    float sm = 0.f;
    for (int i = lo + tid; i < hi; i += 256){
      float w2 = expf(e_buf[i] - mx);
      e_buf[i] = w2;
      sm += w2;
    }
#pragma unroll
    for (int d2 = 32; d2; d2 >>= 1) sm += __shfl_xor(sm, d2, 64);
    if ((tid & 63) == 0) wred[tid >> 6] = sm;
    __syncthreads();
    float denom = fmaxf(wred[0] + wred[1] + wred[2] + wred[3], 1e-30f);
    // pool: sub-based, 4-way unrolled independent loads
    float a0 = 0.f, a1 = 0.f, a2 = 0.f, a3 = 0.f;
    int i = lo + sub;
    for (; i + 24 < hi; i += 32){
      a0 += e_buf[i]      * feat[(size_t)i * 32 + o];
      a1 += e_buf[i + 8]  * feat[(size_t)(i + 8) * 32 + o];
      a2 += e_buf[i + 16] * feat[(size_t)(i + 16) * 32 + o];
      a3 += e_buf[i + 24] * feat[(size_t)(i + 24) * 32 + o];
    }
    for (; i < hi; i += 8) a0 += e_buf[i] * feat[(size_t)i * 32 + o];
    part[sub][o] = (a0 + a1) + (a2 + a3);
    __syncthreads();
    if (tid < 32){
      float r2 = 0.f;
#pragma unroll
      for (int s2 = 0; s2 < 8; s2++) r2 += part[s2][tid];
      qs[32 + tid] = r2 / denom;
    }
    __syncthreads();
  }
  if (tid < 64) out[b * 64 + tid] = qs[tid];
}

// ---------- host ----------

extern "C" void kernel_launch(void* const* d_in, const int* in_sizes, int n_in,
                              void* d_out, int out_size, void* d_ws, size_t ws_size,
                              hipStream_t stream){
  (void)n_in; (void)out_size; (void)ws_size;
  const float* x        = (const float*)d_in[0];
  const int*   ei       = (const int*)  d_in[1];
  const float* eattr    = (const float*)d_in[2];
  const int*   batch    = (const int*)  d_in[3];
  const float* lin0_w   = (const float*)d_in[4];
  const float* lin0_b   = (const float*)d_in[5];
  const float* mlp_w1   = (const float*)d_in[6];
  const float* mlp_b1   = (const float*)d_in[7];
  const float* mlp_w2   = (const float*)d_in[8];
  const float* mlp_b2   = (const float*)d_in[9];
  const float* conv_b   = (const float*)d_in[10];
  const float* gru_wih  = (const float*)d_in[11];
  const float* gru_whh  = (const float*)d_in[12];
  const float* gru_bih  = (const float*)d_in[13];
  const float* gru_bhh  = (const float*)d_in[14];
  const float* lstm_wih = (const float*)d_in[15];
  const float* lstm_whh = (const float*)d_in[16];
  const float* lstm_bih = (const float*)d_in[17];
  const float* lstm_bhh = (const float*)d_in[18];

  int N = in_sizes[0] / NFEAT;
  int E = in_sizes[1] / 2;

  char* ws = (char*)d_ws;
  size_t off = 0;
  auto alloc = [&](size_t bytes) -> char* {
    char* p = ws + off;
    off = align_up(off + bytes, 256);
    return p;
  };

  float* feat0  = (float*)alloc((size_t)N * D * 4);
  float* feat1  = (float*)alloc((size_t)N * D * 4);
  float* msg    = (float*)alloc((size_t)E * D * 4);
  unsigned int* Mpk2 = (unsigned int*)alloc((size_t)130 * 64 * 4 * 4);
  unsigned int* apk = (unsigned int*)alloc((size_t)E * 32 * 4);
  float* e_buf  = (float*)alloc((size_t)N * 4);
  float* deg    = (float*)alloc((size_t)N * 4);
  int* cnt_src  = (int*)alloc((size_t)N * CPAD * 4);   // padded: 1 counter / 64B
  int* cnt_dst  = (int*)alloc((size_t)N * CPAD * 4);
  int* rs       = (int*)alloc((size_t)E * 4);
  int* rd       = (int*)alloc((size_t)E * 4);
  int* src_off  = (int*)alloc((size_t)(N + 1) * 4);
  int* dst_off  = (int*)alloc((size_t)(N + 1) * 4);
  int* boff     = (int*)alloc((size_t)(NB + 1) * 4);
  int* so_src   = (int*)alloc((size_t)E * 4);
  int* so_eid   = (int*)alloc((size_t)E * 4);
  int* s2d      = (int*)alloc((size_t)E * 4);

  // zero the padded counters
  (void)hipMemsetAsync(cnt_src, 0, (size_t)N * CPAD * 4 * 2, stream);

  kBuildMpk2<<<(130 * 64 * 4 + 255) / 256, 256, 0, stream>>>(mlp_w2, mlp_b2, Mpk2);
  kLin0<<<(N * 32 + 255) / 256, 256, 0, stream>>>(x, lin0_w, lin0_b, feat0, N);
  kCountRank<<<(E + 255) / 256, 256, 0, stream>>>(ei, cnt_src, cnt_dst, rs, rd, E);
  kScan<<<3, 256, 0, stream>>>(cnt_src, cnt_dst, batch, src_off, dst_off, boff, deg, N, NB);
  kPlace<<<(E + 255) / 256, 256, 0, stream>>>(ei, src_off, dst_off, rs, rd,
                                              so_src, so_eid, s2d, E);
  kEdgeMLPpk<<<((size_t)E * 32 + 255) / 256, 256, 0, stream>>>(eattr, mlp_w1, mlp_b1,
                                                               so_eid, apk, E);

  int blocksTA = (N + CHUNK - 1) / CHUNK;
  float* fcur = feat0;
  float* fnext = feat1;
  for (int t = 0; t < 3; t++){
    kTA<<<blocksTA, 256, 0, stream>>>(fcur, (const uint4*)Mpk2, so_src, s2d, apk,
                                      src_off, msg, N);
    float* out2 = (t == 2) ? ((float*)d_out + NB * 64) : nullptr;
    kB<<<(N + KBN - 1) / KBN, 256, 0, stream>>>(msg, dst_off, deg, fcur, fnext, out2,
                                                gru_wih, gru_whh, gru_bih, gru_bhh,
                                                conv_b, N);
    float* tmp = fcur; fcur = fnext; fnext = tmp;
  }

  kS2S<<<NB, 256, 0, stream>>>(fcur, boff, lstm_wih, lstm_whh, lstm_bih, lstm_bhh,
                               e_buf, (float*)d_out);
}

// Round 12
// 381.549 us; speedup vs baseline: 5.6983x; 1.0807x over previous
//
#include <hip/hip_runtime.h>
#include <hip/hip_fp16.h>

#define NFEAT 16
#define D 32
#define NB 64        // num graphs
#define TCOLS 2080   // 65*32
#define CHUNK 8      // nodes per fused block
#define TROW 34      // u32 per (node,o) LDS row
#define CPAD 16      // counter padding: one counter per 64B line
#define KBN 16       // nodes per kB block

static inline size_t align_up(size_t x, size_t a){ return (x + a - 1) & ~(a - 1); }

typedef _Float16 f16x2 __attribute__((ext_vector_type(2)));
typedef _Float16 f16x8 __attribute__((ext_vector_type(8)));
typedef float f32x4 __attribute__((ext_vector_type(4)));

__device__ inline unsigned int pk2(float a, float b){
  __half2 h = __floats2half2_rn(a, b);
  union { __half2 h; unsigned int u; } cv; cv.h = h; return cv.u;
}

__device__ inline float dot2(unsigned int a, unsigned int b, float c){
  union { unsigned int u; f16x2 h; } ua, ub; ua.u = a; ub.u = b;
#if __has_builtin(__builtin_amdgcn_fdot2)
  return __builtin_amdgcn_fdot2(ua.h, ub.h, c, false);
#else
  return c + (float)ua.h[0] * (float)ub.h[0] + (float)ua.h[1] * (float)ub.h[1];
#endif
}

// ---------- setup kernels ----------

// B-fragment layout for v_mfma_f32_16x16x32_f16 (tile c: cols c*16..+15, col=h*32+o)
__global__ __launch_bounds__(256) void kBuildMpk2(const float* __restrict__ w2,
                                                  const float* __restrict__ b2,
                                                  unsigned int* __restrict__ Mpk2){
  int idx = blockIdx.x * 256 + threadIdx.x;
  if (idx >= 130 * 64 * 4) return;
  int j2 = idx & 3;
  int l  = (idx >> 2) & 63;
  int c  = idx >> 8;
  int col = c * 16 + (l & 15);
  int h = col >> 5, o = col & 31;
  int ke = (l >> 4) * 8 + 2 * j2;
  float f0, f1;
  if (h < 64){
    f0 = w2[h * 1024 + ke * 32 + o];
    f1 = w2[h * 1024 + (ke + 1) * 32 + o];
  } else {
    f0 = b2[ke * 32 + o];
    f1 = b2[(ke + 1) * 32 + o];
  }
  Mpk2[idx] = pk2(f0, f1);
}

__global__ __launch_bounds__(256) void kLin0(const float* __restrict__ x,
                                             const float* __restrict__ w,
                                             const float* __restrict__ b,
                                             float* __restrict__ feat, int N){
  int idx = blockIdx.x * 256 + threadIdx.x;
  int u = idx >> 5, o = idx & 31;
  if (u >= N) return;
  float acc = b[o];
#pragma unroll
  for (int i = 0; i < NFEAT; i++) acc += x[(size_t)u * NFEAT + i] * w[i * 32 + o];
  feat[idx] = fmaxf(acc, 0.f);
}

// counts (padded) + ranks in one pass
__global__ __launch_bounds__(256) void kCountRank(const int* __restrict__ ei,
                                                  int* __restrict__ cnt_src,
                                                  int* __restrict__ cnt_dst,
                                                  int* __restrict__ rs,
                                                  int* __restrict__ rd, int E){
  int e = blockIdx.x * 256 + threadIdx.x;
  if (e >= E) return;
  int s = ei[e], d = ei[E + e];
  rs[e] = atomicAdd(&cnt_src[(size_t)s * CPAD], 1);
  rd[e] = atomicAdd(&cnt_dst[(size_t)d * CPAD], 1);
}

// hierarchical scan, stage A: per-256-tile block scan; grid (NT, 2)
__global__ __launch_bounds__(256) void kScanA(const int* __restrict__ cnt_src,
                                              const int* __restrict__ cnt_dst,
                                              int* __restrict__ src_off,
                                              int* __restrict__ dst_off,
                                              int* __restrict__ bsum,
                                              float* __restrict__ deg,
                                              int N, int NT){
  int y = blockIdx.y;
  const int* cnt = y ? cnt_dst : cnt_src;
  int* off = y ? dst_off : src_off;
  int t = threadIdx.x;
  int i = blockIdx.x * 256 + t;
  int c = (i < N) ? cnt[(size_t)i * CPAD] : 0;
  if (y && i < N) deg[i] = (float)max(c, 1);
  __shared__ int sh[256];
  sh[t] = c; __syncthreads();
  for (int d = 1; d < 256; d <<= 1){
    int v = (t >= d) ? sh[t - d] : 0;
    __syncthreads();
    sh[t] += v;
    __syncthreads();
  }
  if (i < N) off[i] = sh[t] - c;           // within-tile exclusive
  if (t == 255) bsum[y * NT + blockIdx.x] = sh[255];
}

// stage B: scan tile sums (NT<=256) + batch offsets via bsearch
__global__ __launch_bounds__(256) void kScanB(int* __restrict__ bsum,
                                              const int* __restrict__ batch,
                                              int* __restrict__ boff,
                                              int* __restrict__ src_off,
                                              int* __restrict__ dst_off,
                                              int N, int NT, int B, int E){
  int t = threadIdx.x;
  __shared__ int sh[256];
  for (int y = 0; y < 2; y++){
    int v = (t < NT) ? bsum[y * NT + t] : 0;
    sh[t] = v; __syncthreads();
    for (int d = 1; d < 256; d <<= 1){
      int u = (t >= d) ? sh[t - d] : 0;
      __syncthreads();
      sh[t] += u;
      __syncthreads();
    }
    if (t < NT) bsum[y * NT + t] = sh[t] - v;   // exclusive tile offset
    __syncthreads();
  }
  if (t <= B){
    int lo = 0, hi = N;
    while (lo < hi){ int mid = (lo + hi) >> 1; if (batch[mid] < t) lo = mid + 1; else hi = mid; }
    boff[t] = lo;
  }
  if (t == 0){ src_off[N] = E; dst_off[N] = E; }
}

// stage C: add tile offsets; grid (NT, 2)
__global__ __launch_bounds__(256) void kScanC(int* __restrict__ src_off,
                                              int* __restrict__ dst_off,
                                              const int* __restrict__ bsum,
                                              int N, int NT){
  int y = blockIdx.y;
  int i = blockIdx.x * 256 + threadIdx.x;
  if (i < N) (y ? dst_off : src_off)[i] += bsum[y * NT + blockIdx.x];
}

// atomic-free placement using precomputed ranks
__global__ __launch_bounds__(256) void kPlace(const int* __restrict__ ei,
                                              const int* __restrict__ src_off,
                                              const int* __restrict__ dst_off,
                                              const int* __restrict__ rs,
                                              const int* __restrict__ rd,
                                              int* __restrict__ so_src,
                                              int* __restrict__ so_eid,
                                              int* __restrict__ s2d, int E){
  int e = blockIdx.x * 256 + threadIdx.x;
  if (e >= E) return;
  int s = ei[e], d = ei[E + e];
  int ps = src_off[s] + rs[e];
  so_src[ps] = s;
  so_eid[ps] = e;
  s2d[ps] = dst_off[d] + rd[e];
}

// aperm_pk[j][h2], j in src-CSR order
__global__ __launch_bounds__(256) void kEdgeMLPpk(const float* __restrict__ ea,
                                                  const float* __restrict__ w1,
                                                  const float* __restrict__ b1,
                                                  const int* __restrict__ so_eid,
                                                  unsigned int* __restrict__ apk, int E){
  int idx = blockIdx.x * 256 + threadIdx.x;
  int j = idx >> 5, h2 = idx & 31;
  if (j >= E) return;
  int e = so_eid[j];
  const float* eap = ea + (size_t)e * 5;
  float q0 = eap[0], q1 = eap[1], q2 = eap[2], q3 = eap[3], q4 = eap[4];
  int h = 2 * h2;
  float lo = b1[h]     + q0 * w1[h]       + q1 * w1[64 + h]     + q2 * w1[128 + h]
                       + q3 * w1[192 + h] + q4 * w1[256 + h];
  float hi = b1[h + 1] + q0 * w1[h + 1]   + q1 * w1[64 + h + 1] + q2 * w1[128 + h + 1]
                       + q3 * w1[192 + h + 1] + q4 * w1[256 + h + 1];
  apk[(size_t)j * 32 + h2] = pk2(fmaxf(lo, 0.f), fmaxf(hi, 0.f));
}

// ---------- fused per-iteration kernel ----------
// Edge buffer for the rotate-3 register pipeline (fully unrolled -> registers)
struct EdgeBuf { uint4 a[8]; int u; int d; };

__device__ __forceinline__ void loadEdge(EdgeBuf& b,
                                         const unsigned int* __restrict__ apk,
                                         const int* __restrict__ so_src,
                                         const int* __restrict__ s2d,
                                         int j, int c0){
  const uint4* p = (const uint4*)(apk + (size_t)j * 32);
#pragma unroll
  for (int g = 0; g < 8; g++) b.a[g] = p[g];
  b.u = so_src[j] - c0;
  b.d = s2d[j];
}

__device__ __forceinline__ void compEdge(const EdgeBuf& b,
                                         const unsigned int* __restrict__ Tp,
                                         const float (*bias_l)[33],
                                         float* __restrict__ msg, int o){
  const unsigned int* Tr = Tp + b.u * 1088 + o * TROW;
  float s0 = bias_l[b.u][o], s1 = 0.f;
#pragma unroll
  for (int g = 0; g < 8; g++){
    uint2 tv = *(const uint2*)(Tr + g * 4);
    uint2 tw = *(const uint2*)(Tr + g * 4 + 2);
    s0 = dot2(b.a[g].x, tv.x, s0);
    s1 = dot2(b.a[g].y, tv.y, s1);
    s0 = dot2(b.a[g].z, tw.x, s0);
    s1 = dot2(b.a[g].w, tw.y, s1);
  }
  msg[(size_t)b.d * 32 + o] = s0 + s1;
}

// Phase A: T = feat_chunk @ M via MFMA. Phase B: per-wave edge processing,
// rotate-3 register pipeline on apk rows (depth-3 HBM latency hiding).
__global__ __launch_bounds__(256) void kTA(const float* __restrict__ feat,
                                           const uint4* __restrict__ Mpk2,
                                           const int* __restrict__ so_src,
                                           const int* __restrict__ s2d,
                                           const unsigned int* __restrict__ apk,
                                           const int* __restrict__ src_off,
                                           float* __restrict__ msg,
                                           int N){
  __shared__ unsigned int Tp[CHUNK * 32 * TROW];  // 34816 B
  __shared__ float bias_l[CHUNK][33];
  int tid = threadIdx.x;
  int c0 = blockIdx.x * CHUNK;
  int c1 = min(c0 + CHUNK, N);
  int nvalid = c1 - c0;
  int w = tid >> 6, l = tid & 63;

  // ---- phase A ----
  {
    int nodeA = c0 + (l & 15);
    if (nodeA > c1 - 1) nodeA = c1 - 1;
    int k0 = (l >> 4) * 8;
    const float* fr = feat + (size_t)nodeA * 32 + k0;
    float4 fa = *(const float4*)fr;
    float4 fb = *(const float4*)(fr + 4);
    union { uint4 u; f16x8 h; } A;
    A.u.x = pk2(fa.x, fa.y); A.u.y = pk2(fa.z, fa.w);
    A.u.z = pk2(fb.x, fb.y); A.u.w = pk2(fb.z, fb.w);

    for (int job = w; job < 65; job += 4){
      int cE, cO, s = 0;
      if (job < 64){ int t = job >> 1; s = job & 1; cE = 4 * t + s; cO = 4 * t + 2 + s; }
      else { cE = 128; cO = 129; }
      union { uint4 u; f16x8 h; } BE, BO;
      BE.u = Mpk2[cE * 64 + l];
      BO.u = Mpk2[cO * 64 + l];
      f32x4 z = {0.f, 0.f, 0.f, 0.f};
      f32x4 dE = __builtin_amdgcn_mfma_f32_16x16x32_f16(A.h, BE.h, z, 0, 0, 0);
      f32x4 dO = __builtin_amdgcn_mfma_f32_16x16x32_f16(A.h, BO.h, z, 0, 0, 0);
      if (job < 64){
        int t = job >> 1;
        int o = s * 16 + (l & 15);
#pragma unroll
        for (int r = 0; r < 4; r++){
          int nn = (l >> 4) * 4 + r;
          if (nn < nvalid) Tp[nn * 1088 + o * TROW + t] = pk2(dE[r], dO[r]);
        }
      } else {
#pragma unroll
        for (int r = 0; r < 4; r++){
          int nn = (l >> 4) * 4 + r;
          if (nn < nvalid){
            bias_l[nn][l & 15]        = dE[r];
            bias_l[nn][16 + (l & 15)] = dO[r];
          }
        }
      }
    }
  }
  __syncthreads();

  // ---- phase B: rotate-3 pipelined edge processing ----
  int jj = l >> 5, o = l & 31;
  int e0 = src_off[c0], e1 = src_off[c1];

  EdgeBuf Pa, Pb, Pc;
  int j0 = e0 + w * 2 + jj;
  int j1 = j0 + 8, j2 = j0 + 16;
  bool v0 = j0 < e1, v1 = j1 < e1, v2 = j2 < e1;
  if (v0) loadEdge(Pa, apk, so_src, s2d, j0, c0);
  if (v1) loadEdge(Pb, apk, so_src, s2d, j1, c0);
  if (v2) loadEdge(Pc, apk, so_src, s2d, j2, c0);
  while (v0){
    compEdge(Pa, Tp, bias_l, msg, o);
    j0 = j2 + 8; v0 = j0 < e1;
    if (v0) loadEdge(Pa, apk, so_src, s2d, j0, c0);
    if (!v1) break;
    compEdge(Pb, Tp, bias_l, msg, o);
    j1 = j0 + 8; v1 = j1 < e1;
    if (v1) loadEdge(Pb, apk, so_src, s2d, j1, c0);
    if (!v2) break;
    compEdge(Pc, Tp, bias_l, msg, o);
    j2 = j1 + 8; v2 = j2 < e1;
    if (v2) loadEdge(Pc, apk, so_src, s2d, j2, c0);
  }
}

// aggregate msg (dst-ordered) + conv bias + relu + GRU (packed-f16 dot2)
__global__ __launch_bounds__(256) void kB(const float* __restrict__ msg,
                                          const int* __restrict__ dst_off,
                                          const float* __restrict__ deg,
                                          const float* __restrict__ feat_in,
                                          float* __restrict__ feat_out,
                                          float* __restrict__ out2,
                                          const float* __restrict__ Wih,
                                          const float* __restrict__ Whh,
                                          const float* __restrict__ bih,
                                          const float* __restrict__ bhh,
                                          const float* __restrict__ cbias, int N){
  __shared__ unsigned int wihpk[96][17], whhpk[96][17];
  __shared__ float bi[96], bh[96], cb[32];
  __shared__ unsigned int mshpk[8][17], hshpk[8][17];
  int tid = threadIdx.x;
  for (int k = tid; k < 96 * 16; k += 256){
    int g = k >> 4, q2 = k & 15;
    wihpk[g][q2] = pk2(Wih[g * 32 + 2 * q2], Wih[g * 32 + 2 * q2 + 1]);
    whhpk[g][q2] = pk2(Whh[g * 32 + 2 * q2], Whh[g * 32 + 2 * q2 + 1]);
  }
  if (tid < 96){ bi[tid] = bih[tid]; bh[tid] = bhh[tid]; }
  if (tid < 32) cb[tid] = cbias[tid];
  __syncthreads();
  int s = tid >> 5, o = tid & 31;
  for (int g8 = 0; g8 < KBN / 8; g8++){
    int v = blockIdx.x * KBN + g8 * 8 + s;
    if (v < N){
      int lo = dst_off[v], hi = dst_off[v + 1];
      float h = feat_in[(size_t)v * 32 + o];
      float a0 = 0.f, a1 = 0.f, a2 = 0.f, a3 = 0.f;
      int k = lo;
      for (; k + 3 < hi; k += 4){
        a0 += msg[(size_t)(k + 0) * 32 + o];
        a1 += msg[(size_t)(k + 1) * 32 + o];
        a2 += msg[(size_t)(k + 2) * 32 + o];
        a3 += msg[(size_t)(k + 3) * 32 + o];
      }
      for (; k < hi; k++) a0 += msg[(size_t)k * 32 + o];
      float acc = (a0 + a1) + (a2 + a3);
      float m = fmaxf(acc / deg[v] + cb[o], 0.f);
      float m1 = __shfl_down(m, 1);
      float h1 = __shfl_down(h, 1);
      if (!(o & 1)){
        mshpk[s][o >> 1] = pk2(m, m1);
        hshpk[s][o >> 1] = pk2(h, h1);
      }
      float gr = bi[o], gz = bi[32 + o], gn = bi[64 + o];
      float hr = bh[o], hz = bh[32 + o], hn = bh[64 + o];
#pragma unroll
      for (int q2 = 0; q2 < 16; q2++){
        unsigned int mq = mshpk[s][q2], hq = hshpk[s][q2];
        gr = dot2(mq, wihpk[o][q2], gr);
        gz = dot2(mq, wihpk[32 + o][q2], gz);
        gn = dot2(mq, wihpk[64 + o][q2], gn);
        hr = dot2(hq, whhpk[o][q2], hr);
        hz = dot2(hq, whhpk[32 + o][q2], hz);
        hn = dot2(hq, whhpk[64 + o][q2], hn);
      }
      float r = 1.f / (1.f + expf(-(gr + hr)));
      float z = 1.f / (1.f + expf(-(gz + hz)));
      float n = tanhf(gn + r * hn);
      float val = (1.f - z) * n + z * h;
      feat_out[(size_t)v * 32 + o] = val;
      if (out2) out2[(size_t)v * 32 + o] = val;
    }
  }
}

// ---------- fused Set2Set ----------
__global__ __launch_bounds__(256) void kS2S(const float* __restrict__ feat,
                                            const int* __restrict__ boff,
                                            const float* __restrict__ Wih,
                                            const float* __restrict__ Whh,
                                            const float* __restrict__ bih,
                                            const float* __restrict__ bhh,
                                            float* __restrict__ e_buf,
                                            float* __restrict__ out){
  int b = blockIdx.x;
  __shared__ float WihL[128][65];
  __shared__ float WhhL[128][33];
  __shared__ float qs[64], hst[32], cst[32], garr[128];
  __shared__ float wred[4];
  __shared__ float part[8][33];
  int tid = threadIdx.x;
  for (int k = tid; k < 128 * 64; k += 256) WihL[k >> 6][k & 63] = Wih[k];
  for (int k = tid; k < 128 * 32; k += 256) WhhL[k >> 5][k & 31] = Whh[k];
  if (tid < 64) qs[tid] = 0.f;
  if (tid < 32){ hst[tid] = 0.f; cst[tid] = 0.f; }
  __syncthreads();
  int lo = boff[b], hi = boff[b + 1];
  int sub = tid >> 5, o = tid & 31;
  for (int step = 0; step < 3; step++){
    if (tid < 128){
      float acc = bih[tid] + bhh[tid];
#pragma unroll 8
      for (int j = 0; j < 64; j++) acc += qs[j] * WihL[tid][j];
#pragma unroll 8
      for (int j = 0; j < 32; j++) acc += hst[j] * WhhL[tid][j];
      garr[tid] = acc;
    }
    __syncthreads();
    if (tid < 32){
      float iv = 1.f / (1.f + expf(-garr[tid]));
      float fv = 1.f / (1.f + expf(-garr[32 + tid]));
      float gv = tanhf(garr[64 + tid]);
      float ov = 1.f / (1.f + expf(-garr[96 + tid]));
      float c = fv * cst[tid] + iv * gv;
      cst[tid] = c;
      float hv = ov * tanhf(c);
      hst[tid] = hv;
      qs[tid] = hv;
    }
    __syncthreads();
    float mx = -1e30f;
    for (int i = lo + tid; i < hi; i += 256){
      const float* fr = feat + (size_t)i * 32;
      float acc = 0.f;
#pragma unroll
      for (int c4 = 0; c4 < 8; c4++){
        float4 f = *(const float4*)(fr + c4 * 4);
        acc += f.x * hst[c4 * 4] + f.y * hst[c4 * 4 + 1]
             + f.z * hst[c4 * 4 + 2] + f.w * hst[c4 * 4 + 3];
      }
      e_buf[i] = acc;
      mx = fmaxf(mx, acc);
    }
#pragma unroll
    for (int d2 = 32; d2; d2 >>= 1) mx = fmaxf(mx, __shfl_xor(mx, d2, 64));
    if ((tid & 63) == 0) wred[tid >> 6] = mx;
    __syncthreads();
    mx = fmaxf(fmaxf(wred[0], wred[1]), fmaxf(wred[2], wred[3]));
    __syncthreads();
    float sm = 0.f;
    for (int i = lo + tid; i < hi; i += 256){
      float w2 = expf(e_buf[i] - mx);
      e_buf[i] = w2;
      sm += w2;
    }
#pragma unroll
    for (int d2 = 32; d2; d2 >>= 1) sm += __shfl_xor(sm, d2, 64);
    if ((tid & 63) == 0) wred[tid >> 6] = sm;
    __syncthreads();
    float denom = fmaxf(wred[0] + wred[1] + wred[2] + wred[3], 1e-30f);
    float a0 = 0.f, a1 = 0.f, a2 = 0.f, a3 = 0.f;
    int i = lo + sub;
    for (; i + 24 < hi; i += 32){
      a0 += e_buf[i]      * feat[(size_t)i * 32 + o];
      a1 += e_buf[i + 8]  * feat[(size_t)(i + 8) * 32 + o];
      a2 += e_buf[i + 16] * feat[(size_t)(i + 16) * 32 + o];
      a3 += e_buf[i + 24] * feat[(size_t)(i + 24) * 32 + o];
    }
    for (; i < hi; i += 8) a0 += e_buf[i] * feat[(size_t)i * 32 + o];
    part[sub][o] = (a0 + a1) + (a2 + a3);
    __syncthreads();
    if (tid < 32){
      float r2 = 0.f;
#pragma unroll
      for (int s2 = 0; s2 < 8; s2++) r2 += part[s2][tid];
      qs[32 + tid] = r2 / denom;
    }
    __syncthreads();
  }
  if (tid < 64) out[b * 64 + tid] = qs[tid];
}

// ---------- host ----------

extern "C" void kernel_launch(void* const* d_in, const int* in_sizes, int n_in,
                              void* d_out, int out_size, void* d_ws, size_t ws_size,
                              hipStream_t stream){
  (void)n_in; (void)out_size; (void)ws_size;
  const float* x        = (const float*)d_in[0];
  const int*   ei       = (const int*)  d_in[1];
  const float* eattr    = (const float*)d_in[2];
  const int*   batch    = (const int*)  d_in[3];
  const float* lin0_w   = (const float*)d_in[4];
  const float* lin0_b   = (const float*)d_in[5];
  const float* mlp_w1   = (const float*)d_in[6];
  const float* mlp_b1   = (const float*)d_in[7];
  const float* mlp_w2   = (const float*)d_in[8];
  const float* mlp_b2   = (const float*)d_in[9];
  const float* conv_b   = (const float*)d_in[10];
  const float* gru_wih  = (const float*)d_in[11];
  const float* gru_whh  = (const float*)d_in[12];
  const float* gru_bih  = (const float*)d_in[13];
  const float* gru_bhh  = (const float*)d_in[14];
  const float* lstm_wih = (const float*)d_in[15];
  const float* lstm_whh = (const float*)d_in[16];
  const float* lstm_bih = (const float*)d_in[17];
  const float* lstm_bhh = (const float*)d_in[18];

  int N = in_sizes[0] / NFEAT;
  int E = in_sizes[1] / 2;
  int NT = (N + 255) / 256;

  char* ws = (char*)d_ws;
  size_t off = 0;
  auto alloc = [&](size_t bytes) -> char* {
    char* p = ws + off;
    off = align_up(off + bytes, 256);
    return p;
  };

  float* feat0  = (float*)alloc((size_t)N * D * 4);
  float* feat1  = (float*)alloc((size_t)N * D * 4);
  float* msg    = (float*)alloc((size_t)E * D * 4);
  unsigned int* Mpk2 = (unsigned int*)alloc((size_t)130 * 64 * 4 * 4);
  unsigned int* apk = (unsigned int*)alloc((size_t)E * 32 * 4);
  float* e_buf  = (float*)alloc((size_t)N * 4);
  float* deg    = (float*)alloc((size_t)N * 4);
  int* cnt_src  = (int*)alloc((size_t)N * CPAD * 4);
  int* cnt_dst  = (int*)alloc((size_t)N * CPAD * 4);
  int* rs       = (int*)alloc((size_t)E * 4);
  int* rd       = (int*)alloc((size_t)E * 4);
  int* src_off  = (int*)alloc((size_t)(N + 1) * 4);
  int* dst_off  = (int*)alloc((size_t)(N + 1) * 4);
  int* boff     = (int*)alloc((size_t)(NB + 1) * 4);
  int* bsum     = (int*)alloc((size_t)2 * NT * 4);
  int* so_src   = (int*)alloc((size_t)E * 4);
  int* so_eid   = (int*)alloc((size_t)E * 4);
  int* s2d      = (int*)alloc((size_t)E * 4);

  (void)hipMemsetAsync(cnt_src, 0, (size_t)N * CPAD * 4 * 2, stream);

  kBuildMpk2<<<(130 * 64 * 4 + 255) / 256, 256, 0, stream>>>(mlp_w2, mlp_b2, Mpk2);
  kLin0<<<(N * 32 + 255) / 256, 256, 0, stream>>>(x, lin0_w, lin0_b, feat0, N);
  kCountRank<<<(E + 255) / 256, 256, 0, stream>>>(ei, cnt_src, cnt_dst, rs, rd, E);
  {
    dim3 gA(NT, 2);
    kScanA<<<gA, 256, 0, stream>>>(cnt_src, cnt_dst, src_off, dst_off, bsum, deg, N, NT);
    kScanB<<<1, 256, 0, stream>>>(bsum, batch, boff, src_off, dst_off, N, NT, NB, E);
    kScanC<<<gA, 256, 0, stream>>>(src_off, dst_off, bsum, N, NT);
  }
  kPlace<<<(E + 255) / 256, 256, 0, stream>>>(ei, src_off, dst_off, rs, rd,
                                              so_src, so_eid, s2d, E);
  kEdgeMLPpk<<<((size_t)E * 32 + 255) / 256, 256, 0, stream>>>(eattr, mlp_w1, mlp_b1,
                                                               so_eid, apk, E);

  int blocksTA = (N + CHUNK - 1) / CHUNK;
  float* fcur = feat0;
  float* fnext = feat1;
  for (int t = 0; t < 3; t++){
    kTA<<<blocksTA, 256, 0, stream>>>(fcur, (const uint4*)Mpk2, so_src, s2d, apk,
                                      src_off, msg, N);
    float* out2 = (t == 2) ? ((float*)d_out + NB * 64) : nullptr;
    kB<<<(N + KBN - 1) / KBN, 256, 0, stream>>>(msg, dst_off, deg, fcur, fnext, out2,
                                                gru_wih, gru_whh, gru_bih, gru_bhh,
                                                conv_b, N);
    float* tmp = fcur; fcur = fnext; fnext = tmp;
  }

  kS2S<<<NB, 256, 0, stream>>>(fcur, boff, lstm_wih, lstm_whh, lstm_bih, lstm_bhh,
                               e_buf, (float*)d_out);
}